// Round 1
// baseline (4699.179 us; speedup 1.0000x reference)
//
#include <hip/hip_runtime.h>
#include <cmath>

#define EPS 1e-5f
#define SLOPE 0.2f
#define STAT_CHUNKS 16

// ---------------- direct 4x4 stride-2 pad-1 conv ----------------
__global__ void conv4x4s2_kernel(const float* __restrict__ in, const float* __restrict__ w,
                                 float* __restrict__ out, int Bn, int Ci, int Co,
                                 int Hi, int Wi, int Ho, int Wo) {
    int idx = blockIdx.x * blockDim.x + threadIdx.x;
    int total = Bn * Co * Ho * Wo;
    if (idx >= total) return;
    int ow = idx % Wo;
    int t  = idx / Wo;
    int oh = t % Ho; t /= Ho;
    int co = t % Co;
    int b  = t / Co;
    int ih0 = oh * 2 - 1;
    int iw0 = ow * 2 - 1;
    const float* wp = w + (size_t)co * Ci * 16;
    float acc = 0.f;
    for (int ci = 0; ci < Ci; ++ci) {
        const float* ip = in + ((size_t)b * Ci + ci) * Hi * Wi;
        const float* wc = wp + ci * 16;
#pragma unroll
        for (int kh = 0; kh < 4; ++kh) {
            int ih = ih0 + kh;
            if (ih < 0 || ih >= Hi) continue;
            const float* row = ip + (size_t)ih * Wi;
#pragma unroll
            for (int kw = 0; kw < 4; ++kw) {
                int iw = iw0 + kw;
                if (iw < 0 || iw >= Wi) continue;
                acc = fmaf(row[iw], wc[kh * 4 + kw], acc);
            }
        }
    }
    out[idx] = acc;
}

// ---------------- BN stats: deterministic two-stage reduction ----------------
__global__ void bn_stats_partial(const float* __restrict__ x, float* __restrict__ part,
                                 int Bn, int C, int HW) {
    int c = blockIdx.x / STAT_CHUNKS;
    int chunk = blockIdx.x % STAT_CHUNKS;
    long N = (long)Bn * HW;
    long per = (N + STAT_CHUNKS - 1) / STAT_CHUNKS;
    long lo = (long)chunk * per;
    long hi = lo + per; if (hi > N) hi = N;
    double s1 = 0.0, s2 = 0.0;
    for (long i = lo + threadIdx.x; i < hi; i += blockDim.x) {
        int b = (int)(i / HW);
        int p = (int)(i % HW);
        float v = x[((size_t)b * C + c) * HW + p];
        s1 += v;
        s2 += (double)v * v;
    }
    __shared__ double sh1[256];
    __shared__ double sh2[256];
    int tid = threadIdx.x;
    sh1[tid] = s1; sh2[tid] = s2;
    __syncthreads();
    for (int s = 128; s > 0; s >>= 1) {
        if (tid < s) { sh1[tid] += sh1[tid + s]; sh2[tid] += sh2[tid + s]; }
        __syncthreads();
    }
    if (tid == 0) {
        part[((size_t)c * STAT_CHUNKS + chunk) * 2 + 0] = (float)sh1[0];
        part[((size_t)c * STAT_CHUNKS + chunk) * 2 + 1] = (float)sh2[0];
    }
}

__global__ void bn_finalize(const float* __restrict__ part, const float* __restrict__ g,
                            const float* __restrict__ bb, float* __restrict__ ss,
                            int C, float invN) {
    int c = blockIdx.x * blockDim.x + threadIdx.x;
    if (c >= C) return;
    float s1 = 0.f, s2 = 0.f;
    for (int k = 0; k < STAT_CHUNKS; ++k) {
        s1 += part[((size_t)c * STAT_CHUNKS + k) * 2 + 0];
        s2 += part[((size_t)c * STAT_CHUNKS + k) * 2 + 1];
    }
    float mean = s1 * invN;
    float var  = s2 * invN - mean * mean;
    float inv  = rsqrtf(var + EPS);
    float sc   = inv * g[c];
    ss[c]     = sc;
    ss[C + c] = bb[c] - mean * sc;
}

__global__ void bn_leaky_kernel(float* __restrict__ x, const float* __restrict__ ss,
                                int C, int HW, int total) {
    int idx = blockIdx.x * blockDim.x + threadIdx.x;
    if (idx >= total) return;
    int c = (idx / HW) % C;
    float v = x[idx] * ss[c] + ss[C + c];
    x[idx] = v >= 0.f ? v : SLOPE * v;
}

// ---------------- conv5 (2x2, s=1, p=0) + leaky ----------------
// in (64,256,2,24); w (1000,256,2,2); out (64,1000,23)
__global__ void conv5_leaky(const float* __restrict__ in, const float* __restrict__ w,
                            float* __restrict__ out) {
    int idx = blockIdx.x * blockDim.x + threadIdx.x;
    if (idx >= 64 * 1000 * 23) return;
    int j = idx % 23;
    int o = (idx / 23) % 1000;
    int b = idx / 23000;
    const float* ip = in + (size_t)b * 256 * 48;
    const float* wp = w + (size_t)o * 1024;
    float acc = 0.f;
    for (int ci = 0; ci < 256; ++ci) {
        const float* r  = ip + ci * 48;
        const float* wc = wp + ci * 4;
        acc = fmaf(r[j],      wc[0], acc);
        acc = fmaf(r[j + 1],  wc[1], acc);
        acc = fmaf(r[24 + j], wc[2], acc);
        acc = fmaf(r[25 + j], wc[3], acc);
    }
    out[idx] = acc >= 0.f ? acc : SLOPE * acc;
}

// ---------------- linear (1000->64) + sigmoid ----------------
// sub (64,1000,23); lw (64,1000); sig (64,64,23)
__global__ void linear_sig(const float* __restrict__ sub, const float* __restrict__ lw,
                           float* __restrict__ sig) {
    int idx = blockIdx.x * blockDim.x + threadIdx.x;
    if (idx >= 64 * 64 * 23) return;
    int j = idx % 23;
    int o = (idx / 23) % 64;
    int b = idx / (23 * 64);
    const float* sp = sub + (size_t)b * 23000 + j;
    const float* wp = lw + (size_t)o * 1000;
    float acc = 0.f;
    for (int c = 0; c < 1000; ++c) acc = fmaf(sp[(size_t)c * 23], wp[c], acc);
    sig[idx] = 1.f / (1.f + expf(-acc));
}

// ---------------- final interleave/shuffle ----------------
// sig (64,64,23) -> out (64, 24*32) with out[b, j*32+o] = small[b,o,j]
__global__ void shuffle_out_kernel(const float* __restrict__ sig, float* __restrict__ out) {
    int idx = blockIdx.x * blockDim.x + threadIdx.x;
    if (idx >= 64 * 768) return;
    int o = idx % 32;
    int j = (idx / 32) % 24;
    int b = idx / 768;
    const float* s = sig + (size_t)b * 64 * 23;
    float v;
    if (j == 0)       v = s[o * 23];
    else if (j == 23) v = s[(o + 32) * 23 + 22];
    else              v = 0.5f * (s[(o + 32) * 23 + (j - 1)] + s[o * 23 + j]);
    out[idx] = v;
}

extern "C" void kernel_launch(void* const* d_in, const int* in_sizes, int n_in,
                              void* d_out, int out_size, void* d_ws, size_t ws_size,
                              hipStream_t stream) {
    (void)in_sizes; (void)n_in; (void)out_size; (void)ws_size;

    const float* x = (const float*)d_in[0];
    const float* w[5]; const float* g[5]; const float* bb[5];
    for (int i = 0; i < 5; ++i) {
        w[i]  = (const float*)d_in[1 + 3 * i];
        g[i]  = (const float*)d_in[2 + 3 * i];
        bb[i] = (const float*)d_in[3 + 3 * i];
    }
    const float* w5 = (const float*)d_in[16];
    const float* lw = (const float*)d_in[17];
    float* out = (float*)d_out;

    float* ws   = (float*)d_ws;
    float* bufA = ws;                       // 12,582,912 floats
    float* bufB = ws + 12582912;            //  6,291,456 floats
    float* part = ws + 18874368;            //  8,192 floats
    float* ss   = part + 8192;              //  2,048 floats
    float* sub  = bufB;                     // (64,1000,23) fits in bufB
    float* sig  = bufA + 2097152;           // (64,64,23), clear of conv4 out

    const int Bn = 64;
    const int Ci[5] = {3, 16, 32, 64, 128};
    const int Co[5] = {16, 32, 64, 128, 256};
    const int Hi[5] = {64, 32, 16, 8, 4};
    const int Wi[5] = {768, 384, 192, 96, 48};

    const float* cur = x;
    float* dst = bufA;
    for (int L = 0; L < 5; ++L) {
        int Ho = Hi[L] / 2, Wo = Wi[L] / 2;
        int HW = Ho * Wo;
        int total = Bn * Co[L] * HW;
        hipLaunchKernelGGL(conv4x4s2_kernel, dim3((total + 255) / 256), dim3(256), 0, stream,
                           cur, w[L], dst, Bn, Ci[L], Co[L], Hi[L], Wi[L], Ho, Wo);
        hipLaunchKernelGGL(bn_stats_partial, dim3(Co[L] * STAT_CHUNKS), dim3(256), 0, stream,
                           dst, part, Bn, Co[L], HW);
        float invN = 1.f / (float)(Bn * HW);
        hipLaunchKernelGGL(bn_finalize, dim3((Co[L] + 255) / 256), dim3(256), 0, stream,
                           part, g[L], bb[L], ss, Co[L], invN);
        hipLaunchKernelGGL(bn_leaky_kernel, dim3((total + 255) / 256), dim3(256), 0, stream,
                           dst, ss, Co[L], HW, total);
        cur = dst;
        dst = (L % 2 == 0) ? bufB : bufA;
    }
    // conv4 output now in bufA (64,256,2,24)

    hipLaunchKernelGGL(conv5_leaky, dim3((64 * 1000 * 23 + 255) / 256), dim3(256), 0, stream,
                       bufA, w5, sub);
    hipLaunchKernelGGL(linear_sig, dim3((64 * 64 * 23 + 255) / 256), dim3(256), 0, stream,
                       sub, lw, sig);
    hipLaunchKernelGGL(shuffle_out_kernel, dim3((64 * 768 + 255) / 256), dim3(256), 0, stream,
                       sig, out);
}

// Round 3
// 1684.834 us; speedup vs baseline: 2.7891x; 2.7891x over previous
//
#include <hip/hip_runtime.h>
#include <cmath>

#define EPS 1e-5f
#define SLOPE 0.2f
#define STAT_CHUNKS 16

// ---------------- register-tiled direct 4x4 stride-2 pad-1 conv ----------------
// Each thread computes RC=4 co x RW=4 ow outputs for one (b, oh).
// Block = COG*OWG*OHG threads; COG = Co/4 (full channel coverage),
// TW = OWG*4 with Wo/TW = 6 for all layers; OHG rows of oh per block.
template <int Ci, int Co, int Hi, int Wi, int COG, int OHG>
__global__ __launch_bounds__(256) void conv_t(const float* __restrict__ in,
                                              const float* __restrict__ w,
                                              float* __restrict__ out) {
    constexpr int Ho = Hi / 2, Wo = Wi / 2;
    constexpr int OWG = 64 / COG;
    constexpr int TW = OWG * 4;
    constexpr int WT = Wo / TW;      // = 6 for all layers
    constexpr int OHT = Ho / OHG;

    int t = threadIdx.x;
    int owg = t % OWG;
    int cog = (t / OWG) % COG;
    int ohg = t / (OWG * COG);

    int blk = blockIdx.x;
    int wt = blk % WT;
    int rest = blk / WT;
    int ohb = rest % OHT;
    int b = rest / OHT;
    int oh = ohb * OHG + ohg;

    int ow0 = wt * TW + owg * 4;
    int co0 = cog * 4;
    int p = ow0 * 2 - 1;    // leftmost input column of the 10-wide window
    int ih0 = oh * 2 - 1;

    float acc[4][4];
#pragma unroll
    for (int i = 0; i < 4; ++i)
#pragma unroll
        for (int j = 0; j < 4; ++j) acc[i][j] = 0.f;

    const float* ip_base = in + (size_t)b * Ci * Hi * Wi;
    const float* wp_base = w + (size_t)co0 * Ci * 16;

    for (int ci = 0; ci < Ci; ++ci) {
        const float* ip = ip_base + (size_t)ci * Hi * Wi;
        const float* wp = wp_base + (size_t)ci * 16;
#pragma unroll
        for (int kh = 0; kh < 4; ++kh) {
            int ih = ih0 + kh;
            bool rv = (ih >= 0) && (ih < Hi);
            const float* row = ip + (size_t)ih * Wi;
            float xr[10];
#pragma unroll
            for (int k = 0; k < 10; ++k) {
                int iw = p + k;
                xr[k] = (rv && iw >= 0 && iw < Wi) ? row[iw] : 0.f;
            }
            float4 wv[4];
#pragma unroll
            for (int rc = 0; rc < 4; ++rc)
                wv[rc] = *(const float4*)(wp + (size_t)rc * Ci * 16 + kh * 4);
#pragma unroll
            for (int rc = 0; rc < 4; ++rc) {
#pragma unroll
                for (int rw = 0; rw < 4; ++rw) {
                    acc[rc][rw] = fmaf(xr[2 * rw + 0], wv[rc].x, acc[rc][rw]);
                    acc[rc][rw] = fmaf(xr[2 * rw + 1], wv[rc].y, acc[rc][rw]);
                    acc[rc][rw] = fmaf(xr[2 * rw + 2], wv[rc].z, acc[rc][rw]);
                    acc[rc][rw] = fmaf(xr[2 * rw + 3], wv[rc].w, acc[rc][rw]);
                }
            }
        }
    }

#pragma unroll
    for (int rc = 0; rc < 4; ++rc) {
        size_t base = ((size_t)b * Co + co0 + rc) * (Ho * Wo) + (size_t)oh * Wo + ow0;
#pragma unroll
        for (int rw = 0; rw < 4; ++rw) out[base + rw] = acc[rc][rw];
    }
}

// ---------------- BN stats: deterministic two-stage reduction ----------------
__global__ void bn_stats_partial(const float* __restrict__ x, float* __restrict__ part,
                                 int Bn, int C, int HW) {
    int c = blockIdx.x / STAT_CHUNKS;
    int chunk = blockIdx.x % STAT_CHUNKS;
    long N = (long)Bn * HW;
    long per = (N + STAT_CHUNKS - 1) / STAT_CHUNKS;
    long lo = (long)chunk * per;
    long hi = lo + per; if (hi > N) hi = N;
    double s1 = 0.0, s2 = 0.0;
    for (long i = lo + threadIdx.x; i < hi; i += blockDim.x) {
        int b = (int)(i / HW);
        int p = (int)(i % HW);
        float v = x[((size_t)b * C + c) * HW + p];
        s1 += v;
        s2 += (double)v * v;
    }
    __shared__ double sh1[256];
    __shared__ double sh2[256];
    int tid = threadIdx.x;
    sh1[tid] = s1; sh2[tid] = s2;
    __syncthreads();
    for (int s = 128; s > 0; s >>= 1) {
        if (tid < s) { sh1[tid] += sh1[tid + s]; sh2[tid] += sh2[tid + s]; }
        __syncthreads();
    }
    if (tid == 0) {
        part[((size_t)c * STAT_CHUNKS + chunk) * 2 + 0] = (float)sh1[0];
        part[((size_t)c * STAT_CHUNKS + chunk) * 2 + 1] = (float)sh2[0];
    }
}

__global__ void bn_finalize(const float* __restrict__ part, const float* __restrict__ g,
                            const float* __restrict__ bb, float* __restrict__ ss,
                            int C, float invN) {
    int c = blockIdx.x * blockDim.x + threadIdx.x;
    if (c >= C) return;
    float s1 = 0.f, s2 = 0.f;
    for (int k = 0; k < STAT_CHUNKS; ++k) {
        s1 += part[((size_t)c * STAT_CHUNKS + k) * 2 + 0];
        s2 += part[((size_t)c * STAT_CHUNKS + k) * 2 + 1];
    }
    float mean = s1 * invN;
    float var  = s2 * invN - mean * mean;
    float inv  = rsqrtf(var + EPS);
    float sc   = inv * g[c];
    ss[c]     = sc;
    ss[C + c] = bb[c] - mean * sc;
}

// float4 BN-apply + leaky (HW is a multiple of 4 for every layer)
__global__ void bn_leaky4(float* __restrict__ x, const float* __restrict__ ss,
                          int C, int HW4, int total4) {
    int idx = blockIdx.x * blockDim.x + threadIdx.x;
    if (idx >= total4) return;
    int c = (idx / HW4) % C;
    float sc = ss[c], sh = ss[C + c];
    float4 v = ((float4*)x)[idx];
    v.x = v.x * sc + sh; v.x = v.x >= 0.f ? v.x : SLOPE * v.x;
    v.y = v.y * sc + sh; v.y = v.y >= 0.f ? v.y : SLOPE * v.y;
    v.z = v.z * sc + sh; v.z = v.z >= 0.f ? v.z : SLOPE * v.z;
    v.w = v.w * sc + sh; v.w = v.w >= 0.f ? v.w : SLOPE * v.w;
    ((float4*)x)[idx] = v;
}

// ---------------- conv5 (2x2, s=1, p=0) + leaky ----------------
// in (64,256,2,24); w (1000,256,2,2); out (64,1000,23)
// thread = (b,o), computes all 23 j. Input loads uniform across lanes (same b).
__global__ __launch_bounds__(256) void conv5_leaky_v2(const float* __restrict__ in,
                                                      const float* __restrict__ w5,
                                                      float* __restrict__ out) {
    int idx = blockIdx.x * blockDim.x + threadIdx.x;
    if (idx >= 64000) return;
    int o = idx % 1000;
    int b = idx / 1000;

    float acc[23];
#pragma unroll
    for (int j = 0; j < 23; ++j) acc[j] = 0.f;

    const float* ip = in + (size_t)b * 256 * 48;
    const float* wp = w5 + (size_t)o * 1024;

    for (int ci = 0; ci < 256; ++ci) {
        float4 wv = *(const float4*)(wp + ci * 4);
        float4 r4[12];
        const float4* rp = (const float4*)(ip + ci * 48);
#pragma unroll
        for (int q = 0; q < 12; ++q) r4[q] = rp[q];
        float v[48];
#pragma unroll
        for (int q = 0; q < 12; ++q) {
            v[4 * q + 0] = r4[q].x; v[4 * q + 1] = r4[q].y;
            v[4 * q + 2] = r4[q].z; v[4 * q + 3] = r4[q].w;
        }
#pragma unroll
        for (int j = 0; j < 23; ++j) {
            acc[j] = fmaf(v[j],      wv.x, acc[j]);
            acc[j] = fmaf(v[j + 1],  wv.y, acc[j]);
            acc[j] = fmaf(v[24 + j], wv.z, acc[j]);
            acc[j] = fmaf(v[25 + j], wv.w, acc[j]);
        }
    }
    size_t base = (size_t)idx * 23;
#pragma unroll
    for (int j = 0; j < 23; ++j) {
        float a = acc[j];
        out[base + j] = a >= 0.f ? a : SLOPE * a;
    }
}

// ---------------- linear (1000->64) + sigmoid ----------------
__global__ void linear_sig(const float* __restrict__ sub, const float* __restrict__ lw,
                           float* __restrict__ sig) {
    int idx = blockIdx.x * blockDim.x + threadIdx.x;
    if (idx >= 64 * 64 * 23) return;
    int j = idx % 23;
    int o = (idx / 23) % 64;
    int b = idx / (23 * 64);
    const float* sp = sub + (size_t)b * 23000 + j;
    const float* wp = lw + (size_t)o * 1000;
    float a0 = 0.f, a1 = 0.f, a2 = 0.f, a3 = 0.f;
    for (int c = 0; c < 1000; c += 4) {
        a0 = fmaf(sp[(size_t)(c + 0) * 23], wp[c + 0], a0);
        a1 = fmaf(sp[(size_t)(c + 1) * 23], wp[c + 1], a1);
        a2 = fmaf(sp[(size_t)(c + 2) * 23], wp[c + 2], a2);
        a3 = fmaf(sp[(size_t)(c + 3) * 23], wp[c + 3], a3);
    }
    float acc = (a0 + a1) + (a2 + a3);
    sig[idx] = 1.f / (1.f + expf(-acc));
}

// ---------------- final interleave/shuffle ----------------
__global__ void shuffle_out_kernel(const float* __restrict__ sig, float* __restrict__ out) {
    int idx = blockIdx.x * blockDim.x + threadIdx.x;
    if (idx >= 64 * 768) return;
    int o = idx % 32;
    int j = (idx / 32) % 24;
    int b = idx / 768;
    const float* s = sig + (size_t)b * 64 * 23;
    float v;
    if (j == 0)       v = s[o * 23];
    else if (j == 23) v = s[(o + 32) * 23 + 22];
    else              v = 0.5f * (s[(o + 32) * 23 + (j - 1)] + s[o * 23 + j]);
    out[idx] = v;
}

extern "C" void kernel_launch(void* const* d_in, const int* in_sizes, int n_in,
                              void* d_out, int out_size, void* d_ws, size_t ws_size,
                              hipStream_t stream) {
    (void)in_sizes; (void)n_in; (void)out_size; (void)ws_size;

    const float* x = (const float*)d_in[0];
    const float* w[5]; const float* g[5]; const float* bb[5];
    for (int i = 0; i < 5; ++i) {
        w[i]  = (const float*)d_in[1 + 3 * i];
        g[i]  = (const float*)d_in[2 + 3 * i];
        bb[i] = (const float*)d_in[3 + 3 * i];
    }
    const float* w5 = (const float*)d_in[16];
    const float* lw = (const float*)d_in[17];
    float* out = (float*)d_out;

    float* ws   = (float*)d_ws;
    float* bufA = ws;                       // 12,582,912 floats
    float* bufB = ws + 12582912;            //  6,291,456 floats
    float* part = ws + 18874368;            //  8,192 floats
    float* ss   = part + 8192;              //  2,048 floats
    float* sub  = bufB;                     // (64,1000,23)
    float* sig  = bufA + 2097152;           // (64,64,23)

    const int Bn = 64;
    const int Co[5] = {16, 32, 64, 128, 256};
    const int Hi[5] = {64, 32, 16, 8, 4};
    const int Wi[5] = {768, 384, 192, 96, 48};
    // threads/block = (64/COG)*COG*OHG = 64*OHG; OHG: L0-L3 -> 4 (256 thr), L4 -> 2 (128 thr)
    const int OHGs[5] = {4, 4, 4, 4, 2};

    const float* cur = x;
    float* dst = bufA;
    for (int L = 0; L < 5; ++L) {
        int Ho = Hi[L] / 2, Wo = Wi[L] / 2;
        int HW = Ho * Wo;
        int total = Bn * Co[L] * HW;
        int grid = Bn * (Ho / OHGs[L]) * 6;   // Wo/TW = 6 for every layer
        int thr = 64 * OHGs[L];
        switch (L) {
            case 0: hipLaunchKernelGGL((conv_t<3,   16,  64, 768, 4,  4>), dim3(grid), dim3(thr), 0, stream, cur, w[L], dst); break;
            case 1: hipLaunchKernelGGL((conv_t<16,  32,  32, 384, 8,  4>), dim3(grid), dim3(thr), 0, stream, cur, w[L], dst); break;
            case 2: hipLaunchKernelGGL((conv_t<32,  64,  16, 192, 16, 4>), dim3(grid), dim3(thr), 0, stream, cur, w[L], dst); break;
            case 3: hipLaunchKernelGGL((conv_t<64,  128, 8,  96,  32, 4>), dim3(grid), dim3(thr), 0, stream, cur, w[L], dst); break;
            case 4: hipLaunchKernelGGL((conv_t<128, 256, 4,  48,  64, 2>), dim3(grid), dim3(thr), 0, stream, cur, w[L], dst); break;
        }
        hipLaunchKernelGGL(bn_stats_partial, dim3(Co[L] * STAT_CHUNKS), dim3(256), 0, stream,
                           dst, part, Bn, Co[L], HW);
        float invN = 1.f / (float)(Bn * HW);
        hipLaunchKernelGGL(bn_finalize, dim3((Co[L] + 255) / 256), dim3(256), 0, stream,
                           part, g[L], bb[L], ss, Co[L], invN);
        hipLaunchKernelGGL(bn_leaky4, dim3((total / 4 + 255) / 256), dim3(256), 0, stream,
                           dst, ss, Co[L], HW / 4, total / 4);
        cur = dst;
        dst = (L % 2 == 0) ? bufB : bufA;
    }
    // layer-4 activation now in bufA (64,256,2,24)

    hipLaunchKernelGGL(conv5_leaky_v2, dim3(250), dim3(256), 0, stream, bufA, w5, sub);
    hipLaunchKernelGGL(linear_sig, dim3((64 * 64 * 23 + 255) / 256), dim3(256), 0, stream,
                       sub, lw, sig);
    hipLaunchKernelGGL(shuffle_out_kernel, dim3((64 * 768 + 255) / 256), dim3(256), 0, stream,
                       sig, out);
}

// Round 4
// 1528.936 us; speedup vs baseline: 3.0735x; 1.1020x over previous
//
#include <hip/hip_runtime.h>
#include <cmath>

#define EPS 1e-5f
#define SLOPE 0.2f
#define STAT_CHUNKS 16

// ---------------- register-tiled direct 4x4 stride-2 pad-1 conv, K-split ----------------
// Each thread computes 4co x 4ow outputs for one (b, oh), over ci chunk p (blockIdx.y).
// Block = COG*OWG*OHG threads; COG = Co/4, TW = OWG*4 (Wo/TW = 6 all layers).
// P>1: writes partial plane p at out + p*TOT (reduced by reduceP_k afterwards).
template <int Ci, int Co, int Hi, int Wi, int COG, int OHG, int P>
__global__ __launch_bounds__(256) void conv_t(const float* __restrict__ in,
                                              const float* __restrict__ w,
                                              float* __restrict__ out) {
    constexpr int Ho = Hi / 2, Wo = Wi / 2;
    constexpr int OWG = 64 / COG;
    constexpr int TW = OWG * 4;
    constexpr int WT = Wo / TW;      // = 6 for all layers
    constexpr int OHT = Ho / OHG;
    constexpr int CIP = Ci / P;
    constexpr size_t TOT = (size_t)64 * Co * Ho * Wo;

    int t = threadIdx.x;
    int owg = t % OWG;
    int cog = (t / OWG) % COG;
    int ohg = t / (OWG * COG);

    int blk = blockIdx.x;
    int p = blockIdx.y;
    int wt = blk % WT;
    int rest = blk / WT;
    int ohb = rest % OHT;
    int b = rest / OHT;
    int oh = ohb * OHG + ohg;

    int ow0 = wt * TW + owg * 4;
    int co0 = cog * 4;
    int pcol = ow0 * 2 - 1;    // leftmost input column of the 10-wide window
    int ih0 = oh * 2 - 1;

    float acc[4][4];
#pragma unroll
    for (int i = 0; i < 4; ++i)
#pragma unroll
        for (int j = 0; j < 4; ++j) acc[i][j] = 0.f;

    const float* ip_base = in + (size_t)b * Ci * Hi * Wi;
    const float* wp_base = w + (size_t)co0 * Ci * 16;

    int ci0 = p * CIP;
    for (int ci = ci0; ci < ci0 + CIP; ++ci) {
        const float* ip = ip_base + (size_t)ci * Hi * Wi;
        const float* wp = wp_base + (size_t)ci * 16;
#pragma unroll
        for (int kh = 0; kh < 4; ++kh) {
            int ih = ih0 + kh;
            bool rv = (ih >= 0) && (ih < Hi);
            const float* row = ip + (size_t)ih * Wi;
            float xr[10];
#pragma unroll
            for (int k = 0; k < 10; ++k) {
                int iw = pcol + k;
                xr[k] = (rv && iw >= 0 && iw < Wi) ? row[iw] : 0.f;
            }
            float4 wv[4];
#pragma unroll
            for (int rc = 0; rc < 4; ++rc)
                wv[rc] = *(const float4*)(wp + (size_t)rc * Ci * 16 + kh * 4);
#pragma unroll
            for (int rc = 0; rc < 4; ++rc) {
#pragma unroll
                for (int rw = 0; rw < 4; ++rw) {
                    acc[rc][rw] = fmaf(xr[2 * rw + 0], wv[rc].x, acc[rc][rw]);
                    acc[rc][rw] = fmaf(xr[2 * rw + 1], wv[rc].y, acc[rc][rw]);
                    acc[rc][rw] = fmaf(xr[2 * rw + 2], wv[rc].z, acc[rc][rw]);
                    acc[rc][rw] = fmaf(xr[2 * rw + 3], wv[rc].w, acc[rc][rw]);
                }
            }
        }
    }

    float* op = out + (size_t)p * TOT;
#pragma unroll
    for (int rc = 0; rc < 4; ++rc) {
        size_t base = ((size_t)b * Co + co0 + rc) * (Ho * Wo) + (size_t)oh * Wo + ow0;
#pragma unroll
        for (int rw = 0; rw < 4; ++rw) op[base + rw] = acc[rc][rw];
    }
}

// ---------------- partial-plane reduction (+fused activation) ----------------
// MODE: 0 = none, 1 = leaky, 2 = sigmoid. Deterministic fixed p order.
template <int MODE>
__global__ void reduceP_k(const float* __restrict__ pin, float* __restrict__ out,
                          int tot4, int P) {
    int idx = blockIdx.x * blockDim.x + threadIdx.x;
    if (idx >= tot4) return;
    const float4* p4 = (const float4*)pin;
    float4 a = p4[idx];
    for (int p = 1; p < P; ++p) {
        float4 v = p4[(size_t)p * tot4 + idx];
        a.x += v.x; a.y += v.y; a.z += v.z; a.w += v.w;
    }
    if (MODE == 1) {
        a.x = a.x >= 0.f ? a.x : SLOPE * a.x;
        a.y = a.y >= 0.f ? a.y : SLOPE * a.y;
        a.z = a.z >= 0.f ? a.z : SLOPE * a.z;
        a.w = a.w >= 0.f ? a.w : SLOPE * a.w;
    } else if (MODE == 2) {
        a.x = 1.f / (1.f + expf(-a.x));
        a.y = 1.f / (1.f + expf(-a.y));
        a.z = 1.f / (1.f + expf(-a.z));
        a.w = 1.f / (1.f + expf(-a.w));
    }
    ((float4*)out)[idx] = a;
}

// ---------------- BN stats: deterministic two-stage reduction ----------------
__global__ void bn_stats_partial(const float* __restrict__ x, float* __restrict__ part,
                                 int Bn, int C, int HW) {
    int c = blockIdx.x / STAT_CHUNKS;
    int chunk = blockIdx.x % STAT_CHUNKS;
    long N = (long)Bn * HW;
    long per = (N + STAT_CHUNKS - 1) / STAT_CHUNKS;
    long lo = (long)chunk * per;
    long hi = lo + per; if (hi > N) hi = N;
    double s1 = 0.0, s2 = 0.0;
    for (long i = lo + threadIdx.x; i < hi; i += blockDim.x) {
        int b = (int)(i / HW);
        int p = (int)(i % HW);
        float v = x[((size_t)b * C + c) * HW + p];
        s1 += v;
        s2 += (double)v * v;
    }
    __shared__ double sh1[256];
    __shared__ double sh2[256];
    int tid = threadIdx.x;
    sh1[tid] = s1; sh2[tid] = s2;
    __syncthreads();
    for (int s = 128; s > 0; s >>= 1) {
        if (tid < s) { sh1[tid] += sh1[tid + s]; sh2[tid] += sh2[tid + s]; }
        __syncthreads();
    }
    if (tid == 0) {
        part[((size_t)c * STAT_CHUNKS + chunk) * 2 + 0] = (float)sh1[0];
        part[((size_t)c * STAT_CHUNKS + chunk) * 2 + 1] = (float)sh2[0];
    }
}

__global__ void bn_finalize(const float* __restrict__ part, const float* __restrict__ g,
                            const float* __restrict__ bb, float* __restrict__ ss,
                            int C, float invN) {
    int c = blockIdx.x * blockDim.x + threadIdx.x;
    if (c >= C) return;
    float s1 = 0.f, s2 = 0.f;
    for (int k = 0; k < STAT_CHUNKS; ++k) {
        s1 += part[((size_t)c * STAT_CHUNKS + k) * 2 + 0];
        s2 += part[((size_t)c * STAT_CHUNKS + k) * 2 + 1];
    }
    float mean = s1 * invN;
    float var  = s2 * invN - mean * mean;
    float inv  = rsqrtf(var + EPS);
    float sc   = inv * g[c];
    ss[c]     = sc;
    ss[C + c] = bb[c] - mean * sc;
}

// float4 BN-apply + leaky
__global__ void bn_leaky4(float* __restrict__ x, const float* __restrict__ ss,
                          int C, int HW4, int total4) {
    int idx = blockIdx.x * blockDim.x + threadIdx.x;
    if (idx >= total4) return;
    int c = (idx / HW4) % C;
    float sc = ss[c], sh = ss[C + c];
    float4 v = ((float4*)x)[idx];
    v.x = v.x * sc + sh; v.x = v.x >= 0.f ? v.x : SLOPE * v.x;
    v.y = v.y * sc + sh; v.y = v.y >= 0.f ? v.y : SLOPE * v.y;
    v.z = v.z * sc + sh; v.z = v.z >= 0.f ? v.z : SLOPE * v.z;
    v.w = v.w * sc + sh; v.w = v.w >= 0.f ? v.w : SLOPE * v.w;
    ((float4*)x)[idx] = v;
}

// ---------------- conv5 (2x2, s=1, p=0), K-split partials ----------------
// in (64,256,2,24); w (1000,256,2,2); pout[p] (64,1000,23); p over 8 chunks of 32 ci.
__global__ __launch_bounds__(256) void conv5_part(const float* __restrict__ in,
                                                  const float* __restrict__ w5,
                                                  float* __restrict__ pout) {
    int idx = blockIdx.x * blockDim.x + threadIdx.x;
    if (idx >= 64000) return;
    int p = blockIdx.y;
    int o = idx % 1000;
    int b = idx / 1000;

    float acc[23];
#pragma unroll
    for (int j = 0; j < 23; ++j) acc[j] = 0.f;

    const float* ip = in + (size_t)b * 256 * 48 + (size_t)p * 32 * 48;
    const float* wp = w5 + (size_t)o * 1024 + (size_t)p * 32 * 4;

    for (int ci = 0; ci < 32; ++ci) {
        float4 wv = *(const float4*)(wp + ci * 4);
        float4 r4[12];
        const float4* rp = (const float4*)(ip + ci * 48);
#pragma unroll
        for (int q = 0; q < 12; ++q) r4[q] = rp[q];
        float v[48];
#pragma unroll
        for (int q = 0; q < 12; ++q) {
            v[4 * q + 0] = r4[q].x; v[4 * q + 1] = r4[q].y;
            v[4 * q + 2] = r4[q].z; v[4 * q + 3] = r4[q].w;
        }
#pragma unroll
        for (int j = 0; j < 23; ++j) {
            acc[j] = fmaf(v[j],      wv.x, acc[j]);
            acc[j] = fmaf(v[j + 1],  wv.y, acc[j]);
            acc[j] = fmaf(v[24 + j], wv.z, acc[j]);
            acc[j] = fmaf(v[25 + j], wv.w, acc[j]);
        }
    }
    float* op = pout + (size_t)p * 1472000 + (size_t)idx * 23;
#pragma unroll
    for (int j = 0; j < 23; ++j) op[j] = acc[j];
}

// ---------------- linear (1000->64), K-split partials ----------------
// sub (64,1000,23); lw (64,1000); pout[p] (64,64,23); p over 8 chunks of 125 c.
__global__ void linear_part(const float* __restrict__ sub, const float* __restrict__ lw,
                            float* __restrict__ pout) {
    int idx = blockIdx.x * blockDim.x + threadIdx.x;
    if (idx >= 64 * 64 * 23) return;
    int p = blockIdx.y;
    int j = idx % 23;
    int o = (idx / 23) % 64;
    int b = idx / (23 * 64);
    const float* sp = sub + (size_t)b * 23000 + j;
    const float* wp = lw + (size_t)o * 1000;
    int c0 = p * 125;
    float a0 = 0.f, a1 = 0.f, a2 = 0.f, a3 = 0.f, a4 = 0.f;
    for (int c = c0; c < c0 + 125; c += 5) {
        a0 = fmaf(sp[(size_t)(c + 0) * 23], wp[c + 0], a0);
        a1 = fmaf(sp[(size_t)(c + 1) * 23], wp[c + 1], a1);
        a2 = fmaf(sp[(size_t)(c + 2) * 23], wp[c + 2], a2);
        a3 = fmaf(sp[(size_t)(c + 3) * 23], wp[c + 3], a3);
        a4 = fmaf(sp[(size_t)(c + 4) * 23], wp[c + 4], a4);
    }
    pout[(size_t)p * 94208 + idx] = ((a0 + a1) + (a2 + a3)) + a4;
}

// ---------------- final interleave/shuffle ----------------
__global__ void shuffle_out_kernel(const float* __restrict__ sig, float* __restrict__ out) {
    int idx = blockIdx.x * blockDim.x + threadIdx.x;
    if (idx >= 64 * 768) return;
    int o = idx % 32;
    int j = (idx / 32) % 24;
    int b = idx / 768;
    const float* s = sig + (size_t)b * 64 * 23;
    float v;
    if (j == 0)       v = s[o * 23];
    else if (j == 23) v = s[(o + 32) * 23 + 22];
    else              v = 0.5f * (s[(o + 32) * 23 + (j - 1)] + s[o * 23 + j]);
    out[idx] = v;
}

extern "C" void kernel_launch(void* const* d_in, const int* in_sizes, int n_in,
                              void* d_out, int out_size, void* d_ws, size_t ws_size,
                              hipStream_t stream) {
    (void)in_sizes; (void)n_in; (void)out_size; (void)ws_size;

    const float* x = (const float*)d_in[0];
    const float* w[5]; const float* g[5]; const float* bb[5];
    for (int i = 0; i < 5; ++i) {
        w[i]  = (const float*)d_in[1 + 3 * i];
        g[i]  = (const float*)d_in[2 + 3 * i];
        bb[i] = (const float*)d_in[3 + 3 * i];
    }
    const float* w5 = (const float*)d_in[16];
    const float* lw = (const float*)d_in[17];
    float* out = (float*)d_out;

    float* ws   = (float*)d_ws;
    float* bufA = ws;                       // 12,582,912 floats
    float* bufB = ws + 12582912;            //  6,291,456 floats
    float* part = ws + 18874368;            //  8,192 floats
    float* ss   = part + 8192;              //  2,048 floats
    // partial-sum scratch (overlapped with dead regions, see analysis):
    float* pbufC = bufA + 6291456;          // conv L2/L3/L4 partials (6,291,456 floats)
    float* pbuf5 = bufA + 786432;           // conv5 partials (11,776,000 floats, ends 12,562,432)
    float* sub   = bufB;                    // (64,1000,23) = 1,472,000
    float* pbufL = bufB + 2097152;          // linear partials (753,664 floats)
    float* sig   = bufB + 4194304;          // (64,64,23) = 94,208

    const int Bn = 64;
    const int Co[5] = {16, 32, 64, 128, 256};
    const int Hi[5] = {64, 32, 16, 8, 4};
    const int Wi[5] = {768, 384, 192, 96, 48};
    const int OHGs[5] = {4, 4, 4, 4, 2};
    const int Ps[5]   = {1, 1, 2, 4, 8};

    const float* cur = x;
    float* dst = bufA;
    for (int L = 0; L < 5; ++L) {
        int Ho = Hi[L] / 2, Wo = Wi[L] / 2;
        int HW = Ho * Wo;
        int total = Bn * Co[L] * HW;
        int SB = Bn * (Ho / OHGs[L]) * 6;   // Wo/TW = 6 for every layer
        int thr = 64 * OHGs[L];
        float* cdst = (Ps[L] == 1) ? dst : pbufC;
        switch (L) {
            case 0: hipLaunchKernelGGL((conv_t<3,   16,  64, 768, 4,  4, 1>), dim3(SB, 1), dim3(thr), 0, stream, cur, w[L], cdst); break;
            case 1: hipLaunchKernelGGL((conv_t<16,  32,  32, 384, 8,  4, 1>), dim3(SB, 1), dim3(thr), 0, stream, cur, w[L], cdst); break;
            case 2: hipLaunchKernelGGL((conv_t<32,  64,  16, 192, 16, 4, 2>), dim3(SB, 2), dim3(thr), 0, stream, cur, w[L], cdst); break;
            case 3: hipLaunchKernelGGL((conv_t<64,  128, 8,  96,  32, 4, 4>), dim3(SB, 4), dim3(thr), 0, stream, cur, w[L], cdst); break;
            case 4: hipLaunchKernelGGL((conv_t<128, 256, 4,  48,  64, 2, 8>), dim3(SB, 8), dim3(thr), 0, stream, cur, w[L], cdst); break;
        }
        if (Ps[L] > 1) {
            int tot4 = total / 4;
            hipLaunchKernelGGL(reduceP_k<0>, dim3((tot4 + 255) / 256), dim3(256), 0, stream,
                               pbufC, dst, tot4, Ps[L]);
        }
        hipLaunchKernelGGL(bn_stats_partial, dim3(Co[L] * STAT_CHUNKS), dim3(256), 0, stream,
                           dst, part, Bn, Co[L], HW);
        float invN = 1.f / (float)(Bn * HW);
        hipLaunchKernelGGL(bn_finalize, dim3((Co[L] + 255) / 256), dim3(256), 0, stream,
                           part, g[L], bb[L], ss, Co[L], invN);
        hipLaunchKernelGGL(bn_leaky4, dim3((total / 4 + 255) / 256), dim3(256), 0, stream,
                           dst, ss, Co[L], HW / 4, total / 4);
        cur = dst;
        dst = (L % 2 == 0) ? bufB : bufA;
    }
    // layer-4 activation now in bufA[0..786432) (64,256,2,24)

    hipLaunchKernelGGL(conv5_part, dim3(250, 8), dim3(256), 0, stream, bufA, w5, pbuf5);
    hipLaunchKernelGGL(reduceP_k<1>, dim3((368000 + 255) / 256), dim3(256), 0, stream,
                       pbuf5, sub, 368000, 8);
    hipLaunchKernelGGL(linear_part, dim3(368, 8), dim3(256), 0, stream, sub, lw, pbufL);
    hipLaunchKernelGGL(reduceP_k<2>, dim3((23552 + 255) / 256), dim3(256), 0, stream,
                       pbufL, sig, 23552, 8);
    hipLaunchKernelGGL(shuffle_out_kernel, dim3((64 * 768 + 255) / 256), dim3(256), 0, stream,
                       sig, out);
}

// Round 5
// 818.952 us; speedup vs baseline: 5.7380x; 1.8669x over previous
//
#include <hip/hip_runtime.h>
#include <cmath>

#define EPS 1e-5f
#define SLOPE 0.2f
#define STAT_CHUNKS 16

// ---------------- spatial-lane direct 4x4 stride-2 pad-1 conv ----------------
// Lanes = spatial positions (b,oh,ow) -> coalesced input loads.
// blockIdx.y = co-tile (x K-chunk): weight addresses are wave-uniform -> 1 line/load.
// Each thread: COT=8 co accumulators, 16 input regs reused across all 8 co.
// P>1: writes partial plane p at out + p*TOT (reduced by reduceP_k).
template <int Ci, int Co, int Hi, int Wi, int P>
__global__ __launch_bounds__(256) void conv_s(const float* __restrict__ in,
                                              const float* __restrict__ w,
                                              float* __restrict__ out) {
    constexpr int Ho = Hi / 2, Wo = Wi / 2;
    constexpr int COT = 8;
    constexpr int CT = Co / COT;
    constexpr int CIP = Ci / P;
    constexpr size_t TOT = (size_t)64 * Co * Ho * Wo;

    int s = blockIdx.x * 256 + threadIdx.x;
    int ct = blockIdx.y % CT;
    int p  = blockIdx.y / CT;
    int ow = s % Wo;
    int t  = s / Wo;
    int oh = t % Ho;
    int b  = t / Ho;
    int co0 = ct * COT;
    int ih0 = oh * 2 - 1;
    int iw0 = ow * 2 - 1;

    // precompute clamped offsets + 0/1 masks for the 4x4 window (ci-independent)
    int offs[16];
    float msk[16];
#pragma unroll
    for (int kh = 0; kh < 4; ++kh) {
        int ih = ih0 + kh;
        bool rv = (ih >= 0) && (ih < Hi);
        int ihc = ih < 0 ? 0 : (ih >= Hi ? Hi - 1 : ih);
#pragma unroll
        for (int kw = 0; kw < 4; ++kw) {
            int iw = iw0 + kw;
            bool cv = rv && (iw >= 0) && (iw < Wi);
            int iwc = iw < 0 ? 0 : (iw >= Wi ? Wi - 1 : iw);
            offs[kh * 4 + kw] = ihc * Wi + iwc;
            msk[kh * 4 + kw] = cv ? 1.f : 0.f;
        }
    }

    float acc[COT];
#pragma unroll
    for (int u = 0; u < COT; ++u) acc[u] = 0.f;

    const float* ip = in + (size_t)b * Ci * Hi * Wi;
    int ci0 = p * CIP;
    for (int ci = ci0; ci < ci0 + CIP; ++ci) {
        const float* pc = ip + (size_t)ci * Hi * Wi;
        float xv[16];
#pragma unroll
        for (int k = 0; k < 16; ++k) xv[k] = pc[offs[k]] * msk[k];
#pragma unroll
        for (int u = 0; u < COT; ++u) {
            const float* wp = w + ((size_t)(co0 + u) * Ci + ci) * 16;  // wave-uniform
#pragma unroll
            for (int k = 0; k < 16; ++k) acc[u] = fmaf(xv[k], wp[k], acc[u]);
        }
    }

    float* op = out + (size_t)p * TOT;
#pragma unroll
    for (int u = 0; u < COT; ++u)
        op[((size_t)b * Co + co0 + u) * (Ho * Wo) + (size_t)oh * Wo + ow] = acc[u];
}

// ---------------- partial-plane reduction (+fused activation) ----------------
// MODE: 0 = none, 1 = leaky, 2 = sigmoid. Deterministic fixed p order.
template <int MODE>
__global__ void reduceP_k(const float* __restrict__ pin, float* __restrict__ out,
                          int tot4, int P) {
    int idx = blockIdx.x * blockDim.x + threadIdx.x;
    if (idx >= tot4) return;
    const float4* p4 = (const float4*)pin;
    float4 a = p4[idx];
    for (int p = 1; p < P; ++p) {
        float4 v = p4[(size_t)p * tot4 + idx];
        a.x += v.x; a.y += v.y; a.z += v.z; a.w += v.w;
    }
    if (MODE == 1) {
        a.x = a.x >= 0.f ? a.x : SLOPE * a.x;
        a.y = a.y >= 0.f ? a.y : SLOPE * a.y;
        a.z = a.z >= 0.f ? a.z : SLOPE * a.z;
        a.w = a.w >= 0.f ? a.w : SLOPE * a.w;
    } else if (MODE == 2) {
        a.x = 1.f / (1.f + expf(-a.x));
        a.y = 1.f / (1.f + expf(-a.y));
        a.z = 1.f / (1.f + expf(-a.z));
        a.w = 1.f / (1.f + expf(-a.w));
    }
    ((float4*)out)[idx] = a;
}

// ---------------- BN stats: deterministic two-stage reduction ----------------
__global__ void bn_stats_partial(const float* __restrict__ x, float* __restrict__ part,
                                 int Bn, int C, int HW) {
    int c = blockIdx.x / STAT_CHUNKS;
    int chunk = blockIdx.x % STAT_CHUNKS;
    long N = (long)Bn * HW;
    long per = (N + STAT_CHUNKS - 1) / STAT_CHUNKS;
    long lo = (long)chunk * per;
    long hi = lo + per; if (hi > N) hi = N;
    double s1 = 0.0, s2 = 0.0;
    for (long i = lo + threadIdx.x; i < hi; i += blockDim.x) {
        int b = (int)(i / HW);
        int p = (int)(i % HW);
        float v = x[((size_t)b * C + c) * HW + p];
        s1 += v;
        s2 += (double)v * v;
    }
    __shared__ double sh1[256];
    __shared__ double sh2[256];
    int tid = threadIdx.x;
    sh1[tid] = s1; sh2[tid] = s2;
    __syncthreads();
    for (int s = 128; s > 0; s >>= 1) {
        if (tid < s) { sh1[tid] += sh1[tid + s]; sh2[tid] += sh2[tid + s]; }
        __syncthreads();
    }
    if (tid == 0) {
        part[((size_t)c * STAT_CHUNKS + chunk) * 2 + 0] = (float)sh1[0];
        part[((size_t)c * STAT_CHUNKS + chunk) * 2 + 1] = (float)sh2[0];
    }
}

__global__ void bn_finalize(const float* __restrict__ part, const float* __restrict__ g,
                            const float* __restrict__ bb, float* __restrict__ ss,
                            int C, float invN) {
    int c = blockIdx.x * blockDim.x + threadIdx.x;
    if (c >= C) return;
    float s1 = 0.f, s2 = 0.f;
    for (int k = 0; k < STAT_CHUNKS; ++k) {
        s1 += part[((size_t)c * STAT_CHUNKS + k) * 2 + 0];
        s2 += part[((size_t)c * STAT_CHUNKS + k) * 2 + 1];
    }
    float mean = s1 * invN;
    float var  = s2 * invN - mean * mean;
    float inv  = rsqrtf(var + EPS);
    float sc   = inv * g[c];
    ss[c]     = sc;
    ss[C + c] = bb[c] - mean * sc;
}

// float4 BN-apply + leaky
__global__ void bn_leaky4(float* __restrict__ x, const float* __restrict__ ss,
                          int C, int HW4, int total4) {
    int idx = blockIdx.x * blockDim.x + threadIdx.x;
    if (idx >= total4) return;
    int c = (idx / HW4) % C;
    float sc = ss[c], sh = ss[C + c];
    float4 v = ((float4*)x)[idx];
    v.x = v.x * sc + sh; v.x = v.x >= 0.f ? v.x : SLOPE * v.x;
    v.y = v.y * sc + sh; v.y = v.y >= 0.f ? v.y : SLOPE * v.y;
    v.z = v.z * sc + sh; v.z = v.z >= 0.f ? v.z : SLOPE * v.z;
    v.w = v.w * sc + sh; v.w = v.w >= 0.f ? v.w : SLOPE * v.w;
    ((float4*)x)[idx] = v;
}

// ---------------- conv5 (2x2, s=1, p=0) + leaky, spatial-lane ----------------
// in (64,256,2,24); w (1000,256,2,2); out (64,1000,23).
// Lane = (b,j) spatial (j padded to 24); blockIdx.y = o-tile of 8 (uniform weights).
__global__ __launch_bounds__(256) void conv5_s(const float* __restrict__ in,
                                               const float* __restrict__ w5,
                                               float* __restrict__ out) {
    int s = blockIdx.x * 256 + threadIdx.x;  // 0..1535
    int j = s % 24;
    int b = s / 24;
    int o0 = blockIdx.y * 8;
    bool jv = j < 23;
    int jc = jv ? j : 22;

    float acc[8];
#pragma unroll
    for (int u = 0; u < 8; ++u) acc[u] = 0.f;

    const float* ip = in + (size_t)b * 12288;
    for (int ci = 0; ci < 256; ++ci) {
        const float* r = ip + ci * 48;
        float v0 = r[jc], v1 = r[jc + 1], v2 = r[24 + jc], v3 = r[25 + jc];
#pragma unroll
        for (int u = 0; u < 8; ++u) {
            const float* wp = w5 + ((size_t)(o0 + u) * 256 + ci) * 4;  // wave-uniform
            acc[u] = fmaf(v0, wp[0], acc[u]);
            acc[u] = fmaf(v1, wp[1], acc[u]);
            acc[u] = fmaf(v2, wp[2], acc[u]);
            acc[u] = fmaf(v3, wp[3], acc[u]);
        }
    }
    if (jv) {
#pragma unroll
        for (int u = 0; u < 8; ++u) {
            float a = acc[u];
            a = a >= 0.f ? a : SLOPE * a;
            out[((size_t)b * 1000 + o0 + u) * 23 + j] = a;
        }
    }
}

// ---------------- linear (1000->64), spatial-lane, K-split ----------------
// sub (64,1000,23); lw (64,1000); pout[p] (64,64,23); 8 chunks of 125 c.
__global__ __launch_bounds__(256) void linear_s(const float* __restrict__ sub,
                                                const float* __restrict__ lw,
                                                float* __restrict__ pout) {
    int s = blockIdx.x * 256 + threadIdx.x;  // 0..1535
    int j = s % 24;
    int b = s / 24;
    int ct = blockIdx.y % 8;
    int p  = blockIdx.y / 8;
    int o0 = ct * 8;
    bool jv = j < 23;
    int jc = jv ? j : 22;

    const float* sp = sub + (size_t)b * 23000 + jc;
    float acc[8];
#pragma unroll
    for (int u = 0; u < 8; ++u) acc[u] = 0.f;

    int c0 = p * 125;
    for (int c = c0; c < c0 + 125; ++c) {
        float v = sp[(size_t)c * 23];
#pragma unroll
        for (int u = 0; u < 8; ++u)
            acc[u] = fmaf(v, lw[(size_t)(o0 + u) * 1000 + c], acc[u]);
    }
    if (jv) {
#pragma unroll
        for (int u = 0; u < 8; ++u)
            pout[(size_t)p * 94208 + ((size_t)b * 64 + o0 + u) * 23 + j] = acc[u];
    }
}

// ---------------- final interleave/shuffle ----------------
__global__ void shuffle_out_kernel(const float* __restrict__ sig, float* __restrict__ out) {
    int idx = blockIdx.x * blockDim.x + threadIdx.x;
    if (idx >= 64 * 768) return;
    int o = idx % 32;
    int j = (idx / 32) % 24;
    int b = idx / 768;
    const float* s = sig + (size_t)b * 64 * 23;
    float v;
    if (j == 0)       v = s[o * 23];
    else if (j == 23) v = s[(o + 32) * 23 + 22];
    else              v = 0.5f * (s[(o + 32) * 23 + (j - 1)] + s[o * 23 + j]);
    out[idx] = v;
}

extern "C" void kernel_launch(void* const* d_in, const int* in_sizes, int n_in,
                              void* d_out, int out_size, void* d_ws, size_t ws_size,
                              hipStream_t stream) {
    (void)in_sizes; (void)n_in; (void)out_size; (void)ws_size;

    const float* x = (const float*)d_in[0];
    const float* w[5]; const float* g[5]; const float* bb[5];
    for (int i = 0; i < 5; ++i) {
        w[i]  = (const float*)d_in[1 + 3 * i];
        g[i]  = (const float*)d_in[2 + 3 * i];
        bb[i] = (const float*)d_in[3 + 3 * i];
    }
    const float* w5 = (const float*)d_in[16];
    const float* lw = (const float*)d_in[17];
    float* out = (float*)d_out;

    float* ws   = (float*)d_ws;
    float* bufA = ws;                       // 12,582,912 floats
    float* bufB = ws + 12582912;            //  6,291,456 floats
    float* part = ws + 18874368;            //  8,192 floats
    float* ss   = part + 8192;              //  2,048 floats
    float* pbufC = bufA + 6291456;          // conv L3/L4 partials (<= 3.15M floats)
    float* sub   = bufB;                    // (64,1000,23) = 1,472,000
    float* pbufL = bufB + 2097152;          // linear partials (753,664 floats)
    float* sig   = bufB + 4194304;          // (64,64,23) = 94,208

    const int Bn = 64;
    const int Co[5] = {16, 32, 64, 128, 256};
    const int Hi[5] = {64, 32, 16, 8, 4};
    const int Wi[5] = {768, 384, 192, 96, 48};
    const int Ps[5] = {1, 1, 1, 2, 4};

    const float* cur = x;
    float* dst = bufA;
    for (int L = 0; L < 5; ++L) {
        int Ho = Hi[L] / 2, Wo = Wi[L] / 2;
        int HW = Ho * Wo;
        int total = Bn * Co[L] * HW;
        int SPB = (Bn * HW) / 256;           // spatial blocks (exact for all layers)
        int CT = Co[L] / 8;
        float* cdst = (Ps[L] == 1) ? dst : pbufC;
        switch (L) {
            case 0: hipLaunchKernelGGL((conv_s<3,   16,  64, 768, 1>), dim3(SPB, CT * 1), dim3(256), 0, stream, cur, w[L], cdst); break;
            case 1: hipLaunchKernelGGL((conv_s<16,  32,  32, 384, 1>), dim3(SPB, CT * 1), dim3(256), 0, stream, cur, w[L], cdst); break;
            case 2: hipLaunchKernelGGL((conv_s<32,  64,  16, 192, 1>), dim3(SPB, CT * 1), dim3(256), 0, stream, cur, w[L], cdst); break;
            case 3: hipLaunchKernelGGL((conv_s<64,  128, 8,  96,  2>), dim3(SPB, CT * 2), dim3(256), 0, stream, cur, w[L], cdst); break;
            case 4: hipLaunchKernelGGL((conv_s<128, 256, 4,  48,  4>), dim3(SPB, CT * 4), dim3(256), 0, stream, cur, w[L], cdst); break;
        }
        if (Ps[L] > 1) {
            int tot4 = total / 4;
            hipLaunchKernelGGL(reduceP_k<0>, dim3((tot4 + 255) / 256), dim3(256), 0, stream,
                               pbufC, dst, tot4, Ps[L]);
        }
        hipLaunchKernelGGL(bn_stats_partial, dim3(Co[L] * STAT_CHUNKS), dim3(256), 0, stream,
                           dst, part, Bn, Co[L], HW);
        float invN = 1.f / (float)(Bn * HW);
        hipLaunchKernelGGL(bn_finalize, dim3((Co[L] + 255) / 256), dim3(256), 0, stream,
                           part, g[L], bb[L], ss, Co[L], invN);
        hipLaunchKernelGGL(bn_leaky4, dim3((total / 4 + 255) / 256), dim3(256), 0, stream,
                           dst, ss, Co[L], HW / 4, total / 4);
        cur = dst;
        dst = (L % 2 == 0) ? bufB : bufA;
    }
    // layer-4 activation now in bufA[0..786432) (64,256,2,24)

    hipLaunchKernelGGL(conv5_s, dim3(6, 125), dim3(256), 0, stream, bufA, w5, sub);
    hipLaunchKernelGGL(linear_s, dim3(6, 64), dim3(256), 0, stream, sub, lw, pbufL);
    hipLaunchKernelGGL(reduceP_k<2>, dim3((23552 + 255) / 256), dim3(256), 0, stream,
                       pbufL, sig, 23552, 8);
    hipLaunchKernelGGL(shuffle_out_kernel, dim3((64 * 768 + 255) / 256), dim3(256), 0, stream,
                       sig, out);
}

// Round 6
// 547.903 us; speedup vs baseline: 8.5767x; 1.4947x over previous
//
#include <hip/hip_runtime.h>
#include <cmath>

#define EPS 1e-5f
#define SLOPE 0.2f
#define STAT_CHUNKS 16

typedef unsigned short u16;
typedef unsigned int u32;
typedef __attribute__((ext_vector_type(8))) short bf16x8;
typedef __attribute__((ext_vector_type(4))) float f32x4;

__device__ __forceinline__ u16 f2b(float f) {
    union { float f; u32 u; } v; v.f = f;
    u32 r = (v.u + 0x7FFF + ((v.u >> 16) & 1)) >> 16;
    return (u16)r;
}
__device__ __forceinline__ float b2f(u16 h) {
    union { u32 u; float f; } v; v.u = ((u32)h) << 16;
    return v.f;
}

// ---------------- weight fp32 -> bf16 (K padded with zeros) ----------------
__global__ void wcvt(const float* __restrict__ src, u16* __restrict__ dst,
                     int total, int K, int Kp) {
    int idx = blockIdx.x * blockDim.x + threadIdx.x;
    if (idx >= total) return;
    int k = idx % Kp;
    int co = idx / Kp;
    dst[idx] = (k < K) ? f2b(src[(size_t)co * K + k]) : (u16)0;
}

// ---------------- x fp32 -> padded bf16 [64,4(pad),66,770] ----------------
__global__ void xpad_k(const float* __restrict__ x, u16* __restrict__ out) {
    int idx = blockIdx.x * blockDim.x + threadIdx.x;
    if (idx >= 64 * 3 * 64 * 768) return;
    int w = idx % 768;
    int h = (idx / 768) % 64;
    int c = (idx / 49152) % 3;
    int b = idx / 147456;
    out[((size_t)(b * 4 + c) * 66 + h + 1) * 770 + w + 1] = f2b(x[idx]);
}

// ---------------- implicit-GEMM MFMA conv (4x4, s2, p1 via pre-padded input) ----------------
// A = W_bf16 [Co x Kp] row-major; B = patches from padded bf16 input [64,CiPad,Hi+2,Wi+2].
// One wave per 16(m) x 16(n) output tile; K-loop: 32 per step (one ci pair).
template <int Co, int CiPad, int Kp, int Hi, int Wi, bool OB>
__global__ __launch_bounds__(256) void conv_mfma(const u16* __restrict__ inp,
                                                 const u16* __restrict__ wt,
                                                 void* __restrict__ outv) {
    constexpr int Ho = Hi / 2, Wo = Wi / 2, HW = Ho * Wo;
    constexpr int Hp = Hi + 2, Wp = Wi + 2;
    constexpr int M16 = Co / 16;

    int tid = threadIdx.x;
    int wid = blockIdx.x * 4 + (tid >> 6);
    int lane = tid & 63;
    int r = lane & 15;
    int quad = lane >> 4;
    int mt = wid % M16;
    int nt = wid / M16;

    int n = nt * 16 + r;
    int b = n / HW;
    int hw = n % HW;
    int oh = hw / Wo;
    int ow = hw % Wo;

    int ciq = quad >> 1;          // which ci of the pair this lane covers
    int kh0 = (quad & 1) * 2;     // kh rows {0,1} or {2,3}

    const u16* pB = inp + ((size_t)(b * CiPad + ciq) * Hp + (2 * oh + kh0)) * Wp + 2 * ow;
    const u16* pA = wt + (size_t)(mt * 16 + r) * Kp + quad * 8;

    f32x4 acc = {0.f, 0.f, 0.f, 0.f};
#pragma unroll
    for (int kk = 0; kk < Kp / 32; ++kk) {
        bf16x8 a = *(const bf16x8*)pA;
        union { u32 u[4]; bf16x8 v; } bb;
        bb.u[0] = *(const u32*)(pB);
        bb.u[1] = *(const u32*)(pB + 2);
        bb.u[2] = *(const u32*)(pB + Wp);
        bb.u[3] = *(const u32*)(pB + Wp + 2);
        acc = __builtin_amdgcn_mfma_f32_16x16x32_bf16(a, bb.v, acc, 0, 0, 0);
        pA += 32;
        pB += (size_t)2 * Hp * Wp;
    }

    // D: col = r (n-index, reuse b/hw), row = quad*4 + j (co)
    if (OB) {
        u16* o = (u16*)outv;
#pragma unroll
        for (int j = 0; j < 4; ++j)
            o[((size_t)b * Co + mt * 16 + quad * 4 + j) * HW + hw] = f2b(acc[j]);
    } else {
        float* o = (float*)outv;
#pragma unroll
        for (int j = 0; j < 4; ++j)
            o[((size_t)b * Co + mt * 16 + quad * 4 + j) * HW + hw] = acc[j];
    }
}

// ---------------- BN stats: deterministic two-stage reduction (fp32 in) ----------------
__global__ void bn_stats_partial(const float* __restrict__ x, float* __restrict__ part,
                                 int Bn, int C, int HW) {
    int c = blockIdx.x / STAT_CHUNKS;
    int chunk = blockIdx.x % STAT_CHUNKS;
    long N = (long)Bn * HW;
    long per = (N + STAT_CHUNKS - 1) / STAT_CHUNKS;
    long lo = (long)chunk * per;
    long hi = lo + per; if (hi > N) hi = N;
    double s1 = 0.0, s2 = 0.0;
    for (long i = lo + threadIdx.x; i < hi; i += blockDim.x) {
        int b = (int)(i / HW);
        int p = (int)(i % HW);
        float v = x[((size_t)b * C + c) * HW + p];
        s1 += v;
        s2 += (double)v * v;
    }
    __shared__ double sh1[256];
    __shared__ double sh2[256];
    int tid = threadIdx.x;
    sh1[tid] = s1; sh2[tid] = s2;
    __syncthreads();
    for (int s = 128; s > 0; s >>= 1) {
        if (tid < s) { sh1[tid] += sh1[tid + s]; sh2[tid] += sh2[tid + s]; }
        __syncthreads();
    }
    if (tid == 0) {
        part[((size_t)c * STAT_CHUNKS + chunk) * 2 + 0] = (float)sh1[0];
        part[((size_t)c * STAT_CHUNKS + chunk) * 2 + 1] = (float)sh2[0];
    }
}

// bf16-input variant (L0 conv out stored bf16)
__global__ void bn_stats_partial_b(const u16* __restrict__ x, float* __restrict__ part,
                                   int Bn, int C, int HW) {
    int c = blockIdx.x / STAT_CHUNKS;
    int chunk = blockIdx.x % STAT_CHUNKS;
    long N = (long)Bn * HW;
    long per = (N + STAT_CHUNKS - 1) / STAT_CHUNKS;
    long lo = (long)chunk * per;
    long hi = lo + per; if (hi > N) hi = N;
    double s1 = 0.0, s2 = 0.0;
    for (long i = lo + threadIdx.x; i < hi; i += blockDim.x) {
        int b = (int)(i / HW);
        int p = (int)(i % HW);
        float v = b2f(x[((size_t)b * C + c) * HW + p]);
        s1 += v;
        s2 += (double)v * v;
    }
    __shared__ double sh1[256];
    __shared__ double sh2[256];
    int tid = threadIdx.x;
    sh1[tid] = s1; sh2[tid] = s2;
    __syncthreads();
    for (int s = 128; s > 0; s >>= 1) {
        if (tid < s) { sh1[tid] += sh1[tid + s]; sh2[tid] += sh2[tid + s]; }
        __syncthreads();
    }
    if (tid == 0) {
        part[((size_t)c * STAT_CHUNKS + chunk) * 2 + 0] = (float)sh1[0];
        part[((size_t)c * STAT_CHUNKS + chunk) * 2 + 1] = (float)sh2[0];
    }
}

__global__ void bn_finalize(const float* __restrict__ part, const float* __restrict__ g,
                            const float* __restrict__ bb, float* __restrict__ ss,
                            int C, float invN) {
    int c = blockIdx.x * blockDim.x + threadIdx.x;
    if (c >= C) return;
    float s1 = 0.f, s2 = 0.f;
    for (int k = 0; k < STAT_CHUNKS; ++k) {
        s1 += part[((size_t)c * STAT_CHUNKS + k) * 2 + 0];
        s2 += part[((size_t)c * STAT_CHUNKS + k) * 2 + 1];
    }
    float mean = s1 * invN;
    float var  = s2 * invN - mean * mean;
    float inv  = rsqrtf(var + EPS);
    float sc   = inv * g[c];
    ss[c]     = sc;
    ss[C + c] = bb[c] - mean * sc;
}

// ---------------- BN-apply + leaky + write padded bf16 next-layer input ----------------
// in: [64,C,H,W] (fp32 or bf16) -> out: padded bf16 [64,C,H+2,W+2] (halo pre-zeroed)
template <bool INB>
__global__ void bn_pad(const void* __restrict__ in, const float* __restrict__ ss,
                       u16* __restrict__ outp, int C, int H, int W, int total) {
    int idx = blockIdx.x * blockDim.x + threadIdx.x;
    if (idx >= total) return;
    int w = idx % W;
    int h = (idx / W) % H;
    int c = (idx / (W * H)) % C;
    int b = idx / (W * H * C);
    float v = INB ? b2f(((const u16*)in)[idx]) : ((const float*)in)[idx];
    v = v * ss[c] + ss[C + c];
    v = v >= 0.f ? v : SLOPE * v;
    outp[((size_t)(b * C + c) * (H + 2) + h + 1) * (W + 2) + w + 1] = f2b(v);
}

// float4 BN-apply + leaky in place (L4)
__global__ void bn_leaky4(float* __restrict__ x, const float* __restrict__ ss,
                          int C, int HW4, int total4) {
    int idx = blockIdx.x * blockDim.x + threadIdx.x;
    if (idx >= total4) return;
    int c = (idx / HW4) % C;
    float sc = ss[c], sh = ss[C + c];
    float4 v = ((float4*)x)[idx];
    v.x = v.x * sc + sh; v.x = v.x >= 0.f ? v.x : SLOPE * v.x;
    v.y = v.y * sc + sh; v.y = v.y >= 0.f ? v.y : SLOPE * v.y;
    v.z = v.z * sc + sh; v.z = v.z >= 0.f ? v.z : SLOPE * v.z;
    v.w = v.w * sc + sh; v.w = v.w >= 0.f ? v.w : SLOPE * v.w;
    ((float4*)x)[idx] = v;
}

// ---------------- conv5 (2x2, s1, p0) + leaky, spatial-lane ----------------
__global__ __launch_bounds__(256) void conv5_s(const float* __restrict__ in,
                                               const float* __restrict__ w5,
                                               float* __restrict__ out) {
    int s = blockIdx.x * 256 + threadIdx.x;  // 0..1535
    int j = s % 24;
    int b = s / 24;
    int o0 = blockIdx.y * 8;
    bool jv = j < 23;
    int jc = jv ? j : 22;

    float acc[8];
#pragma unroll
    for (int u = 0; u < 8; ++u) acc[u] = 0.f;

    const float* ip = in + (size_t)b * 12288;
    for (int ci = 0; ci < 256; ++ci) {
        const float* r = ip + ci * 48;
        float v0 = r[jc], v1 = r[jc + 1], v2 = r[24 + jc], v3 = r[25 + jc];
#pragma unroll
        for (int u = 0; u < 8; ++u) {
            const float* wp = w5 + ((size_t)(o0 + u) * 256 + ci) * 4;  // wave-uniform
            acc[u] = fmaf(v0, wp[0], acc[u]);
            acc[u] = fmaf(v1, wp[1], acc[u]);
            acc[u] = fmaf(v2, wp[2], acc[u]);
            acc[u] = fmaf(v3, wp[3], acc[u]);
        }
    }
    if (jv) {
#pragma unroll
        for (int u = 0; u < 8; ++u) {
            float a = acc[u];
            a = a >= 0.f ? a : SLOPE * a;
            out[((size_t)b * 1000 + o0 + u) * 23 + j] = a;
        }
    }
}

// ---------------- linear (1000->64), spatial-lane, K-split ----------------
__global__ __launch_bounds__(256) void linear_s(const float* __restrict__ sub,
                                                const float* __restrict__ lw,
                                                float* __restrict__ pout) {
    int s = blockIdx.x * 256 + threadIdx.x;  // 0..1535
    int j = s % 24;
    int b = s / 24;
    int ct = blockIdx.y % 8;
    int p  = blockIdx.y / 8;
    int o0 = ct * 8;
    bool jv = j < 23;
    int jc = jv ? j : 22;

    const float* sp = sub + (size_t)b * 23000 + jc;
    float acc[8];
#pragma unroll
    for (int u = 0; u < 8; ++u) acc[u] = 0.f;

    int c0 = p * 125;
    for (int c = c0; c < c0 + 125; ++c) {
        float v = sp[(size_t)c * 23];
#pragma unroll
        for (int u = 0; u < 8; ++u)
            acc[u] = fmaf(v, lw[(size_t)(o0 + u) * 1000 + c], acc[u]);
    }
    if (jv) {
#pragma unroll
        for (int u = 0; u < 8; ++u)
            pout[(size_t)p * 94208 + ((size_t)b * 64 + o0 + u) * 23 + j] = acc[u];
    }
}

// ---------------- partial-plane reduction (+fused activation) ----------------
template <int MODE>
__global__ void reduceP_k(const float* __restrict__ pin, float* __restrict__ out,
                          int tot4, int P) {
    int idx = blockIdx.x * blockDim.x + threadIdx.x;
    if (idx >= tot4) return;
    const float4* p4 = (const float4*)pin;
    float4 a = p4[idx];
    for (int p = 1; p < P; ++p) {
        float4 v = p4[(size_t)p * tot4 + idx];
        a.x += v.x; a.y += v.y; a.z += v.z; a.w += v.w;
    }
    if (MODE == 1) {
        a.x = a.x >= 0.f ? a.x : SLOPE * a.x;
        a.y = a.y >= 0.f ? a.y : SLOPE * a.y;
        a.z = a.z >= 0.f ? a.z : SLOPE * a.z;
        a.w = a.w >= 0.f ? a.w : SLOPE * a.w;
    } else if (MODE == 2) {
        a.x = 1.f / (1.f + expf(-a.x));
        a.y = 1.f / (1.f + expf(-a.y));
        a.z = 1.f / (1.f + expf(-a.z));
        a.w = 1.f / (1.f + expf(-a.w));
    }
    ((float4*)out)[idx] = a;
}

// ---------------- final interleave/shuffle ----------------
__global__ void shuffle_out_kernel(const float* __restrict__ sig, float* __restrict__ out) {
    int idx = blockIdx.x * blockDim.x + threadIdx.x;
    if (idx >= 64 * 768) return;
    int o = idx % 32;
    int j = (idx / 32) % 24;
    int b = idx / 768;
    const float* s = sig + (size_t)b * 64 * 23;
    float v;
    if (j == 0)       v = s[o * 23];
    else if (j == 23) v = s[(o + 32) * 23 + 22];
    else              v = 0.5f * (s[(o + 32) * 23 + (j - 1)] + s[o * 23 + j]);
    out[idx] = v;
}

extern "C" void kernel_launch(void* const* d_in, const int* in_sizes, int n_in,
                              void* d_out, int out_size, void* d_ws, size_t ws_size,
                              hipStream_t stream) {
    (void)in_sizes; (void)n_in; (void)out_size; (void)ws_size;

    const float* x = (const float*)d_in[0];
    const float* w[5]; const float* g[5]; const float* bb[5];
    for (int i = 0; i < 5; ++i) {
        w[i]  = (const float*)d_in[1 + 3 * i];
        g[i]  = (const float*)d_in[2 + 3 * i];
        bb[i] = (const float*)d_in[3 + 3 * i];
    }
    const float* w5 = (const float*)d_in[16];
    const float* lw = (const float*)d_in[17];
    float* out = (float*)d_out;

    // ---- workspace layout (53.5 MB total) ----
    float* A       = (float*)d_ws;                  // 6,291,456 f32: conv-out region (bf16 for L0)
    u16*   slotB   = (u16*)(A + 6291456);           // 13,438,976 bf16: padded input slot
    float* slotB_f = (float*)slotB;
    u16*   wbf     = slotB + 13438976;              // 697,344 bf16 weights
    float* part    = (float*)(wbf + 697344);        // 8,192 f32
    float* ss      = part + 8192;                   // 2,048 f32
    float* sub     = slotB_f;                       // (64,1000,23) after L4
    float* pbufL   = slotB_f + 1572864;             // 8 x 94,208
    float* sig     = slotB_f + 2359296;             // (64,64,23)

    // weight offsets (elements) and K/Kp per layer
    const size_t wofs[5] = {0, 1024, 9216, 41984, 173056};
    const int    Ks[5]   = {48, 256, 512, 1024, 2048};
    const int    Kps[5]  = {64, 256, 512, 1024, 2048};
    const int    Cos[5]  = {16, 32, 64, 128, 256};

    // ---- weights -> bf16 (K zero-padded for L0) ----
    for (int L = 0; L < 5; ++L) {
        int tot = Cos[L] * Kps[L];
        hipLaunchKernelGGL(wcvt, dim3((tot + 255) / 256), dim3(256), 0, stream,
                           w[L], wbf + wofs[L], tot, Ks[L], Kps[L]);
    }

    // ---- x -> padded bf16 [64,4,66,770] ----
    hipMemsetAsync(slotB, 0, (size_t)13009920 * 2, stream);
    hipLaunchKernelGGL(xpad_k, dim3(36864), dim3(256), 0, stream, x, slotB);

    // padded-input byte sizes for layers 1..4 (memset before bn_pad writes)
    const size_t padBytes[5] = {0, (size_t)13438976 * 2, (size_t)7151616 * 2,
                                (size_t)4014080 * 2, (size_t)2457600 * 2};
    const int Hos[5] = {32, 16, 8, 4, 2};
    const int Wos[5] = {384, 192, 96, 48, 24};

    for (int L = 0; L < 5; ++L) {
        int Ho = Hos[L], Wo = Wos[L];
        int HW = Ho * Wo;
        int N16 = (64 * HW) / 16;
        int blocks = (Cos[L] / 16) * N16 / 4;
        switch (L) {
            case 0: hipLaunchKernelGGL((conv_mfma<16,  4,   64,   64, 768, true >), dim3(blocks), dim3(256), 0, stream, slotB, wbf + wofs[0], A); break;
            case 1: hipLaunchKernelGGL((conv_mfma<32,  16,  256,  32, 384, false>), dim3(blocks), dim3(256), 0, stream, slotB, wbf + wofs[1], A); break;
            case 2: hipLaunchKernelGGL((conv_mfma<64,  32,  512,  16, 192, false>), dim3(blocks), dim3(256), 0, stream, slotB, wbf + wofs[2], A); break;
            case 3: hipLaunchKernelGGL((conv_mfma<128, 64,  1024, 8,  96,  false>), dim3(blocks), dim3(256), 0, stream, slotB, wbf + wofs[3], A); break;
            case 4: hipLaunchKernelGGL((conv_mfma<256, 128, 2048, 4,  48,  false>), dim3(blocks), dim3(256), 0, stream, slotB, wbf + wofs[4], A); break;
        }
        // BN stats
        if (L == 0)
            hipLaunchKernelGGL(bn_stats_partial_b, dim3(Cos[L] * STAT_CHUNKS), dim3(256), 0, stream,
                               (const u16*)A, part, 64, Cos[L], HW);
        else
            hipLaunchKernelGGL(bn_stats_partial, dim3(Cos[L] * STAT_CHUNKS), dim3(256), 0, stream,
                               A, part, 64, Cos[L], HW);
        float invN = 1.f / (float)(64 * HW);
        hipLaunchKernelGGL(bn_finalize, dim3(1), dim3(256), 0, stream,
                           part, g[L], bb[L], ss, Cos[L], invN);
        // BN apply + leaky (+ pad-convert for next layer)
        int total = 64 * Cos[L] * HW;
        if (L < 4) {
            hipMemsetAsync(slotB, 0, padBytes[L + 1], stream);
            if (L == 0)
                hipLaunchKernelGGL(bn_pad<true>,  dim3((total + 255) / 256), dim3(256), 0, stream,
                                   (const void*)A, ss, slotB, Cos[L], Ho, Wo, total);
            else
                hipLaunchKernelGGL(bn_pad<false>, dim3((total + 255) / 256), dim3(256), 0, stream,
                                   (const void*)A, ss, slotB, Cos[L], Ho, Wo, total);
        } else {
            hipLaunchKernelGGL(bn_leaky4, dim3((total / 4 + 255) / 256), dim3(256), 0, stream,
                               A, ss, Cos[L], HW / 4, total / 4);
        }
    }
    // L4 activation: fp32 [64,256,2,24] in A

    hipLaunchKernelGGL(conv5_s, dim3(6, 125), dim3(256), 0, stream, A, w5, sub);
    hipLaunchKernelGGL(linear_s, dim3(6, 64), dim3(256), 0, stream, sub, lw, pbufL);
    hipLaunchKernelGGL(reduceP_k<2>, dim3((23552 + 255) / 256), dim3(256), 0, stream,
                       pbufL, sig, 23552, 8);
    hipLaunchKernelGGL(shuffle_out_kernel, dim3((64 * 768 + 255) / 256), dim3(256), 0, stream,
                       sig, out);
}

// Round 7
// 519.217 us; speedup vs baseline: 9.0505x; 1.0552x over previous
//
#include <hip/hip_runtime.h>
#include <cmath>

#define EPS 1e-5f
#define SLOPE 0.2f
#define STAT_CHUNKS 16

typedef unsigned short u16;
typedef unsigned int u32;
typedef __attribute__((ext_vector_type(8))) short bf16x8;
typedef __attribute__((ext_vector_type(4))) float f32x4;

__device__ __forceinline__ u16 f2b(float f) {
    union { float f; u32 u; } v; v.f = f;
    u32 r = (v.u + 0x7FFF + ((v.u >> 16) & 1)) >> 16;
    return (u16)r;
}
__device__ __forceinline__ float b2f(u16 h) {
    union { u32 u; float f; } v; v.u = ((u32)h) << 16;
    return v.f;
}

// ---------------- weight fp32 -> bf16 (K padded with zeros) ----------------
__global__ void wcvt(const float* __restrict__ src, u16* __restrict__ dst,
                     int total, int K, int Kp) {
    int idx = blockIdx.x * blockDim.x + threadIdx.x;
    if (idx >= total) return;
    int k = idx % Kp;
    int co = idx / Kp;
    dst[idx] = (k < K) ? f2b(src[(size_t)co * K + k]) : (u16)0;
}

// weight fp32 -> bf16 with co zero-padding (rows co >= Com are zero)
__global__ void wcvtM(const float* __restrict__ src, u16* __restrict__ dst,
                      int total, int K, int Com) {
    int idx = blockIdx.x * blockDim.x + threadIdx.x;
    if (idx >= total) return;
    int k = idx % K;
    int co = idx / K;
    dst[idx] = (co < Com) ? f2b(src[(size_t)co * K + k]) : (u16)0;
}

// ---------------- x fp32 -> padded bf16 [64,4(pad),66,770] ----------------
__global__ void xpad_k(const float* __restrict__ x, u16* __restrict__ out) {
    int idx = blockIdx.x * blockDim.x + threadIdx.x;
    if (idx >= 64 * 3 * 64 * 768) return;
    int w = idx % 768;
    int h = (idx / 768) % 64;
    int c = (idx / 49152) % 3;
    int b = idx / 147456;
    out[((size_t)(b * 4 + c) * 66 + h + 1) * 770 + w + 1] = f2b(x[idx]);
}

// ---------------- implicit-GEMM MFMA conv (4x4, s2, p1 via pre-padded input) ----------------
template <int Co, int CiPad, int Kp, int Hi, int Wi, bool OB>
__global__ __launch_bounds__(256) void conv_mfma(const u16* __restrict__ inp,
                                                 const u16* __restrict__ wt,
                                                 void* __restrict__ outv) {
    constexpr int Ho = Hi / 2, Wo = Wi / 2, HW = Ho * Wo;
    constexpr int Hp = Hi + 2, Wp = Wi + 2;
    constexpr int M16 = Co / 16;

    int tid = threadIdx.x;
    int wid = blockIdx.x * 4 + (tid >> 6);
    int lane = tid & 63;
    int r = lane & 15;
    int quad = lane >> 4;
    int mt = wid % M16;
    int nt = wid / M16;

    int n = nt * 16 + r;
    int b = n / HW;
    int hw = n % HW;
    int oh = hw / Wo;
    int ow = hw % Wo;

    int ciq = quad >> 1;          // which ci of the pair this lane covers
    int kh0 = (quad & 1) * 2;     // kh rows {0,1} or {2,3}

    const u16* pB = inp + ((size_t)(b * CiPad + ciq) * Hp + (2 * oh + kh0)) * Wp + 2 * ow;
    const u16* pA = wt + (size_t)(mt * 16 + r) * Kp + quad * 8;

    f32x4 acc = {0.f, 0.f, 0.f, 0.f};
#pragma unroll
    for (int kk = 0; kk < Kp / 32; ++kk) {
        bf16x8 a = *(const bf16x8*)pA;
        union { u32 u[4]; bf16x8 v; } bb;
        bb.u[0] = *(const u32*)(pB);
        bb.u[1] = *(const u32*)(pB + 2);
        bb.u[2] = *(const u32*)(pB + Wp);
        bb.u[3] = *(const u32*)(pB + Wp + 2);
        acc = __builtin_amdgcn_mfma_f32_16x16x32_bf16(a, bb.v, acc, 0, 0, 0);
        pA += 32;
        pB += (size_t)2 * Hp * Wp;
    }

    // D: col = r (n-index), row = quad*4 + j (co)
    if (OB) {
        u16* o = (u16*)outv;
#pragma unroll
        for (int j = 0; j < 4; ++j)
            o[((size_t)b * Co + mt * 16 + quad * 4 + j) * HW + hw] = f2b(acc[j]);
    } else {
        float* o = (float*)outv;
#pragma unroll
        for (int j = 0; j < 4; ++j)
            o[((size_t)b * Co + mt * 16 + quad * 4 + j) * HW + hw] = acc[j];
    }
}

// ---------------- BN stats: deterministic two-stage reduction (fp32 in) ----------------
__global__ void bn_stats_partial(const float* __restrict__ x, float* __restrict__ part,
                                 int Bn, int C, int HW) {
    int c = blockIdx.x / STAT_CHUNKS;
    int chunk = blockIdx.x % STAT_CHUNKS;
    long N = (long)Bn * HW;
    long per = (N + STAT_CHUNKS - 1) / STAT_CHUNKS;
    long lo = (long)chunk * per;
    long hi = lo + per; if (hi > N) hi = N;
    double s1 = 0.0, s2 = 0.0;
    for (long i = lo + threadIdx.x; i < hi; i += blockDim.x) {
        int b = (int)(i / HW);
        int p = (int)(i % HW);
        float v = x[((size_t)b * C + c) * HW + p];
        s1 += v;
        s2 += (double)v * v;
    }
    __shared__ double sh1[256];
    __shared__ double sh2[256];
    int tid = threadIdx.x;
    sh1[tid] = s1; sh2[tid] = s2;
    __syncthreads();
    for (int s = 128; s > 0; s >>= 1) {
        if (tid < s) { sh1[tid] += sh1[tid + s]; sh2[tid] += sh2[tid + s]; }
        __syncthreads();
    }
    if (tid == 0) {
        part[((size_t)c * STAT_CHUNKS + chunk) * 2 + 0] = (float)sh1[0];
        part[((size_t)c * STAT_CHUNKS + chunk) * 2 + 1] = (float)sh2[0];
    }
}

// bf16-input variant (L0 conv out stored bf16)
__global__ void bn_stats_partial_b(const u16* __restrict__ x, float* __restrict__ part,
                                   int Bn, int C, int HW) {
    int c = blockIdx.x / STAT_CHUNKS;
    int chunk = blockIdx.x % STAT_CHUNKS;
    long N = (long)Bn * HW;
    long per = (N + STAT_CHUNKS - 1) / STAT_CHUNKS;
    long lo = (long)chunk * per;
    long hi = lo + per; if (hi > N) hi = N;
    double s1 = 0.0, s2 = 0.0;
    for (long i = lo + threadIdx.x; i < hi; i += blockDim.x) {
        int b = (int)(i / HW);
        int p = (int)(i % HW);
        float v = b2f(x[((size_t)b * C + c) * HW + p]);
        s1 += v;
        s2 += (double)v * v;
    }
    __shared__ double sh1[256];
    __shared__ double sh2[256];
    int tid = threadIdx.x;
    sh1[tid] = s1; sh2[tid] = s2;
    __syncthreads();
    for (int s = 128; s > 0; s >>= 1) {
        if (tid < s) { sh1[tid] += sh1[tid + s]; sh2[tid] += sh2[tid + s]; }
        __syncthreads();
    }
    if (tid == 0) {
        part[((size_t)c * STAT_CHUNKS + chunk) * 2 + 0] = (float)sh1[0];
        part[((size_t)c * STAT_CHUNKS + chunk) * 2 + 1] = (float)sh2[0];
    }
}

__global__ void bn_finalize(const float* __restrict__ part, const float* __restrict__ g,
                            const float* __restrict__ bb, float* __restrict__ ss,
                            int C, float invN) {
    int c = blockIdx.x * blockDim.x + threadIdx.x;
    if (c >= C) return;
    float s1 = 0.f, s2 = 0.f;
    for (int k = 0; k < STAT_CHUNKS; ++k) {
        s1 += part[((size_t)c * STAT_CHUNKS + k) * 2 + 0];
        s2 += part[((size_t)c * STAT_CHUNKS + k) * 2 + 1];
    }
    float mean = s1 * invN;
    float var  = s2 * invN - mean * mean;
    float inv  = rsqrtf(var + EPS);
    float sc   = inv * g[c];
    ss[c]     = sc;
    ss[C + c] = bb[c] - mean * sc;
}

// ---------------- BN-apply + leaky + write padded bf16 next-layer input ----------------
template <bool INB>
__global__ void bn_pad(const void* __restrict__ in, const float* __restrict__ ss,
                       u16* __restrict__ outp, int C, int H, int W, int total) {
    int idx = blockIdx.x * blockDim.x + threadIdx.x;
    if (idx >= total) return;
    int w = idx % W;
    int h = (idx / W) % H;
    int c = (idx / (W * H)) % C;
    int b = idx / (W * H * C);
    float v = INB ? b2f(((const u16*)in)[idx]) : ((const float*)in)[idx];
    v = v * ss[c] + ss[C + c];
    v = v >= 0.f ? v : SLOPE * v;
    outp[((size_t)(b * C + c) * (H + 2) + h + 1) * (W + 2) + w + 1] = f2b(v);
}

// ---------------- L4: BN-apply + leaky + im2col bf16 for conv5 ----------------
// A (fp32, [64,256,2,24]) -> ic ([1472, 1024] bf16), n = b*23+j, k = ci*4+kh*2+kw
__global__ void im2col5(const float* __restrict__ A, const float* __restrict__ ss,
                        u16* __restrict__ ic) {
    int idx = blockIdx.x * blockDim.x + threadIdx.x;
    if (idx >= 1472 * 1024) return;
    int k = idx & 1023;
    int n = idx >> 10;
    int b = n / 23, j = n % 23;
    int ci = k >> 2, kh = (k >> 1) & 1, kw = k & 1;
    float v = A[(size_t)b * 12288 + ci * 48 + kh * 24 + j + kw];
    v = v * ss[ci] + ss[256 + ci];
    v = v >= 0.f ? v : SLOPE * v;
    ic[idx] = f2b(v);
}

// ---------------- conv5 as MFMA GEMM: [1008 x 1024] x [1024 x 1472] ----------------
// A = w5 bf16 [1008,1024]; B = ic [1472,1024] (n-major, k contiguous). Leaky fused.
__global__ __launch_bounds__(256) void conv5_mfma(const u16* __restrict__ ic,
                                                  const u16* __restrict__ w5b,
                                                  float* __restrict__ sub) {
    int tid = threadIdx.x;
    int wid = blockIdx.x * 4 + (tid >> 6);
    int lane = tid & 63;
    int r = lane & 15;
    int quad = lane >> 4;
    int mt = wid % 63;          // 63 m-tiles (1008/16)
    int nt = wid / 63;          // 92 n-tiles (1472/16)

    int n = nt * 16 + r;
    const u16* pB = ic + (size_t)n * 1024 + quad * 8;
    const u16* pA = w5b + (size_t)(mt * 16 + r) * 1024 + quad * 8;

    f32x4 acc = {0.f, 0.f, 0.f, 0.f};
#pragma unroll
    for (int kk = 0; kk < 32; ++kk) {
        bf16x8 a = *(const bf16x8*)pA;
        bf16x8 bv = *(const bf16x8*)pB;
        acc = __builtin_amdgcn_mfma_f32_16x16x32_bf16(a, bv, acc, 0, 0, 0);
        pA += 32;
        pB += 32;
    }

    int b = n / 23, j = n % 23;
#pragma unroll
    for (int jj = 0; jj < 4; ++jj) {
        int co = mt * 16 + quad * 4 + jj;
        if (co < 1000) {
            float v = acc[jj];
            v = v >= 0.f ? v : SLOPE * v;
            sub[(size_t)b * 23000 + (size_t)co * 23 + j] = v;
        }
    }
}

// ---------------- linear (1000->64), spatial-lane, K-split ----------------
__global__ __launch_bounds__(256) void linear_s(const float* __restrict__ sub,
                                                const float* __restrict__ lw,
                                                float* __restrict__ pout) {
    int s = blockIdx.x * 256 + threadIdx.x;  // 0..1535
    int j = s % 24;
    int b = s / 24;
    int ct = blockIdx.y % 8;
    int p  = blockIdx.y / 8;
    int o0 = ct * 8;
    bool jv = j < 23;
    int jc = jv ? j : 22;

    const float* sp = sub + (size_t)b * 23000 + jc;
    float acc[8];
#pragma unroll
    for (int u = 0; u < 8; ++u) acc[u] = 0.f;

    int c0 = p * 125;
    for (int c = c0; c < c0 + 125; ++c) {
        float v = sp[(size_t)c * 23];
#pragma unroll
        for (int u = 0; u < 8; ++u)
            acc[u] = fmaf(v, lw[(size_t)(o0 + u) * 1000 + c], acc[u]);
    }
    if (jv) {
#pragma unroll
        for (int u = 0; u < 8; ++u)
            pout[(size_t)p * 94208 + ((size_t)b * 64 + o0 + u) * 23 + j] = acc[u];
    }
}

// ---------------- partial-plane reduction (+fused activation) ----------------
template <int MODE>
__global__ void reduceP_k(const float* __restrict__ pin, float* __restrict__ out,
                          int tot4, int P) {
    int idx = blockIdx.x * blockDim.x + threadIdx.x;
    if (idx >= tot4) return;
    const float4* p4 = (const float4*)pin;
    float4 a = p4[idx];
    for (int p = 1; p < P; ++p) {
        float4 v = p4[(size_t)p * tot4 + idx];
        a.x += v.x; a.y += v.y; a.z += v.z; a.w += v.w;
    }
    if (MODE == 1) {
        a.x = a.x >= 0.f ? a.x : SLOPE * a.x;
        a.y = a.y >= 0.f ? a.y : SLOPE * a.y;
        a.z = a.z >= 0.f ? a.z : SLOPE * a.z;
        a.w = a.w >= 0.f ? a.w : SLOPE * a.w;
    } else if (MODE == 2) {
        a.x = 1.f / (1.f + expf(-a.x));
        a.y = 1.f / (1.f + expf(-a.y));
        a.z = 1.f / (1.f + expf(-a.z));
        a.w = 1.f / (1.f + expf(-a.w));
    }
    ((float4*)out)[idx] = a;
}

// ---------------- final interleave/shuffle ----------------
__global__ void shuffle_out_kernel(const float* __restrict__ sig, float* __restrict__ out) {
    int idx = blockIdx.x * blockDim.x + threadIdx.x;
    if (idx >= 64 * 768) return;
    int o = idx % 32;
    int j = (idx / 32) % 24;
    int b = idx / 768;
    const float* s = sig + (size_t)b * 64 * 23;
    float v;
    if (j == 0)       v = s[o * 23];
    else if (j == 23) v = s[(o + 32) * 23 + 22];
    else              v = 0.5f * (s[(o + 32) * 23 + (j - 1)] + s[o * 23 + j]);
    out[idx] = v;
}

extern "C" void kernel_launch(void* const* d_in, const int* in_sizes, int n_in,
                              void* d_out, int out_size, void* d_ws, size_t ws_size,
                              hipStream_t stream) {
    (void)in_sizes; (void)n_in; (void)out_size; (void)ws_size;

    const float* x = (const float*)d_in[0];
    const float* w[5]; const float* g[5]; const float* bb[5];
    for (int i = 0; i < 5; ++i) {
        w[i]  = (const float*)d_in[1 + 3 * i];
        g[i]  = (const float*)d_in[2 + 3 * i];
        bb[i] = (const float*)d_in[3 + 3 * i];
    }
    const float* w5 = (const float*)d_in[16];
    const float* lw = (const float*)d_in[17];
    float* out = (float*)d_out;

    // ---- workspace layout (~58.6 MB total) ----
    float* A       = (float*)d_ws;                  // 6,291,456 f32: conv-out region
    u16*   slotB   = (u16*)(A + 6291456);           // 13,438,976 bf16: padded input slot
    float* slotB_f = (float*)slotB;
    u16*   wbf     = slotB + 13438976;              // 697,344 bf16 weights (L0-L4)
    float* part    = (float*)(wbf + 697344);        // 8,192 f32
    float* ss      = part + 8192;                   // 2,048 f32
    u16*   w5b     = (u16*)(ss + 2048);             // 1,032,192 bf16 (w5 padded to 1008 rows)
    u16*   ic      = w5b + 1032192;                 // 1,507,328 bf16 (conv5 im2col)
    float* sub     = slotB_f;                       // (64,1000,23) fp32 (slotB dead by then)
    float* pbufL   = slotB_f + 1572864;             // 8 x 94,208
    float* sig     = slotB_f + 2359296;             // (64,64,23)

    const size_t wofs[5] = {0, 1024, 9216, 41984, 173056};
    const int    Ks[5]   = {48, 256, 512, 1024, 2048};
    const int    Kps[5]  = {64, 256, 512, 1024, 2048};
    const int    Cos[5]  = {16, 32, 64, 128, 256};

    // ---- weights -> bf16 ----
    for (int L = 0; L < 5; ++L) {
        int tot = Cos[L] * Kps[L];
        hipLaunchKernelGGL(wcvt, dim3((tot + 255) / 256), dim3(256), 0, stream,
                           w[L], wbf + wofs[L], tot, Ks[L], Kps[L]);
    }
    hipLaunchKernelGGL(wcvtM, dim3((1008 * 1024) / 256), dim3(256), 0, stream,
                       w5, w5b, 1008 * 1024, 1024, 1000);

    // ---- x -> padded bf16 [64,4,66,770] ----
    hipMemsetAsync(slotB, 0, (size_t)13009920 * 2, stream);
    hipLaunchKernelGGL(xpad_k, dim3(36864), dim3(256), 0, stream, x, slotB);

    const size_t padBytes[5] = {0, (size_t)13438976 * 2, (size_t)7151616 * 2,
                                (size_t)4014080 * 2, (size_t)2457600 * 2};
    const int Hos[5] = {32, 16, 8, 4, 2};
    const int Wos[5] = {384, 192, 96, 48, 24};

    for (int L = 0; L < 5; ++L) {
        int Ho = Hos[L], Wo = Wos[L];
        int HW = Ho * Wo;
        int N16 = (64 * HW) / 16;
        int blocks = (Cos[L] / 16) * N16 / 4;
        switch (L) {
            case 0: hipLaunchKernelGGL((conv_mfma<16,  4,   64,   64, 768, true >), dim3(blocks), dim3(256), 0, stream, slotB, wbf + wofs[0], A); break;
            case 1: hipLaunchKernelGGL((conv_mfma<32,  16,  256,  32, 384, false>), dim3(blocks), dim3(256), 0, stream, slotB, wbf + wofs[1], A); break;
            case 2: hipLaunchKernelGGL((conv_mfma<64,  32,  512,  16, 192, false>), dim3(blocks), dim3(256), 0, stream, slotB, wbf + wofs[2], A); break;
            case 3: hipLaunchKernelGGL((conv_mfma<128, 64,  1024, 8,  96,  false>), dim3(blocks), dim3(256), 0, stream, slotB, wbf + wofs[3], A); break;
            case 4: hipLaunchKernelGGL((conv_mfma<256, 128, 2048, 4,  48,  false>), dim3(blocks), dim3(256), 0, stream, slotB, wbf + wofs[4], A); break;
        }
        if (L == 0)
            hipLaunchKernelGGL(bn_stats_partial_b, dim3(Cos[L] * STAT_CHUNKS), dim3(256), 0, stream,
                               (const u16*)A, part, 64, Cos[L], HW);
        else
            hipLaunchKernelGGL(bn_stats_partial, dim3(Cos[L] * STAT_CHUNKS), dim3(256), 0, stream,
                               A, part, 64, Cos[L], HW);
        float invN = 1.f / (float)(64 * HW);
        hipLaunchKernelGGL(bn_finalize, dim3(1), dim3(256), 0, stream,
                           part, g[L], bb[L], ss, Cos[L], invN);
        int total = 64 * Cos[L] * HW;
        if (L < 4) {
            hipMemsetAsync(slotB, 0, padBytes[L + 1], stream);
            if (L == 0)
                hipLaunchKernelGGL(bn_pad<true>,  dim3((total + 255) / 256), dim3(256), 0, stream,
                                   (const void*)A, ss, slotB, Cos[L], Ho, Wo, total);
            else
                hipLaunchKernelGGL(bn_pad<false>, dim3((total + 255) / 256), dim3(256), 0, stream,
                                   (const void*)A, ss, slotB, Cos[L], Ho, Wo, total);
        } else {
            // L4: BN+leaky+im2col into bf16 for conv5
            hipLaunchKernelGGL(im2col5, dim3((1472 * 1024) / 256), dim3(256), 0, stream,
                               A, ss, ic);
        }
    }

    hipLaunchKernelGGL(conv5_mfma, dim3(1449), dim3(256), 0, stream, ic, w5b, sub);
    hipLaunchKernelGGL(linear_s, dim3(6, 64), dim3(256), 0, stream, sub, lw, pbufL);
    hipLaunchKernelGGL(reduceP_k<2>, dim3((23552 + 255) / 256), dim3(256), 0, stream,
                       pbufL, sig, 23552, 8);
    hipLaunchKernelGGL(shuffle_out_kernel, dim3((64 * 768 + 255) / 256), dim3(256), 0, stream,
                       sig, out);
}

// Round 8
// 350.915 us; speedup vs baseline: 13.3912x; 1.4796x over previous
//
#include <hip/hip_runtime.h>
#include <cmath>

#define EPS 1e-5f
#define SLOPE 0.2f

typedef unsigned short u16;
typedef unsigned int u32;
typedef __attribute__((ext_vector_type(8))) short bf16x8;
typedef __attribute__((ext_vector_type(8))) unsigned short u16x8;
typedef __attribute__((ext_vector_type(4))) float f32x4;

__device__ __forceinline__ u16 f2b(float f) {
    union { float f; u32 u; } v; v.f = f;
    u32 r = (v.u + 0x7FFF + ((v.u >> 16) & 1)) >> 16;
    return (u16)r;
}
__device__ __forceinline__ float b2f(u16 h) {
    union { u32 u; float f; } v; v.u = ((u32)h) << 16;
    return v.f;
}
__device__ __forceinline__ float leaky(float v) { return v >= 0.f ? v : SLOPE * v; }

// ---------------- weight fp32 -> bf16 (K padded with zeros) ----------------
__global__ void wcvt(const float* __restrict__ src, u16* __restrict__ dst,
                     int total, int K, int Kp) {
    int idx = blockIdx.x * blockDim.x + threadIdx.x;
    if (idx >= total) return;
    int k = idx % Kp;
    int co = idx / Kp;
    dst[idx] = (k < K) ? f2b(src[(size_t)co * K + k]) : (u16)0;
}

// weight fp32 -> bf16 with co zero-padding (rows co >= Com are zero)
__global__ void wcvtM(const float* __restrict__ src, u16* __restrict__ dst,
                      int total, int K, int Com) {
    int idx = blockIdx.x * blockDim.x + threadIdx.x;
    if (idx >= total) return;
    int k = idx % K;
    int co = idx / K;
    dst[idx] = (co < Com) ? f2b(src[(size_t)co * K + k]) : (u16)0;
}

// ---------------- x fp32 -> padded bf16 [64,4,66,776], vector stores ----------------
__global__ __launch_bounds__(256) void xpad_v(const float* __restrict__ x,
                                              u16* __restrict__ outp) {
    constexpr int H = 64, W = 768, G = 97, Wp = 776, Hp = 66;
    int idx = blockIdx.x * 256 + threadIdx.x;
    if (idx >= 64 * 4 * Hp * G) return;
    int m = idx % G;
    int hp = (idx / G) % Hp;
    int c = (idx / (G * Hp)) % 4;
    int b = idx / (G * Hp * 4);

    u16x8 o;
#pragma unroll
    for (int i = 0; i < 8; ++i) o[i] = 0;

    if (c < 3 && hp >= 1 && hp <= H) {
        const float* base = x + ((size_t)(b * 3 + c) * H + (hp - 1)) * W;
        if (m > 0) o[0] = f2b(base[8 * m - 1]);
        if (m < G - 1) {
            float4 a  = *(const float4*)(base + 8 * m);
            float4 b4 = *(const float4*)(base + 8 * m + 4);
            o[1] = f2b(a.x); o[2] = f2b(a.y); o[3] = f2b(a.z); o[4] = f2b(a.w);
            o[5] = f2b(b4.x); o[6] = f2b(b4.y); o[7] = f2b(b4.z);
        }
    }
    *(u16x8*)(outp + ((size_t)(b * 4 + c) * Hp + hp) * Wp + 8 * m) = o;
}

// ---------------- implicit-GEMM MFMA conv (4x4, s2, p1 via pre-padded input) ----------------
template <int Co, int CiPad, int Kp, int Hi, int Wi, int Hp, int Wp, bool OB>
__global__ __launch_bounds__(256) void conv_mfma(const u16* __restrict__ inp,
                                                 const u16* __restrict__ wt,
                                                 void* __restrict__ outv) {
    constexpr int Ho = Hi / 2, Wo = Wi / 2, HW = Ho * Wo;
    constexpr int M16 = Co / 16;

    int tid = threadIdx.x;
    int wid = blockIdx.x * 4 + (tid >> 6);
    int lane = tid & 63;
    int r = lane & 15;
    int quad = lane >> 4;
    int mt = wid % M16;
    int nt = wid / M16;

    int n = nt * 16 + r;
    int b = n / HW;
    int hw = n % HW;
    int oh = hw / Wo;
    int ow = hw % Wo;

    int ciq = quad >> 1;
    int kh0 = (quad & 1) * 2;

    const u16* pB = inp + ((size_t)(b * CiPad + ciq) * Hp + (2 * oh + kh0)) * Wp + 2 * ow;
    const u16* pA = wt + (size_t)(mt * 16 + r) * Kp + quad * 8;

    f32x4 acc = {0.f, 0.f, 0.f, 0.f};
#pragma unroll
    for (int kk = 0; kk < Kp / 32; ++kk) {
        bf16x8 a = *(const bf16x8*)pA;
        union { u32 u[4]; bf16x8 v; } bb;
        bb.u[0] = *(const u32*)(pB);
        bb.u[1] = *(const u32*)(pB + 2);
        bb.u[2] = *(const u32*)(pB + Wp);
        bb.u[3] = *(const u32*)(pB + Wp + 2);
        acc = __builtin_amdgcn_mfma_f32_16x16x32_bf16(a, bb.v, acc, 0, 0, 0);
        pA += 32;
        pB += (size_t)2 * Hp * Wp;
    }

    if (OB) {
        u16* o = (u16*)outv;
#pragma unroll
        for (int j = 0; j < 4; ++j)
            o[((size_t)b * Co + mt * 16 + quad * 4 + j) * HW + hw] = f2b(acc[j]);
    } else {
        float* o = (float*)outv;
#pragma unroll
        for (int j = 0; j < 4; ++j)
            o[((size_t)b * Co + mt * 16 + quad * 4 + j) * HW + hw] = acc[j];
    }
}

// ---------------- BN stats: vectorized, division-free, deterministic ----------------
// grid = C*16 blocks; chunk = 4 consecutive b; per-thread double accum; shared reduce.
template <int C, int HW>
__global__ __launch_bounds__(256) void stats_bf(const u16* __restrict__ x,
                                                float* __restrict__ part) {
    int c = blockIdx.x >> 4;
    int chunk = blockIdx.x & 15;
    double s1 = 0.0, s2 = 0.0;
    for (int bi = 0; bi < 4; ++bi) {
        const u16* base = x + ((size_t)(chunk * 4 + bi) * C + c) * HW;
        for (int p = threadIdx.x * 8; p < HW; p += 2048) {
            bf16x8 v = *(const bf16x8*)(base + p);
#pragma unroll
            for (int e = 0; e < 8; ++e) {
                float f = b2f((u16)v[e]);
                s1 += f; s2 += (double)f * f;
            }
        }
    }
    __shared__ double sh1[256];
    __shared__ double sh2[256];
    int tid = threadIdx.x;
    sh1[tid] = s1; sh2[tid] = s2;
    __syncthreads();
    for (int s = 128; s > 0; s >>= 1) {
        if (tid < s) { sh1[tid] += sh1[tid + s]; sh2[tid] += sh2[tid + s]; }
        __syncthreads();
    }
    if (tid == 0) {
        part[((size_t)c * 16 + chunk) * 2 + 0] = (float)sh1[0];
        part[((size_t)c * 16 + chunk) * 2 + 1] = (float)sh2[0];
    }
}

template <int C, int HW>
__global__ __launch_bounds__(256) void stats_f32(const float* __restrict__ x,
                                                 float* __restrict__ part) {
    int c = blockIdx.x >> 4;
    int chunk = blockIdx.x & 15;
    double s1 = 0.0, s2 = 0.0;
    for (int bi = 0; bi < 4; ++bi) {
        const float* base = x + ((size_t)(chunk * 4 + bi) * C + c) * HW;
        for (int p = threadIdx.x * 4; p < HW; p += 1024) {
            float4 v = *(const float4*)(base + p);
            s1 += v.x; s2 += (double)v.x * v.x;
            s1 += v.y; s2 += (double)v.y * v.y;
            s1 += v.z; s2 += (double)v.z * v.z;
            s1 += v.w; s2 += (double)v.w * v.w;
        }
    }
    __shared__ double sh1[256];
    __shared__ double sh2[256];
    int tid = threadIdx.x;
    sh1[tid] = s1; sh2[tid] = s2;
    __syncthreads();
    for (int s = 128; s > 0; s >>= 1) {
        if (tid < s) { sh1[tid] += sh1[tid + s]; sh2[tid] += sh2[tid + s]; }
        __syncthreads();
    }
    if (tid == 0) {
        part[((size_t)c * 16 + chunk) * 2 + 0] = (float)sh1[0];
        part[((size_t)c * 16 + chunk) * 2 + 1] = (float)sh2[0];
    }
}

__global__ void bn_finalize(const float* __restrict__ part, const float* __restrict__ g,
                            const float* __restrict__ bb, float* __restrict__ ss,
                            int C, float invN) {
    int c = blockIdx.x * blockDim.x + threadIdx.x;
    if (c >= C) return;
    float s1 = 0.f, s2 = 0.f;
    for (int k = 0; k < 16; ++k) {
        s1 += part[((size_t)c * 16 + k) * 2 + 0];
        s2 += part[((size_t)c * 16 + k) * 2 + 1];
    }
    float mean = s1 * invN;
    float var  = s2 * invN - mean * mean;
    float inv  = rsqrtf(var + EPS);
    float sc   = inv * g[c];
    ss[c]     = sc;
    ss[C + c] = bb[c] - mean * sc;
}

// ---------------- BN + leaky + padded bf16 write, aligned 16B vector stores ----------------
// Writes the ENTIRE padded buffer (halo rows/cols as zeros) -> no memset needed.
template <int C, int H, int W, bool INB>
__global__ __launch_bounds__(256) void bn_pad_v(const void* __restrict__ in,
                                                const float* __restrict__ ss,
                                                u16* __restrict__ outp) {
    constexpr int G = W / 8 + 1;
    constexpr int Wp = 8 * G;
    constexpr int Hp = H + 2;
    int idx = blockIdx.x * 256 + threadIdx.x;
    if (idx >= 64 * C * Hp * G) return;
    int m = idx % G;
    int hp = (idx / G) % Hp;
    int c = (idx / (G * Hp)) % C;
    int b = idx / (G * Hp * C);

    u16x8 o;
#pragma unroll
    for (int i = 0; i < 8; ++i) o[i] = 0;

    if (hp >= 1 && hp <= H) {
        float sc = ss[c], sh = ss[C + c];
        float vals[8];
        if (INB) {
            const u16* base = (const u16*)in + ((size_t)(b * C + c) * H + (hp - 1)) * W;
            vals[0] = (m > 0) ? b2f(base[8 * m - 1]) : 0.f;
            if (m < G - 1) {
                bf16x8 va = *(const bf16x8*)(base + 8 * m);
#pragma unroll
                for (int i = 0; i < 7; ++i) vals[i + 1] = b2f((u16)va[i]);
            }
        } else {
            const float* base = (const float*)in + ((size_t)(b * C + c) * H + (hp - 1)) * W;
            vals[0] = (m > 0) ? base[8 * m - 1] : 0.f;
            if (m < G - 1) {
                float4 a  = *(const float4*)(base + 8 * m);
                float4 b4 = *(const float4*)(base + 8 * m + 4);
                vals[1] = a.x; vals[2] = a.y; vals[3] = a.z; vals[4] = a.w;
                vals[5] = b4.x; vals[6] = b4.y; vals[7] = b4.z;
            }
        }
        if (m > 0) o[0] = f2b(leaky(vals[0] * sc + sh));
        if (m < G - 1) {
#pragma unroll
            for (int i = 1; i < 8; ++i) o[i] = f2b(leaky(vals[i] * sc + sh));
        }
    }
    *(u16x8*)(outp + ((size_t)(b * C + c) * Hp + hp) * Wp + 8 * m) = o;
}

// ---------------- L4: BN + leaky + im2col bf16 for conv5 ----------------
__global__ void im2col5(const float* __restrict__ A, const float* __restrict__ ss,
                        u16* __restrict__ ic) {
    int idx = blockIdx.x * blockDim.x + threadIdx.x;
    if (idx >= 1472 * 1024) return;
    int k = idx & 1023;
    int n = idx >> 10;
    int b = n / 23, j = n % 23;
    int ci = k >> 2, kh = (k >> 1) & 1, kw = k & 1;
    float v = A[(size_t)b * 12288 + ci * 48 + kh * 24 + j + kw];
    v = leaky(v * ss[ci] + ss[256 + ci]);
    ic[idx] = f2b(v);
}

// ---------------- conv5 as MFMA GEMM: [1008 x 1024] x [1024 x 1472] ----------------
__global__ __launch_bounds__(256) void conv5_mfma(const u16* __restrict__ ic,
                                                  const u16* __restrict__ w5b,
                                                  float* __restrict__ sub) {
    int tid = threadIdx.x;
    int wid = blockIdx.x * 4 + (tid >> 6);
    int lane = tid & 63;
    int r = lane & 15;
    int quad = lane >> 4;
    int mt = wid % 63;
    int nt = wid / 63;

    int n = nt * 16 + r;
    const u16* pB = ic + (size_t)n * 1024 + quad * 8;
    const u16* pA = w5b + (size_t)(mt * 16 + r) * 1024 + quad * 8;

    f32x4 acc = {0.f, 0.f, 0.f, 0.f};
#pragma unroll
    for (int kk = 0; kk < 32; ++kk) {
        bf16x8 a = *(const bf16x8*)pA;
        bf16x8 bv = *(const bf16x8*)pB;
        acc = __builtin_amdgcn_mfma_f32_16x16x32_bf16(a, bv, acc, 0, 0, 0);
        pA += 32;
        pB += 32;
    }

    int b = n / 23, j = n % 23;
#pragma unroll
    for (int jj = 0; jj < 4; ++jj) {
        int co = mt * 16 + quad * 4 + jj;
        if (co < 1000) {
            sub[(size_t)b * 23000 + (size_t)co * 23 + j] = leaky(acc[jj]);
        }
    }
}

// ---------------- linear (1000->64), spatial-lane, K-split ----------------
__global__ __launch_bounds__(256) void linear_s(const float* __restrict__ sub,
                                                const float* __restrict__ lw,
                                                float* __restrict__ pout) {
    int s = blockIdx.x * 256 + threadIdx.x;
    int j = s % 24;
    int b = s / 24;
    int ct = blockIdx.y % 8;
    int p  = blockIdx.y / 8;
    int o0 = ct * 8;
    bool jv = j < 23;
    int jc = jv ? j : 22;

    const float* sp = sub + (size_t)b * 23000 + jc;
    float acc[8];
#pragma unroll
    for (int u = 0; u < 8; ++u) acc[u] = 0.f;

    int c0 = p * 125;
    for (int c = c0; c < c0 + 125; ++c) {
        float v = sp[(size_t)c * 23];
#pragma unroll
        for (int u = 0; u < 8; ++u)
            acc[u] = fmaf(v, lw[(size_t)(o0 + u) * 1000 + c], acc[u]);
    }
    if (jv) {
#pragma unroll
        for (int u = 0; u < 8; ++u)
            pout[(size_t)p * 94208 + ((size_t)b * 64 + o0 + u) * 23 + j] = acc[u];
    }
}

// ---------------- partial-plane reduction + sigmoid ----------------
__global__ void reduceP_sig(const float* __restrict__ pin, float* __restrict__ out,
                            int tot4, int P) {
    int idx = blockIdx.x * blockDim.x + threadIdx.x;
    if (idx >= tot4) return;
    const float4* p4 = (const float4*)pin;
    float4 a = p4[idx];
    for (int p = 1; p < P; ++p) {
        float4 v = p4[(size_t)p * tot4 + idx];
        a.x += v.x; a.y += v.y; a.z += v.z; a.w += v.w;
    }
    a.x = 1.f / (1.f + expf(-a.x));
    a.y = 1.f / (1.f + expf(-a.y));
    a.z = 1.f / (1.f + expf(-a.z));
    a.w = 1.f / (1.f + expf(-a.w));
    ((float4*)out)[idx] = a;
}

// ---------------- final interleave/shuffle ----------------
__global__ void shuffle_out_kernel(const float* __restrict__ sig, float* __restrict__ out) {
    int idx = blockIdx.x * blockDim.x + threadIdx.x;
    if (idx >= 64 * 768) return;
    int o = idx % 32;
    int j = (idx / 32) % 24;
    int b = idx / 768;
    const float* s = sig + (size_t)b * 64 * 23;
    float v;
    if (j == 0)       v = s[o * 23];
    else if (j == 23) v = s[(o + 32) * 23 + 22];
    else              v = 0.5f * (s[(o + 32) * 23 + (j - 1)] + s[o * 23 + j]);
    out[idx] = v;
}

extern "C" void kernel_launch(void* const* d_in, const int* in_sizes, int n_in,
                              void* d_out, int out_size, void* d_ws, size_t ws_size,
                              hipStream_t stream) {
    (void)in_sizes; (void)n_in; (void)out_size; (void)ws_size;

    const float* x = (const float*)d_in[0];
    const float* w[5]; const float* g[5]; const float* bb[5];
    for (int i = 0; i < 5; ++i) {
        w[i]  = (const float*)d_in[1 + 3 * i];
        g[i]  = (const float*)d_in[2 + 3 * i];
        bb[i] = (const float*)d_in[3 + 3 * i];
    }
    const float* w5 = (const float*)d_in[16];
    const float* lw = (const float*)d_in[17];
    float* out = (float*)d_out;

    // ---- workspace layout (~59 MB) ----
    float* ws   = (float*)d_ws;
    float* A    = ws;                          // 6,291,456 f32 (conv-out; L0 as u16)
    u16*   P    = (u16*)(ws + 6291456);        // 13,647,872 u16 max (padded inputs)
    u16*   wbf  = (u16*)(ws + 13115392);       // 697,344 u16
    float* part = ws + 13464064;               // 8,192 f32
    float* ss   = ws + 13472256;               // 2,048 f32
    u16*   w5b  = (u16*)(ws + 13474304);       // 1,032,192 u16
    u16*   ic   = (u16*)(ws + 13990400);       // 1,507,328 u16
    float* sub   = ws;                         // reuse A after im2col5
    float* pbufL = ws + 1572864;
    float* sig   = ws + 2359296;

    const size_t wofs[5] = {0, 1024, 9216, 41984, 173056};
    const int    Ks[5]   = {48, 256, 512, 1024, 2048};
    const int    Kps[5]  = {64, 256, 512, 1024, 2048};
    const int    Cos[5]  = {16, 32, 64, 128, 256};

    for (int L = 0; L < 5; ++L) {
        int tot = Cos[L] * Kps[L];
        hipLaunchKernelGGL(wcvt, dim3((tot + 255) / 256), dim3(256), 0, stream,
                           w[L], wbf + wofs[L], tot, Ks[L], Kps[L]);
    }
    hipLaunchKernelGGL(wcvtM, dim3((1008 * 1024) / 256), dim3(256), 0, stream,
                       w5, w5b, 1008 * 1024, 1024, 1000);

    // ---- x -> padded bf16 [64,4,66,776] (writes halos; no memset) ----
    hipLaunchKernelGGL(xpad_v, dim3(6402), dim3(256), 0, stream, x, P);

    // L0: conv -> bf16 A
    hipLaunchKernelGGL((conv_mfma<16, 4, 64, 64, 768, 66, 776, true>),
                       dim3(12288), dim3(256), 0, stream, P, wbf + wofs[0], A);
    hipLaunchKernelGGL((stats_bf<16, 12288>), dim3(256), dim3(256), 0, stream,
                       (const u16*)A, part);
    hipLaunchKernelGGL(bn_finalize, dim3(1), dim3(256), 0, stream,
                       part, g[0], bb[0], ss, 16, 1.f / 786432.f);
    hipLaunchKernelGGL((bn_pad_v<16, 32, 384, true>), dim3(6664), dim3(256), 0, stream,
                       (const void*)A, ss, P);

    // L1
    hipLaunchKernelGGL((conv_mfma<32, 16, 256, 32, 384, 34, 392, false>),
                       dim3(6144), dim3(256), 0, stream, P, wbf + wofs[1], A);
    hipLaunchKernelGGL((stats_f32<32, 3072>), dim3(512), dim3(256), 0, stream, A, part);
    hipLaunchKernelGGL(bn_finalize, dim3(1), dim3(256), 0, stream,
                       part, g[1], bb[1], ss, 32, 1.f / 196608.f);
    hipLaunchKernelGGL((bn_pad_v<32, 16, 192, false>), dim3(3600), dim3(256), 0, stream,
                       (const void*)A, ss, P);

    // L2
    hipLaunchKernelGGL((conv_mfma<64, 32, 512, 16, 192, 18, 200, false>),
                       dim3(3072), dim3(256), 0, stream, P, wbf + wofs[2], A);
    hipLaunchKernelGGL((stats_f32<64, 768>), dim3(1024), dim3(256), 0, stream, A, part);
    hipLaunchKernelGGL(bn_finalize, dim3(1), dim3(256), 0, stream,
                       part, g[2], bb[2], ss, 64, 1.f / 49152.f);
    hipLaunchKernelGGL((bn_pad_v<64, 8, 96, false>), dim3(2080), dim3(256), 0, stream,
                       (const void*)A, ss, P);

    // L3
    hipLaunchKernelGGL((conv_mfma<128, 64, 1024, 8, 96, 10, 104, false>),
                       dim3(1536), dim3(256), 0, stream, P, wbf + wofs[3], A);
    hipLaunchKernelGGL((stats_f32<128, 192>), dim3(2048), dim3(256), 0, stream, A, part);
    hipLaunchKernelGGL(bn_finalize, dim3(1), dim3(256), 0, stream,
                       part, g[3], bb[3], ss, 128, 1.f / 12288.f);
    hipLaunchKernelGGL((bn_pad_v<128, 4, 48, false>), dim3(1344), dim3(256), 0, stream,
                       (const void*)A, ss, P);

    // L4
    hipLaunchKernelGGL((conv_mfma<256, 128, 2048, 4, 48, 6, 56, false>),
                       dim3(768), dim3(256), 0, stream, P, wbf + wofs[4], A);
    hipLaunchKernelGGL((stats_f32<256, 48>), dim3(4096), dim3(256), 0, stream, A, part);
    hipLaunchKernelGGL(bn_finalize, dim3(1), dim3(256), 0, stream,
                       part, g[4], bb[4], ss, 256, 1.f / 3072.f);
    hipLaunchKernelGGL(im2col5, dim3((1472 * 1024) / 256), dim3(256), 0, stream,
                       A, ss, ic);

    // tail
    hipLaunchKernelGGL(conv5_mfma, dim3(1449), dim3(256), 0, stream, ic, w5b, sub);
    hipLaunchKernelGGL(linear_s, dim3(6, 64), dim3(256), 0, stream, sub, lw, pbufL);
    hipLaunchKernelGGL(reduceP_sig, dim3((23552 + 255) / 256), dim3(256), 0, stream,
                       pbufL, sig, 23552, 8);
    hipLaunchKernelGGL(shuffle_out_kernel, dim3((64 * 768 + 255) / 256), dim3(256), 0, stream,
                       sig, out);
}

// Round 9
// 337.891 us; speedup vs baseline: 13.9074x; 1.0385x over previous
//
#include <hip/hip_runtime.h>
#include <cmath>

#define EPS 1e-5f
#define SLOPE 0.2f

typedef unsigned short u16;
typedef unsigned int u32;
typedef __attribute__((ext_vector_type(8))) short bf16x8;
typedef __attribute__((ext_vector_type(8))) unsigned short u16x8;
typedef __attribute__((ext_vector_type(4))) float f32x4;

__device__ __forceinline__ u16 f2b(float f) {
    union { float f; u32 u; } v; v.f = f;
    u32 r = (v.u + 0x7FFF + ((v.u >> 16) & 1)) >> 16;
    return (u16)r;
}
__device__ __forceinline__ float b2f(u16 h) {
    union { u32 u; float f; } v; v.u = ((u32)h) << 16;
    return v.f;
}
__device__ __forceinline__ float leaky(float v) { return v >= 0.f ? v : SLOPE * v; }

// ---------------- weight fp32 -> bf16 (K padded with zeros) ----------------
__global__ void wcvt(const float* __restrict__ src, u16* __restrict__ dst,
                     int total, int K, int Kp) {
    int idx = blockIdx.x * blockDim.x + threadIdx.x;
    if (idx >= total) return;
    int k = idx % Kp;
    int co = idx / Kp;
    dst[idx] = (k < K) ? f2b(src[(size_t)co * K + k]) : (u16)0;
}

// weight fp32 -> bf16 with co zero-padding (rows co >= Com are zero)
__global__ void wcvtM(const float* __restrict__ src, u16* __restrict__ dst,
                      int total, int K, int Com) {
    int idx = blockIdx.x * blockDim.x + threadIdx.x;
    if (idx >= total) return;
    int k = idx % K;
    int co = idx / K;
    dst[idx] = (co < Com) ? f2b(src[(size_t)co * K + k]) : (u16)0;
}

// ---------------- x fp32 -> padded bf16 [64,4,66,776], vector stores ----------------
__global__ __launch_bounds__(256) void xpad_v(const float* __restrict__ x,
                                              u16* __restrict__ outp) {
    constexpr int H = 64, W = 768, G = 97, Wp = 776, Hp = 66;
    int idx = blockIdx.x * 256 + threadIdx.x;
    if (idx >= 64 * 4 * Hp * G) return;
    int m = idx % G;
    int hp = (idx / G) % Hp;
    int c = (idx / (G * Hp)) % 4;
    int b = idx / (G * Hp * 4);

    u16x8 o;
#pragma unroll
    for (int i = 0; i < 8; ++i) o[i] = 0;

    if (c < 3 && hp >= 1 && hp <= H) {
        const float* base = x + ((size_t)(b * 3 + c) * H + (hp - 1)) * W;
        if (m > 0) o[0] = f2b(base[8 * m - 1]);
        if (m < G - 1) {
            float4 a  = *(const float4*)(base + 8 * m);
            float4 b4 = *(const float4*)(base + 8 * m + 4);
            o[1] = f2b(a.x); o[2] = f2b(a.y); o[3] = f2b(a.z); o[4] = f2b(a.w);
            o[5] = f2b(b4.x); o[6] = f2b(b4.y); o[7] = f2b(b4.z);
        }
    }
    *(u16x8*)(outp + ((size_t)(b * 4 + c) * Hp + hp) * Wp + 8 * m) = o;
}

// ---------------- implicit-GEMM MFMA conv, MT m-tiles per wave ----------------
// B-fragment (input patch) loaded once per K-step, reused across MT MFMAs.
template <int Co, int CiPad, int Kp, int Hi, int Wi, int Hp, int Wp, int MT, bool OB>
__global__ __launch_bounds__(256) void conv_mfma(const u16* __restrict__ inp,
                                                 const u16* __restrict__ wt,
                                                 void* __restrict__ outv) {
    constexpr int Ho = Hi / 2, Wo = Wi / 2, HW = Ho * Wo;
    constexpr int MG = Co / 16 / MT;   // m-groups

    int tid = threadIdx.x;
    int wid = blockIdx.x * 4 + (tid >> 6);
    int lane = tid & 63;
    int r = lane & 15;
    int quad = lane >> 4;
    int mg = wid % MG;
    int nt = wid / MG;

    int n = nt * 16 + r;
    int b = n / HW;
    int hw = n % HW;
    int oh = hw / Wo;
    int ow = hw % Wo;

    int ciq = quad >> 1;
    int kh0 = (quad & 1) * 2;

    const u16* pB = inp + ((size_t)(b * CiPad + ciq) * Hp + (2 * oh + kh0)) * Wp + 2 * ow;
    const u16* pA = wt + (size_t)(mg * MT * 16 + r) * Kp + quad * 8;

    f32x4 acc[MT];
#pragma unroll
    for (int mt = 0; mt < MT; ++mt) acc[mt] = (f32x4){0.f, 0.f, 0.f, 0.f};

#pragma unroll 4
    for (int kk = 0; kk < Kp / 32; ++kk) {
        union { u32 u[4]; bf16x8 v; } bb;
        bb.u[0] = *(const u32*)(pB);
        bb.u[1] = *(const u32*)(pB + 2);
        bb.u[2] = *(const u32*)(pB + Wp);
        bb.u[3] = *(const u32*)(pB + Wp + 2);
#pragma unroll
        for (int mt = 0; mt < MT; ++mt) {
            bf16x8 a = *(const bf16x8*)(pA + (size_t)mt * 16 * Kp);
            acc[mt] = __builtin_amdgcn_mfma_f32_16x16x32_bf16(a, bb.v, acc[mt], 0, 0, 0);
        }
        pA += 32;
        pB += (size_t)2 * Hp * Wp;
    }

#pragma unroll
    for (int mt = 0; mt < MT; ++mt) {
        int co0 = mg * MT * 16 + mt * 16 + quad * 4;
        if (OB) {
            u16* o = (u16*)outv;
#pragma unroll
            for (int j = 0; j < 4; ++j)
                o[((size_t)b * Co + co0 + j) * HW + hw] = f2b(acc[mt][j]);
        } else {
            float* o = (float*)outv;
#pragma unroll
            for (int j = 0; j < 4; ++j)
                o[((size_t)b * Co + co0 + j) * HW + hw] = acc[mt][j];
        }
    }
}

// ---------------- BN stats: vectorized, division-free, deterministic ----------------
template <int C, int HW>
__global__ __launch_bounds__(256) void stats_bf(const u16* __restrict__ x,
                                                float* __restrict__ part) {
    int c = blockIdx.x >> 4;
    int chunk = blockIdx.x & 15;
    double s1 = 0.0, s2 = 0.0;
    for (int bi = 0; bi < 4; ++bi) {
        const u16* base = x + ((size_t)(chunk * 4 + bi) * C + c) * HW;
        for (int p = threadIdx.x * 8; p < HW; p += 2048) {
            bf16x8 v = *(const bf16x8*)(base + p);
#pragma unroll
            for (int e = 0; e < 8; ++e) {
                float f = b2f((u16)v[e]);
                s1 += f; s2 += (double)f * f;
            }
        }
    }
    __shared__ double sh1[256];
    __shared__ double sh2[256];
    int tid = threadIdx.x;
    sh1[tid] = s1; sh2[tid] = s2;
    __syncthreads();
    for (int s = 128; s > 0; s >>= 1) {
        if (tid < s) { sh1[tid] += sh1[tid + s]; sh2[tid] += sh2[tid + s]; }
        __syncthreads();
    }
    if (tid == 0) {
        part[((size_t)c * 16 + chunk) * 2 + 0] = (float)sh1[0];
        part[((size_t)c * 16 + chunk) * 2 + 1] = (float)sh2[0];
    }
}

template <int C, int HW>
__global__ __launch_bounds__(256) void stats_f32(const float* __restrict__ x,
                                                 float* __restrict__ part) {
    int c = blockIdx.x >> 4;
    int chunk = blockIdx.x & 15;
    double s1 = 0.0, s2 = 0.0;
    for (int bi = 0; bi < 4; ++bi) {
        const float* base = x + ((size_t)(chunk * 4 + bi) * C + c) * HW;
        for (int p = threadIdx.x * 4; p < HW; p += 1024) {
            float4 v = *(const float4*)(base + p);
            s1 += v.x; s2 += (double)v.x * v.x;
            s1 += v.y; s2 += (double)v.y * v.y;
            s1 += v.z; s2 += (double)v.z * v.z;
            s1 += v.w; s2 += (double)v.w * v.w;
        }
    }
    __shared__ double sh1[256];
    __shared__ double sh2[256];
    int tid = threadIdx.x;
    sh1[tid] = s1; sh2[tid] = s2;
    __syncthreads();
    for (int s = 128; s > 0; s >>= 1) {
        if (tid < s) { sh1[tid] += sh1[tid + s]; sh2[tid] += sh2[tid + s]; }
        __syncthreads();
    }
    if (tid == 0) {
        part[((size_t)c * 16 + chunk) * 2 + 0] = (float)sh1[0];
        part[((size_t)c * 16 + chunk) * 2 + 1] = (float)sh2[0];
    }
}

__global__ void bn_finalize(const float* __restrict__ part, const float* __restrict__ g,
                            const float* __restrict__ bb, float* __restrict__ ss,
                            int C, float invN) {
    int c = blockIdx.x * blockDim.x + threadIdx.x;
    if (c >= C) return;
    float s1 = 0.f, s2 = 0.f;
    for (int k = 0; k < 16; ++k) {
        s1 += part[((size_t)c * 16 + k) * 2 + 0];
        s2 += part[((size_t)c * 16 + k) * 2 + 1];
    }
    float mean = s1 * invN;
    float var  = s2 * invN - mean * mean;
    float inv  = rsqrtf(var + EPS);
    float sc   = inv * g[c];
    ss[c]     = sc;
    ss[C + c] = bb[c] - mean * sc;
}

// ---------------- BN + leaky + padded bf16 write, aligned 16B vector stores ----------------
template <int C, int H, int W, bool INB>
__global__ __launch_bounds__(256) void bn_pad_v(const void* __restrict__ in,
                                                const float* __restrict__ ss,
                                                u16* __restrict__ outp) {
    constexpr int G = W / 8 + 1;
    constexpr int Wp = 8 * G;
    constexpr int Hp = H + 2;
    int idx = blockIdx.x * 256 + threadIdx.x;
    if (idx >= 64 * C * Hp * G) return;
    int m = idx % G;
    int hp = (idx / G) % Hp;
    int c = (idx / (G * Hp)) % C;
    int b = idx / (G * Hp * C);

    u16x8 o;
#pragma unroll
    for (int i = 0; i < 8; ++i) o[i] = 0;

    if (hp >= 1 && hp <= H) {
        float sc = ss[c], sh = ss[C + c];
        float vals[8];
        if (INB) {
            const u16* base = (const u16*)in + ((size_t)(b * C + c) * H + (hp - 1)) * W;
            vals[0] = (m > 0) ? b2f(base[8 * m - 1]) : 0.f;
            if (m < G - 1) {
                bf16x8 va = *(const bf16x8*)(base + 8 * m);
#pragma unroll
                for (int i = 0; i < 7; ++i) vals[i + 1] = b2f((u16)va[i]);
            }
        } else {
            const float* base = (const float*)in + ((size_t)(b * C + c) * H + (hp - 1)) * W;
            vals[0] = (m > 0) ? base[8 * m - 1] : 0.f;
            if (m < G - 1) {
                float4 a  = *(const float4*)(base + 8 * m);
                float4 b4 = *(const float4*)(base + 8 * m + 4);
                vals[1] = a.x; vals[2] = a.y; vals[3] = a.z; vals[4] = a.w;
                vals[5] = b4.x; vals[6] = b4.y; vals[7] = b4.z;
            }
        }
        if (m > 0) o[0] = f2b(leaky(vals[0] * sc + sh));
        if (m < G - 1) {
#pragma unroll
            for (int i = 1; i < 8; ++i) o[i] = f2b(leaky(vals[i] * sc + sh));
        }
    }
    *(u16x8*)(outp + ((size_t)(b * C + c) * Hp + hp) * Wp + 8 * m) = o;
}

// ---------------- L4: BN + leaky + im2col bf16 for conv5 ----------------
__global__ void im2col5(const float* __restrict__ A, const float* __restrict__ ss,
                        u16* __restrict__ ic) {
    int idx = blockIdx.x * blockDim.x + threadIdx.x;
    if (idx >= 1472 * 1024) return;
    int k = idx & 1023;
    int n = idx >> 10;
    int b = n / 23, j = n % 23;
    int ci = k >> 2, kh = (k >> 1) & 1, kw = k & 1;
    float v = A[(size_t)b * 12288 + ci * 48 + kh * 24 + j + kw];
    v = leaky(v * ss[ci] + ss[256 + ci]);
    ic[idx] = f2b(v);
}

// ---------------- conv5 GEMM: [1024 x 1024] x [1024 x 1472], 32x32 per wave ----------------
// 4 waves/block as 2x2 -> 64x64 block tile. A/B frags reused 2x each.
__global__ __launch_bounds__(256) void conv5_mfma2(const u16* __restrict__ ic,
                                                   const u16* __restrict__ w5b,
                                                   float* __restrict__ sub) {
    int tid = threadIdx.x;
    int wave = tid >> 6;
    int lane = tid & 63;
    int r = lane & 15;
    int quad = lane >> 4;
    int gx = blockIdx.x % 23;      // n-block (64)
    int gy = blockIdx.x / 23;      // m-block (64), 0..15
    int m0 = gy * 64 + (wave >> 1) * 32;
    int n0 = gx * 64 + (wave & 1) * 32;

    const u16* pA0 = w5b + (size_t)(m0 + r) * 1024 + quad * 8;
    const u16* pA1 = pA0 + 16 * 1024;
    const u16* pB0 = ic + (size_t)(n0 + r) * 1024 + quad * 8;
    const u16* pB1 = pB0 + 16 * 1024;

    f32x4 a00 = {0.f,0.f,0.f,0.f}, a01 = {0.f,0.f,0.f,0.f};
    f32x4 a10 = {0.f,0.f,0.f,0.f}, a11 = {0.f,0.f,0.f,0.f};

#pragma unroll 4
    for (int kk = 0; kk < 32; ++kk) {
        bf16x8 fa0 = *(const bf16x8*)pA0;
        bf16x8 fa1 = *(const bf16x8*)pA1;
        bf16x8 fb0 = *(const bf16x8*)pB0;
        bf16x8 fb1 = *(const bf16x8*)pB1;
        a00 = __builtin_amdgcn_mfma_f32_16x16x32_bf16(fa0, fb0, a00, 0, 0, 0);
        a01 = __builtin_amdgcn_mfma_f32_16x16x32_bf16(fa0, fb1, a01, 0, 0, 0);
        a10 = __builtin_amdgcn_mfma_f32_16x16x32_bf16(fa1, fb0, a10, 0, 0, 0);
        a11 = __builtin_amdgcn_mfma_f32_16x16x32_bf16(fa1, fb1, a11, 0, 0, 0);
        pA0 += 32; pA1 += 32; pB0 += 32; pB1 += 32;
    }

    // epilogue: co = m0 + mi*16 + quad*4 + j ; n = n0 + ni*16 + r
#pragma unroll
    for (int mi = 0; mi < 2; ++mi) {
#pragma unroll
        for (int ni = 0; ni < 2; ++ni) {
            f32x4 acc = (mi == 0) ? (ni == 0 ? a00 : a01) : (ni == 0 ? a10 : a11);
            int n = n0 + ni * 16 + r;
            int b = n / 23, jc = n % 23;
#pragma unroll
            for (int j = 0; j < 4; ++j) {
                int co = m0 + mi * 16 + quad * 4 + j;
                if (co < 1000)
                    sub[(size_t)b * 23000 + (size_t)co * 23 + jc] = leaky(acc[j]);
            }
        }
    }
}

// ---------------- linear (1000->64), spatial-lane, K-split ----------------
__global__ __launch_bounds__(256) void linear_s(const float* __restrict__ sub,
                                                const float* __restrict__ lw,
                                                float* __restrict__ pout) {
    int s = blockIdx.x * 256 + threadIdx.x;
    int j = s % 24;
    int b = s / 24;
    int ct = blockIdx.y % 8;
    int p  = blockIdx.y / 8;
    int o0 = ct * 8;
    bool jv = j < 23;
    int jc = jv ? j : 22;

    const float* sp = sub + (size_t)b * 23000 + jc;
    float acc[8];
#pragma unroll
    for (int u = 0; u < 8; ++u) acc[u] = 0.f;

    int c0 = p * 125;
    for (int c = c0; c < c0 + 125; ++c) {
        float v = sp[(size_t)c * 23];
#pragma unroll
        for (int u = 0; u < 8; ++u)
            acc[u] = fmaf(v, lw[(size_t)(o0 + u) * 1000 + c], acc[u]);
    }
    if (jv) {
#pragma unroll
        for (int u = 0; u < 8; ++u)
            pout[(size_t)p * 94208 + ((size_t)b * 64 + o0 + u) * 23 + j] = acc[u];
    }
}

// ---------------- partial-plane reduction + sigmoid ----------------
__global__ void reduceP_sig(const float* __restrict__ pin, float* __restrict__ out,
                            int tot4, int P) {
    int idx = blockIdx.x * blockDim.x + threadIdx.x;
    if (idx >= tot4) return;
    const float4* p4 = (const float4*)pin;
    float4 a = p4[idx];
    for (int p = 1; p < P; ++p) {
        float4 v = p4[(size_t)p * tot4 + idx];
        a.x += v.x; a.y += v.y; a.z += v.z; a.w += v.w;
    }
    a.x = 1.f / (1.f + expf(-a.x));
    a.y = 1.f / (1.f + expf(-a.y));
    a.z = 1.f / (1.f + expf(-a.z));
    a.w = 1.f / (1.f + expf(-a.w));
    ((float4*)out)[idx] = a;
}

// ---------------- final interleave/shuffle ----------------
__global__ void shuffle_out_kernel(const float* __restrict__ sig, float* __restrict__ out) {
    int idx = blockIdx.x * blockDim.x + threadIdx.x;
    if (idx >= 64 * 768) return;
    int o = idx % 32;
    int j = (idx / 32) % 24;
    int b = idx / 768;
    const float* s = sig + (size_t)b * 64 * 23;
    float v;
    if (j == 0)       v = s[o * 23];
    else if (j == 23) v = s[(o + 32) * 23 + 22];
    else              v = 0.5f * (s[(o + 32) * 23 + (j - 1)] + s[o * 23 + j]);
    out[idx] = v;
}

extern "C" void kernel_launch(void* const* d_in, const int* in_sizes, int n_in,
                              void* d_out, int out_size, void* d_ws, size_t ws_size,
                              hipStream_t stream) {
    (void)in_sizes; (void)n_in; (void)out_size; (void)ws_size;

    const float* x = (const float*)d_in[0];
    const float* w[5]; const float* g[5]; const float* bb[5];
    for (int i = 0; i < 5; ++i) {
        w[i]  = (const float*)d_in[1 + 3 * i];
        g[i]  = (const float*)d_in[2 + 3 * i];
        bb[i] = (const float*)d_in[3 + 3 * i];
    }
    const float* w5 = (const float*)d_in[16];
    const float* lw = (const float*)d_in[17];
    float* out = (float*)d_out;

    // ---- workspace layout (~59 MB) ----
    float* ws   = (float*)d_ws;
    float* A    = ws;                          // 6,291,456 f32 (conv-out; L0 as u16)
    u16*   P    = (u16*)(ws + 6291456);        // up to 13,647,872 u16 (padded inputs)
    u16*   wbf  = (u16*)(ws + 13115392);       // 697,344 u16
    float* part = ws + 13464064;               // 8,192 f32
    float* ss   = ws + 13472256;               // 2,048 f32
    u16*   w5b  = (u16*)(ws + 13474304);       // 1,048,576 u16 (w5 padded to 1024 rows)
    u16*   ic   = (u16*)(ws + 13998592);       // 1,507,328 u16
    float* sub   = ws;                         // reuse A after im2col5
    float* pbufL = ws + 1572864;
    float* sig   = ws + 2359296;

    const size_t wofs[5] = {0, 1024, 9216, 41984, 173056};
    const int    Ks[5]   = {48, 256, 512, 1024, 2048};
    const int    Kps[5]  = {64, 256, 512, 1024, 2048};
    const int    Cos[5]  = {16, 32, 64, 128, 256};

    for (int L = 0; L < 5; ++L) {
        int tot = Cos[L] * Kps[L];
        hipLaunchKernelGGL(wcvt, dim3((tot + 255) / 256), dim3(256), 0, stream,
                           w[L], wbf + wofs[L], tot, Ks[L], Kps[L]);
    }
    hipLaunchKernelGGL(wcvtM, dim3((1024 * 1024) / 256), dim3(256), 0, stream,
                       w5, w5b, 1024 * 1024, 1024, 1000);

    // ---- x -> padded bf16 [64,4,66,776] (writes halos; no memset) ----
    hipLaunchKernelGGL(xpad_v, dim3(6402), dim3(256), 0, stream, x, P);

    // L0: conv -> bf16 A   (N16 = 49152, MG=1 -> blocks 12288)
    hipLaunchKernelGGL((conv_mfma<16, 4, 64, 64, 768, 66, 776, 1, true>),
                       dim3(12288), dim3(256), 0, stream, P, wbf + wofs[0], A);
    hipLaunchKernelGGL((stats_bf<16, 12288>), dim3(256), dim3(256), 0, stream,
                       (const u16*)A, part);
    hipLaunchKernelGGL(bn_finalize, dim3(1), dim3(256), 0, stream,
                       part, g[0], bb[0], ss, 16, 1.f / 786432.f);
    hipLaunchKernelGGL((bn_pad_v<16, 32, 384, true>), dim3(6664), dim3(256), 0, stream,
                       (const void*)A, ss, P);

    // L1: MT=2, MG=1, N16=12288 -> blocks 3072
    hipLaunchKernelGGL((conv_mfma<32, 16, 256, 32, 384, 34, 392, 2, false>),
                       dim3(3072), dim3(256), 0, stream, P, wbf + wofs[1], A);
    hipLaunchKernelGGL((stats_f32<32, 3072>), dim3(512), dim3(256), 0, stream, A, part);
    hipLaunchKernelGGL(bn_finalize, dim3(1), dim3(256), 0, stream,
                       part, g[1], bb[1], ss, 32, 1.f / 196608.f);
    hipLaunchKernelGGL((bn_pad_v<32, 16, 192, false>), dim3(3600), dim3(256), 0, stream,
                       (const void*)A, ss, P);

    // L2: MT=4, MG=1, N16=3072 -> blocks 768
    hipLaunchKernelGGL((conv_mfma<64, 32, 512, 16, 192, 18, 200, 4, false>),
                       dim3(768), dim3(256), 0, stream, P, wbf + wofs[2], A);
    hipLaunchKernelGGL((stats_f32<64, 768>), dim3(1024), dim3(256), 0, stream, A, part);
    hipLaunchKernelGGL(bn_finalize, dim3(1), dim3(256), 0, stream,
                       part, g[2], bb[2], ss, 64, 1.f / 49152.f);
    hipLaunchKernelGGL((bn_pad_v<64, 8, 96, false>), dim3(2080), dim3(256), 0, stream,
                       (const void*)A, ss, P);

    // L3: MT=4, MG=2, N16=768 -> wid 1536, blocks 384
    hipLaunchKernelGGL((conv_mfma<128, 64, 1024, 8, 96, 10, 104, 4, false>),
                       dim3(384), dim3(256), 0, stream, P, wbf + wofs[3], A);
    hipLaunchKernelGGL((stats_f32<128, 192>), dim3(2048), dim3(256), 0, stream, A, part);
    hipLaunchKernelGGL(bn_finalize, dim3(1), dim3(256), 0, stream,
                       part, g[3], bb[3], ss, 128, 1.f / 12288.f);
    hipLaunchKernelGGL((bn_pad_v<128, 4, 48, false>), dim3(1344), dim3(256), 0, stream,
                       (const void*)A, ss, P);

    // L4: MT=4, MG=4, N16=192 -> wid 768, blocks 192
    hipLaunchKernelGGL((conv_mfma<256, 128, 2048, 4, 48, 6, 56, 4, false>),
                       dim3(192), dim3(256), 0, stream, P, wbf + wofs[4], A);
    hipLaunchKernelGGL((stats_f32<256, 48>), dim3(4096), dim3(256), 0, stream, A, part);
    hipLaunchKernelGGL(bn_finalize, dim3(1), dim3(256), 0, stream,
                       part, g[4], bb[4], ss, 256, 1.f / 3072.f);
    hipLaunchKernelGGL(im2col5, dim3((1472 * 1024) / 256), dim3(256), 0, stream,
                       A, ss, ic);

    // tail: conv5 GEMM (368 blocks), linear, sigmoid-reduce, shuffle
    hipLaunchKernelGGL(conv5_mfma2, dim3(368), dim3(256), 0, stream, ic, w5b, sub);
    hipLaunchKernelGGL(linear_s, dim3(6, 64), dim3(256), 0, stream, sub, lw, pbufL);
    hipLaunchKernelGGL(reduceP_sig, dim3((23552 + 255) / 256), dim3(256), 0, stream,
                       pbufL, sig, 23552, 8);
    hipLaunchKernelGGL(shuffle_out_kernel, dim3((64 * 768 + 255) / 256), dim3(256), 0, stream,
                       sig, out);
}

// Round 10
// 308.454 us; speedup vs baseline: 15.2346x; 1.0954x over previous
//
#include <hip/hip_runtime.h>
#include <cmath>

#define EPS 1e-5f
#define SLOPE 0.2f

typedef unsigned short u16;
typedef unsigned int u32;
typedef __attribute__((ext_vector_type(8))) short bf16x8;
typedef __attribute__((ext_vector_type(8))) unsigned short u16x8;
typedef __attribute__((ext_vector_type(4))) unsigned short u16x4;
typedef __attribute__((ext_vector_type(4))) float f32x4;

__device__ __forceinline__ u16 f2b(float f) {
    union { float f; u32 u; } v; v.f = f;
    u32 r = (v.u + 0x7FFF + ((v.u >> 16) & 1)) >> 16;
    return (u16)r;
}
__device__ __forceinline__ float b2f(u16 h) {
    union { u32 u; float f; } v; v.u = ((u32)h) << 16;
    return v.f;
}
__device__ __forceinline__ float leaky(float v) { return v >= 0.f ? v : SLOPE * v; }

// ---------------- weight fp32 -> bf16 (K padded with zeros) ----------------
__global__ void wcvt(const float* __restrict__ src, u16* __restrict__ dst,
                     int total, int K, int Kp) {
    int idx = blockIdx.x * blockDim.x + threadIdx.x;
    if (idx >= total) return;
    int k = idx % Kp;
    int co = idx / Kp;
    dst[idx] = (k < K) ? f2b(src[(size_t)co * K + k]) : (u16)0;
}

// weight fp32 -> bf16 with co zero-padding (rows co >= Com are zero)
__global__ void wcvtM(const float* __restrict__ src, u16* __restrict__ dst,
                      int total, int K, int Com) {
    int idx = blockIdx.x * blockDim.x + threadIdx.x;
    if (idx >= total) return;
    int k = idx % K;
    int co = idx / K;
    dst[idx] = (co < Com) ? f2b(src[(size_t)co * K + k]) : (u16)0;
}

// ---------------- x fp32 -> padded bf16 [64,4,66,776], vector stores ----------------
__global__ __launch_bounds__(256) void xpad_v(const float* __restrict__ x,
                                              u16* __restrict__ outp) {
    constexpr int H = 64, W = 768, G = 97, Wp = 776, Hp = 66;
    int idx = blockIdx.x * 256 + threadIdx.x;
    if (idx >= 64 * 4 * Hp * G) return;
    int m = idx % G;
    int hp = (idx / G) % Hp;
    int c = (idx / (G * Hp)) % 4;
    int b = idx / (G * Hp * 4);

    u16x8 o;
#pragma unroll
    for (int i = 0; i < 8; ++i) o[i] = 0;

    if (c < 3 && hp >= 1 && hp <= H) {
        const float* base = x + ((size_t)(b * 3 + c) * H + (hp - 1)) * W;
        if (m > 0) o[0] = f2b(base[8 * m - 1]);
        if (m < G - 1) {
            float4 a  = *(const float4*)(base + 8 * m);
            float4 b4 = *(const float4*)(base + 8 * m + 4);
            o[1] = f2b(a.x); o[2] = f2b(a.y); o[3] = f2b(a.z); o[4] = f2b(a.w);
            o[5] = f2b(b4.x); o[6] = f2b(b4.y); o[7] = f2b(b4.z);
        }
    }
    *(u16x8*)(outp + ((size_t)(b * 4 + c) * Hp + hp) * Wp + 8 * m) = o;
}

// ---------------- implicit-GEMM MFMA conv, MT m-tiles per wave ----------------
template <int Co, int CiPad, int Kp, int Hi, int Wi, int Hp, int Wp, int MT, bool OB>
__global__ __launch_bounds__(256) void conv_mfma(const u16* __restrict__ inp,
                                                 const u16* __restrict__ wt,
                                                 void* __restrict__ outv) {
    constexpr int Ho = Hi / 2, Wo = Wi / 2, HW = Ho * Wo;
    constexpr int MG = Co / 16 / MT;   // m-groups

    int tid = threadIdx.x;
    int wid = blockIdx.x * 4 + (tid >> 6);
    int lane = tid & 63;
    int r = lane & 15;
    int quad = lane >> 4;
    int mg = wid % MG;
    int nt = wid / MG;

    int n = nt * 16 + r;
    int b = n / HW;
    int hw = n % HW;
    int oh = hw / Wo;
    int ow = hw % Wo;

    int ciq = quad >> 1;
    int kh0 = (quad & 1) * 2;

    const u16* pB = inp + ((size_t)(b * CiPad + ciq) * Hp + (2 * oh + kh0)) * Wp + 2 * ow;
    const u16* pA = wt + (size_t)(mg * MT * 16 + r) * Kp + quad * 8;

    f32x4 acc[MT];
#pragma unroll
    for (int mt = 0; mt < MT; ++mt) acc[mt] = (f32x4){0.f, 0.f, 0.f, 0.f};

#pragma unroll 4
    for (int kk = 0; kk < Kp / 32; ++kk) {
        union { u32 u[4]; bf16x8 v; } bb;
        bb.u[0] = *(const u32*)(pB);
        bb.u[1] = *(const u32*)(pB + 2);
        bb.u[2] = *(const u32*)(pB + Wp);
        bb.u[3] = *(const u32*)(pB + Wp + 2);
#pragma unroll
        for (int mt = 0; mt < MT; ++mt) {
            bf16x8 a = *(const bf16x8*)(pA + (size_t)mt * 16 * Kp);
            acc[mt] = __builtin_amdgcn_mfma_f32_16x16x32_bf16(a, bb.v, acc[mt], 0, 0, 0);
        }
        pA += 32;
        pB += (size_t)2 * Hp * Wp;
    }

#pragma unroll
    for (int mt = 0; mt < MT; ++mt) {
        int co0 = mg * MT * 16 + mt * 16 + quad * 4;
        if (OB) {
            u16* o = (u16*)outv;
#pragma unroll
            for (int j = 0; j < 4; ++j)
                o[((size_t)b * Co + co0 + j) * HW + hw] = f2b(acc[mt][j]);
        } else {
            float* o = (float*)outv;
#pragma unroll
            for (int j = 0; j < 4; ++j)
                o[((size_t)b * Co + co0 + j) * HW + hw] = acc[mt][j];
        }
    }
}

// ---------------- BN stats: vectorized, division-free, deterministic ----------------
template <int C, int HW>
__global__ __launch_bounds__(256) void stats_bf(const u16* __restrict__ x,
                                                float* __restrict__ part) {
    int c = blockIdx.x >> 4;
    int chunk = blockIdx.x & 15;
    double s1 = 0.0, s2 = 0.0;
    for (int bi = 0; bi < 4; ++bi) {
        const u16* base = x + ((size_t)(chunk * 4 + bi) * C + c) * HW;
        for (int p = threadIdx.x * 8; p < HW; p += 2048) {
            bf16x8 v = *(const bf16x8*)(base + p);
#pragma unroll
            for (int e = 0; e < 8; ++e) {
                float f = b2f((u16)v[e]);
                s1 += f; s2 += (double)f * f;
            }
        }
    }
    __shared__ double sh1[256];
    __shared__ double sh2[256];
    int tid = threadIdx.x;
    sh1[tid] = s1; sh2[tid] = s2;
    __syncthreads();
    for (int s = 128; s > 0; s >>= 1) {
        if (tid < s) { sh1[tid] += sh1[tid + s]; sh2[tid] += sh2[tid + s]; }
        __syncthreads();
    }
    if (tid == 0) {
        part[((size_t)c * 16 + chunk) * 2 + 0] = (float)sh1[0];
        part[((size_t)c * 16 + chunk) * 2 + 1] = (float)sh2[0];
    }
}

template <int C, int HW>
__global__ __launch_bounds__(256) void stats_f32(const float* __restrict__ x,
                                                 float* __restrict__ part) {
    int c = blockIdx.x >> 4;
    int chunk = blockIdx.x & 15;
    double s1 = 0.0, s2 = 0.0;
    for (int bi = 0; bi < 4; ++bi) {
        const float* base = x + ((size_t)(chunk * 4 + bi) * C + c) * HW;
        for (int p = threadIdx.x * 4; p < HW; p += 1024) {
            float4 v = *(const float4*)(base + p);
            s1 += v.x; s2 += (double)v.x * v.x;
            s1 += v.y; s2 += (double)v.y * v.y;
            s1 += v.z; s2 += (double)v.z * v.z;
            s1 += v.w; s2 += (double)v.w * v.w;
        }
    }
    __shared__ double sh1[256];
    __shared__ double sh2[256];
    int tid = threadIdx.x;
    sh1[tid] = s1; sh2[tid] = s2;
    __syncthreads();
    for (int s = 128; s > 0; s >>= 1) {
        if (tid < s) { sh1[tid] += sh1[tid + s]; sh2[tid] += sh2[tid + s]; }
        __syncthreads();
    }
    if (tid == 0) {
        part[((size_t)c * 16 + chunk) * 2 + 0] = (float)sh1[0];
        part[((size_t)c * 16 + chunk) * 2 + 1] = (float)sh2[0];
    }
}

__global__ void bn_finalize(const float* __restrict__ part, const float* __restrict__ g,
                            const float* __restrict__ bb, float* __restrict__ ss,
                            int C, float invN) {
    int c = blockIdx.x * blockDim.x + threadIdx.x;
    if (c >= C) return;
    float s1 = 0.f, s2 = 0.f;
    for (int k = 0; k < 16; ++k) {
        s1 += part[((size_t)c * 16 + k) * 2 + 0];
        s2 += part[((size_t)c * 16 + k) * 2 + 1];
    }
    float mean = s1 * invN;
    float var  = s2 * invN - mean * mean;
    float inv  = rsqrtf(var + EPS);
    float sc   = inv * g[c];
    ss[c]     = sc;
    ss[C + c] = bb[c] - mean * sc;
}

// ---------------- BN + leaky + padded bf16 write, aligned 16B vector stores ----------------
template <int C, int H, int W, bool INB>
__global__ __launch_bounds__(256) void bn_pad_v(const void* __restrict__ in,
                                                const float* __restrict__ ss,
                                                u16* __restrict__ outp) {
    constexpr int G = W / 8 + 1;
    constexpr int Wp = 8 * G;
    constexpr int Hp = H + 2;
    int idx = blockIdx.x * 256 + threadIdx.x;
    if (idx >= 64 * C * Hp * G) return;
    int m = idx % G;
    int hp = (idx / G) % Hp;
    int c = (idx / (G * Hp)) % C;
    int b = idx / (G * Hp * C);

    u16x8 o;
#pragma unroll
    for (int i = 0; i < 8; ++i) o[i] = 0;

    if (hp >= 1 && hp <= H) {
        float sc = ss[c], sh = ss[C + c];
        float vals[8];
        if (INB) {
            const u16* base = (const u16*)in + ((size_t)(b * C + c) * H + (hp - 1)) * W;
            vals[0] = (m > 0) ? b2f(base[8 * m - 1]) : 0.f;
            if (m < G - 1) {
                bf16x8 va = *(const bf16x8*)(base + 8 * m);
#pragma unroll
                for (int i = 0; i < 7; ++i) vals[i + 1] = b2f((u16)va[i]);
            }
        } else {
            const float* base = (const float*)in + ((size_t)(b * C + c) * H + (hp - 1)) * W;
            vals[0] = (m > 0) ? base[8 * m - 1] : 0.f;
            if (m < G - 1) {
                float4 a  = *(const float4*)(base + 8 * m);
                float4 b4 = *(const float4*)(base + 8 * m + 4);
                vals[1] = a.x; vals[2] = a.y; vals[3] = a.z; vals[4] = a.w;
                vals[5] = b4.x; vals[6] = b4.y; vals[7] = b4.z;
            }
        }
        if (m > 0) o[0] = f2b(leaky(vals[0] * sc + sh));
        if (m < G - 1) {
#pragma unroll
            for (int i = 1; i < 8; ++i) o[i] = f2b(leaky(vals[i] * sc + sh));
        }
    }
    *(u16x8*)(outp + ((size_t)(b * C + c) * Hp + hp) * Wp + 8 * m) = o;
}

// ---------------- L4: BN + leaky + im2col bf16 for conv5 ----------------
__global__ void im2col5(const float* __restrict__ A, const float* __restrict__ ss,
                        u16* __restrict__ ic) {
    int idx = blockIdx.x * blockDim.x + threadIdx.x;
    if (idx >= 1472 * 1024) return;
    int k = idx & 1023;
    int n = idx >> 10;
    int b = n / 23, j = n % 23;
    int ci = k >> 2, kh = (k >> 1) & 1, kw = k & 1;
    float v = A[(size_t)b * 12288 + ci * 48 + kh * 24 + j + kw];
    v = leaky(v * ss[ci] + ss[256 + ci]);
    ic[idx] = f2b(v);
}

// ---------------- conv5 GEMM: [1024 x 1024] x [1024 x 1472], 32x32 per wave ----------------
// Epilogue: leaky + bf16 write to ic2[n][1024] (B-matrix layout for linear GEMM).
__global__ __launch_bounds__(256) void conv5_mfma2(const u16* __restrict__ ic,
                                                   const u16* __restrict__ w5b,
                                                   u16* __restrict__ ic2) {
    int tid = threadIdx.x;
    int wave = tid >> 6;
    int lane = tid & 63;
    int r = lane & 15;
    int quad = lane >> 4;
    int gx = blockIdx.x % 23;      // n-block (64)
    int gy = blockIdx.x / 23;      // m-block (64), 0..15
    int m0 = gy * 64 + (wave >> 1) * 32;
    int n0 = gx * 64 + (wave & 1) * 32;

    const u16* pA0 = w5b + (size_t)(m0 + r) * 1024 + quad * 8;
    const u16* pA1 = pA0 + 16 * 1024;
    const u16* pB0 = ic + (size_t)(n0 + r) * 1024 + quad * 8;
    const u16* pB1 = pB0 + 16 * 1024;

    f32x4 a00 = {0.f,0.f,0.f,0.f}, a01 = {0.f,0.f,0.f,0.f};
    f32x4 a10 = {0.f,0.f,0.f,0.f}, a11 = {0.f,0.f,0.f,0.f};

#pragma unroll 4
    for (int kk = 0; kk < 32; ++kk) {
        bf16x8 fa0 = *(const bf16x8*)pA0;
        bf16x8 fa1 = *(const bf16x8*)pA1;
        bf16x8 fb0 = *(const bf16x8*)pB0;
        bf16x8 fb1 = *(const bf16x8*)pB1;
        a00 = __builtin_amdgcn_mfma_f32_16x16x32_bf16(fa0, fb0, a00, 0, 0, 0);
        a01 = __builtin_amdgcn_mfma_f32_16x16x32_bf16(fa0, fb1, a01, 0, 0, 0);
        a10 = __builtin_amdgcn_mfma_f32_16x16x32_bf16(fa1, fb0, a10, 0, 0, 0);
        a11 = __builtin_amdgcn_mfma_f32_16x16x32_bf16(fa1, fb1, a11, 0, 0, 0);
        pA0 += 32; pA1 += 32; pB0 += 32; pB1 += 32;
    }

    // co0..co0+3 contiguous -> one 8B bf16 store per (mi,ni)
#pragma unroll
    for (int mi = 0; mi < 2; ++mi) {
#pragma unroll
        for (int ni = 0; ni < 2; ++ni) {
            f32x4 acc = (mi == 0) ? (ni == 0 ? a00 : a01) : (ni == 0 ? a10 : a11);
            int n = n0 + ni * 16 + r;
            int co0 = m0 + mi * 16 + quad * 4;
            u16x4 pk;
#pragma unroll
            for (int j = 0; j < 4; ++j) pk[j] = f2b(leaky(acc[j]));
            *(u16x4*)(ic2 + (size_t)n * 1024 + co0) = pk;
        }
    }
}

// ---------------- linear as MFMA GEMM [64 x 1024] x [1024 x 1472] + sigmoid ----------------
// A = lwb bf16 [64][1024] (K zero-padded); B = ic2 [1472][1024]. Writes sig fp32 [64,64,23].
__global__ __launch_bounds__(256) void linear_mfma(const u16* __restrict__ ic2,
                                                   const u16* __restrict__ lwb,
                                                   float* __restrict__ sig) {
    int tid = threadIdx.x;
    int wid = blockIdx.x * 4 + (tid >> 6);
    int lane = tid & 63;
    int r = lane & 15;
    int quad = lane >> 4;
    int mt = wid & 3;           // 4 m-tiles (64 rows)
    int nt = wid >> 2;          // 92 n-tiles

    int n = nt * 16 + r;
    const u16* pA = lwb + (size_t)(mt * 16 + r) * 1024 + quad * 8;
    const u16* pB = ic2 + (size_t)n * 1024 + quad * 8;

    f32x4 acc = {0.f, 0.f, 0.f, 0.f};
#pragma unroll 4
    for (int kk = 0; kk < 32; ++kk) {
        bf16x8 a = *(const bf16x8*)pA;
        bf16x8 bv = *(const bf16x8*)pB;
        acc = __builtin_amdgcn_mfma_f32_16x16x32_bf16(a, bv, acc, 0, 0, 0);
        pA += 32;
        pB += 32;
    }

    int b = n / 23, j = n % 23;
#pragma unroll
    for (int jj = 0; jj < 4; ++jj) {
        int o = mt * 16 + quad * 4 + jj;
        float v = 1.f / (1.f + expf(-acc[jj]));
        sig[(size_t)b * 1472 + (size_t)o * 23 + j] = v;
    }
}

// ---------------- final interleave/shuffle ----------------
__global__ void shuffle_out_kernel(const float* __restrict__ sig, float* __restrict__ out) {
    int idx = blockIdx.x * blockDim.x + threadIdx.x;
    if (idx >= 64 * 768) return;
    int o = idx % 32;
    int j = (idx / 32) % 24;
    int b = idx / 768;
    const float* s = sig + (size_t)b * 64 * 23;
    float v;
    if (j == 0)       v = s[o * 23];
    else if (j == 23) v = s[(o + 32) * 23 + 22];
    else              v = 0.5f * (s[(o + 32) * 23 + (j - 1)] + s[o * 23 + j]);
    out[idx] = v;
}

extern "C" void kernel_launch(void* const* d_in, const int* in_sizes, int n_in,
                              void* d_out, int out_size, void* d_ws, size_t ws_size,
                              hipStream_t stream) {
    (void)in_sizes; (void)n_in; (void)out_size; (void)ws_size;

    const float* x = (const float*)d_in[0];
    const float* w[5]; const float* g[5]; const float* bb[5];
    for (int i = 0; i < 5; ++i) {
        w[i]  = (const float*)d_in[1 + 3 * i];
        g[i]  = (const float*)d_in[2 + 3 * i];
        bb[i] = (const float*)d_in[3 + 3 * i];
    }
    const float* w5 = (const float*)d_in[16];
    const float* lw = (const float*)d_in[17];
    float* out = (float*)d_out;

    // ---- workspace layout (~60 MB) ----
    float* ws   = (float*)d_ws;
    float* A    = ws;                          // 6,291,456 f32 (conv-out; L0 as u16)
    u16*   P    = (u16*)(ws + 6291456);        // up to 13,647,872 u16 (padded inputs)
    u16*   wbf  = (u16*)(ws + 13115392);       // 697,344 u16
    float* part = ws + 13464064;               // 8,192 f32
    float* ss   = ws + 13472256;               // 2,048 f32
    u16*   w5b  = (u16*)(ws + 13474304);       // 1,048,576 u16 (w5 padded to 1024 rows)
    u16*   ic   = (u16*)(ws + 13998592);       // 1,507,328 u16 (conv5 B-matrix)
    u16*   ic2  = (u16*)(ws + 14752256);       // 1,507,328 u16 (linear B-matrix)
    u16*   lwb  = (u16*)(ws + 15505920);       // 65,536 u16 (lw K-padded)
    float* sig  = ws + 2359296;                // (64,64,23) f32 (inside dead A region)

    const size_t wofs[5] = {0, 1024, 9216, 41984, 173056};
    const int    Ks[5]   = {48, 256, 512, 1024, 2048};
    const int    Kps[5]  = {64, 256, 512, 1024, 2048};
    const int    Cos[5]  = {16, 32, 64, 128, 256};

    for (int L = 0; L < 5; ++L) {
        int tot = Cos[L] * Kps[L];
        hipLaunchKernelGGL(wcvt, dim3((tot + 255) / 256), dim3(256), 0, stream,
                           w[L], wbf + wofs[L], tot, Ks[L], Kps[L]);
    }
    hipLaunchKernelGGL(wcvtM, dim3((1024 * 1024) / 256), dim3(256), 0, stream,
                       w5, w5b, 1024 * 1024, 1024, 1000);
    hipLaunchKernelGGL(wcvt, dim3((64 * 1024) / 256), dim3(256), 0, stream,
                       lw, lwb, 64 * 1024, 1000, 1024);

    // ---- x -> padded bf16 [64,4,66,776] (writes halos; no memset) ----
    hipLaunchKernelGGL(xpad_v, dim3(6402), dim3(256), 0, stream, x, P);

    // L0: conv -> bf16 A
    hipLaunchKernelGGL((conv_mfma<16, 4, 64, 64, 768, 66, 776, 1, true>),
                       dim3(12288), dim3(256), 0, stream, P, wbf + wofs[0], A);
    hipLaunchKernelGGL((stats_bf<16, 12288>), dim3(256), dim3(256), 0, stream,
                       (const u16*)A, part);
    hipLaunchKernelGGL(bn_finalize, dim3(1), dim3(256), 0, stream,
                       part, g[0], bb[0], ss, 16, 1.f / 786432.f);
    hipLaunchKernelGGL((bn_pad_v<16, 32, 384, true>), dim3(6664), dim3(256), 0, stream,
                       (const void*)A, ss, P);

    // L1
    hipLaunchKernelGGL((conv_mfma<32, 16, 256, 32, 384, 34, 392, 2, false>),
                       dim3(3072), dim3(256), 0, stream, P, wbf + wofs[1], A);
    hipLaunchKernelGGL((stats_f32<32, 3072>), dim3(512), dim3(256), 0, stream, A, part);
    hipLaunchKernelGGL(bn_finalize, dim3(1), dim3(256), 0, stream,
                       part, g[1], bb[1], ss, 32, 1.f / 196608.f);
    hipLaunchKernelGGL((bn_pad_v<32, 16, 192, false>), dim3(3600), dim3(256), 0, stream,
                       (const void*)A, ss, P);

    // L2
    hipLaunchKernelGGL((conv_mfma<64, 32, 512, 16, 192, 18, 200, 4, false>),
                       dim3(768), dim3(256), 0, stream, P, wbf + wofs[2], A);
    hipLaunchKernelGGL((stats_f32<64, 768>), dim3(1024), dim3(256), 0, stream, A, part);
    hipLaunchKernelGGL(bn_finalize, dim3(1), dim3(256), 0, stream,
                       part, g[2], bb[2], ss, 64, 1.f / 49152.f);
    hipLaunchKernelGGL((bn_pad_v<64, 8, 96, false>), dim3(2080), dim3(256), 0, stream,
                       (const void*)A, ss, P);

    // L3
    hipLaunchKernelGGL((conv_mfma<128, 64, 1024, 8, 96, 10, 104, 4, false>),
                       dim3(384), dim3(256), 0, stream, P, wbf + wofs[3], A);
    hipLaunchKernelGGL((stats_f32<128, 192>), dim3(2048), dim3(256), 0, stream, A, part);
    hipLaunchKernelGGL(bn_finalize, dim3(1), dim3(256), 0, stream,
                       part, g[3], bb[3], ss, 128, 1.f / 12288.f);
    hipLaunchKernelGGL((bn_pad_v<128, 4, 48, false>), dim3(1344), dim3(256), 0, stream,
                       (const void*)A, ss, P);

    // L4
    hipLaunchKernelGGL((conv_mfma<256, 128, 2048, 4, 48, 6, 56, 4, false>),
                       dim3(192), dim3(256), 0, stream, P, wbf + wofs[4], A);
    hipLaunchKernelGGL((stats_f32<256, 48>), dim3(4096), dim3(256), 0, stream, A, part);
    hipLaunchKernelGGL(bn_finalize, dim3(1), dim3(256), 0, stream,
                       part, g[4], bb[4], ss, 256, 1.f / 3072.f);
    hipLaunchKernelGGL(im2col5, dim3((1472 * 1024) / 256), dim3(256), 0, stream,
                       A, ss, ic);

    // tail: conv5 GEMM -> ic2 (bf16), linear GEMM + sigmoid -> sig, shuffle
    hipLaunchKernelGGL(conv5_mfma2, dim3(368), dim3(256), 0, stream, ic, w5b, ic2);
    hipLaunchKernelGGL(linear_mfma, dim3(92), dim3(256), 0, stream, ic2, lwb, sig);
    hipLaunchKernelGGL(shuffle_out_kernel, dim3((64 * 768 + 255) / 256), dim3(256), 0, stream,
                       sig, out);
}

// Round 11
// 307.322 us; speedup vs baseline: 15.2907x; 1.0037x over previous
//
#include <hip/hip_runtime.h>
#include <cmath>

#define EPS 1e-5f
#define SLOPE 0.2f

typedef unsigned short u16;
typedef unsigned int u32;
typedef __attribute__((ext_vector_type(8))) short bf16x8;
typedef __attribute__((ext_vector_type(8))) unsigned short u16x8;
typedef __attribute__((ext_vector_type(4))) unsigned short u16x4;
typedef __attribute__((ext_vector_type(4))) float f32x4;

__device__ __forceinline__ u16 f2b(float f) {
    union { float f; u32 u; } v; v.f = f;
    u32 r = (v.u + 0x7FFF + ((v.u >> 16) & 1)) >> 16;
    return (u16)r;
}
__device__ __forceinline__ float b2f(u16 h) {
    union { u32 u; float f; } v; v.u = ((u32)h) << 16;
    return v.f;
}
__device__ __forceinline__ float leaky(float v) { return v >= 0.f ? v : SLOPE * v; }

// ---------------- fused prep: all weight->bf16 converts + x padding ----------------
// Section A [0,697344): layer weights (K zero-padded for L0)
// Section B [697344,1745920): w5 -> [1024][1024] (co zero-padded)
// Section C [1745920,1811456): lw -> [64][1024] (K zero-padded)
// Section D [1811456,3450368): x -> padded bf16 [64,4,66,776] (u16x8 stores)
__global__ __launch_bounds__(256) void prep(const float* __restrict__ x,
                                            const float* __restrict__ w0,
                                            const float* __restrict__ w1,
                                            const float* __restrict__ w2,
                                            const float* __restrict__ w3,
                                            const float* __restrict__ w4,
                                            const float* __restrict__ w5,
                                            const float* __restrict__ lw,
                                            u16* __restrict__ wbf,
                                            u16* __restrict__ w5b,
                                            u16* __restrict__ lwb,
                                            u16* __restrict__ P) {
    int idx = blockIdx.x * 256 + threadIdx.x;
    if (idx < 697344) {
        const float* src; int K, Kp; int base;
        if (idx < 1024)        { src = w0; K = 48;   Kp = 64;   base = 0; }
        else if (idx < 9216)   { src = w1; K = 256;  Kp = 256;  base = 1024; }
        else if (idx < 41984)  { src = w2; K = 512;  Kp = 512;  base = 9216; }
        else if (idx < 173056) { src = w3; K = 1024; Kp = 1024; base = 41984; }
        else                   { src = w4; K = 2048; Kp = 2048; base = 173056; }
        int local = idx - base;
        int k = local % Kp;
        int co = local / Kp;
        wbf[idx] = (k < K) ? f2b(src[(size_t)co * K + k]) : (u16)0;
    } else if (idx < 1745920) {
        int local = idx - 697344;
        int k = local & 1023;
        int co = local >> 10;
        w5b[local] = (co < 1000) ? f2b(w5[(size_t)co * 1024 + k]) : (u16)0;
    } else if (idx < 1811456) {
        int local = idx - 1745920;
        int k = local & 1023;
        int o = local >> 10;
        lwb[local] = (k < 1000) ? f2b(lw[(size_t)o * 1000 + k]) : (u16)0;
    } else if (idx < 3450368) {
        constexpr int H = 64, W = 768, G = 97, Wp = 776, Hp = 66;
        int local = idx - 1811456;
        int m = local % G;
        int hp = (local / G) % Hp;
        int c = (local / (G * Hp)) % 4;
        int b = local / (G * Hp * 4);
        u16x8 o;
#pragma unroll
        for (int i = 0; i < 8; ++i) o[i] = 0;
        if (c < 3 && hp >= 1 && hp <= H) {
            const float* base = x + ((size_t)(b * 3 + c) * H + (hp - 1)) * W;
            if (m > 0) o[0] = f2b(base[8 * m - 1]);
            if (m < G - 1) {
                float4 a  = *(const float4*)(base + 8 * m);
                float4 b4 = *(const float4*)(base + 8 * m + 4);
                o[1] = f2b(a.x); o[2] = f2b(a.y); o[3] = f2b(a.z); o[4] = f2b(a.w);
                o[5] = f2b(b4.x); o[6] = f2b(b4.y); o[7] = f2b(b4.z);
            }
        }
        *(u16x8*)(P + ((size_t)(b * 4 + c) * Hp + hp) * Wp + 8 * m) = o;
    }
}

// ---------------- implicit-GEMM MFMA conv, MT m-tiles per wave ----------------
template <int Co, int CiPad, int Kp, int Hi, int Wi, int Hp, int Wp, int MT, bool OB>
__global__ __launch_bounds__(256) void conv_mfma(const u16* __restrict__ inp,
                                                 const u16* __restrict__ wt,
                                                 void* __restrict__ outv) {
    constexpr int Ho = Hi / 2, Wo = Wi / 2, HW = Ho * Wo;
    constexpr int MG = Co / 16 / MT;   // m-groups

    int tid = threadIdx.x;
    int wid = blockIdx.x * 4 + (tid >> 6);
    int lane = tid & 63;
    int r = lane & 15;
    int quad = lane >> 4;
    int mg = wid % MG;
    int nt = wid / MG;

    int n = nt * 16 + r;
    int b = n / HW;
    int hw = n % HW;
    int oh = hw / Wo;
    int ow = hw % Wo;

    int ciq = quad >> 1;
    int kh0 = (quad & 1) * 2;

    const u16* pB = inp + ((size_t)(b * CiPad + ciq) * Hp + (2 * oh + kh0)) * Wp + 2 * ow;
    const u16* pA = wt + (size_t)(mg * MT * 16 + r) * Kp + quad * 8;

    f32x4 acc[MT];
#pragma unroll
    for (int mt = 0; mt < MT; ++mt) acc[mt] = (f32x4){0.f, 0.f, 0.f, 0.f};

#pragma unroll 4
    for (int kk = 0; kk < Kp / 32; ++kk) {
        union { u32 u[4]; bf16x8 v; } bb;
        bb.u[0] = *(const u32*)(pB);
        bb.u[1] = *(const u32*)(pB + 2);
        bb.u[2] = *(const u32*)(pB + Wp);
        bb.u[3] = *(const u32*)(pB + Wp + 2);
#pragma unroll
        for (int mt = 0; mt < MT; ++mt) {
            bf16x8 a = *(const bf16x8*)(pA + (size_t)mt * 16 * Kp);
            acc[mt] = __builtin_amdgcn_mfma_f32_16x16x32_bf16(a, bb.v, acc[mt], 0, 0, 0);
        }
        pA += 32;
        pB += (size_t)2 * Hp * Wp;
    }

#pragma unroll
    for (int mt = 0; mt < MT; ++mt) {
        int co0 = mg * MT * 16 + mt * 16 + quad * 4;
        if (OB) {
            u16* o = (u16*)outv;
#pragma unroll
            for (int j = 0; j < 4; ++j)
                o[((size_t)b * Co + co0 + j) * HW + hw] = f2b(acc[mt][j]);
        } else {
            float* o = (float*)outv;
#pragma unroll
            for (int j = 0; j < 4; ++j)
                o[((size_t)b * Co + co0 + j) * HW + hw] = acc[mt][j];
        }
    }
}

// ---------------- BN stats: vectorized, division-free, deterministic ----------------
template <int C, int HW>
__global__ __launch_bounds__(256) void stats_bf(const u16* __restrict__ x,
                                                float* __restrict__ part) {
    int c = blockIdx.x >> 4;
    int chunk = blockIdx.x & 15;
    double s1 = 0.0, s2 = 0.0;
    for (int bi = 0; bi < 4; ++bi) {
        const u16* base = x + ((size_t)(chunk * 4 + bi) * C + c) * HW;
        for (int p = threadIdx.x * 8; p < HW; p += 2048) {
            bf16x8 v = *(const bf16x8*)(base + p);
#pragma unroll
            for (int e = 0; e < 8; ++e) {
                float f = b2f((u16)v[e]);
                s1 += f; s2 += (double)f * f;
            }
        }
    }
    __shared__ double sh1[256];
    __shared__ double sh2[256];
    int tid = threadIdx.x;
    sh1[tid] = s1; sh2[tid] = s2;
    __syncthreads();
    for (int s = 128; s > 0; s >>= 1) {
        if (tid < s) { sh1[tid] += sh1[tid + s]; sh2[tid] += sh2[tid + s]; }
        __syncthreads();
    }
    if (tid == 0) {
        part[((size_t)c * 16 + chunk) * 2 + 0] = (float)sh1[0];
        part[((size_t)c * 16 + chunk) * 2 + 1] = (float)sh2[0];
    }
}

template <int C, int HW>
__global__ __launch_bounds__(256) void stats_f32(const float* __restrict__ x,
                                                 float* __restrict__ part) {
    int c = blockIdx.x >> 4;
    int chunk = blockIdx.x & 15;
    double s1 = 0.0, s2 = 0.0;
    for (int bi = 0; bi < 4; ++bi) {
        const float* base = x + ((size_t)(chunk * 4 + bi) * C + c) * HW;
        for (int p = threadIdx.x * 4; p < HW; p += 1024) {
            float4 v = *(const float4*)(base + p);
            s1 += v.x; s2 += (double)v.x * v.x;
            s1 += v.y; s2 += (double)v.y * v.y;
            s1 += v.z; s2 += (double)v.z * v.z;
            s1 += v.w; s2 += (double)v.w * v.w;
        }
    }
    __shared__ double sh1[256];
    __shared__ double sh2[256];
    int tid = threadIdx.x;
    sh1[tid] = s1; sh2[tid] = s2;
    __syncthreads();
    for (int s = 128; s > 0; s >>= 1) {
        if (tid < s) { sh1[tid] += sh1[tid + s]; sh2[tid] += sh2[tid + s]; }
        __syncthreads();
    }
    if (tid == 0) {
        part[((size_t)c * 16 + chunk) * 2 + 0] = (float)sh1[0];
        part[((size_t)c * 16 + chunk) * 2 + 1] = (float)sh2[0];
    }
}

// ---------------- BN finalize (per-block, into LDS) + leaky + padded bf16 write ----------------
// H,W here = conv-output dims of this layer. Finalize folded in: thread t<C reduces
// channel t's 16 partials (same FP order as the old bn_finalize -> bit-identical).
template <int C, int H, int W, bool INB>
__global__ __launch_bounds__(256) void bn_pad_v(const void* __restrict__ in,
                                                const float* __restrict__ part,
                                                const float* __restrict__ g,
                                                const float* __restrict__ bbias,
                                                u16* __restrict__ outp) {
    constexpr int G = W / 8 + 1;
    constexpr int Wp = 8 * G;
    constexpr int Hp = H + 2;
    constexpr float invN = 1.f / (64.f * H * W);

    __shared__ float s_sc[C], s_sh[C];
    int t = threadIdx.x;
    if (t < C) {
        float s1 = 0.f, s2 = 0.f;
#pragma unroll
        for (int k = 0; k < 16; ++k) {
            s1 += part[((size_t)t * 16 + k) * 2 + 0];
            s2 += part[((size_t)t * 16 + k) * 2 + 1];
        }
        float mean = s1 * invN;
        float var  = s2 * invN - mean * mean;
        float inv  = rsqrtf(var + EPS);
        float sc   = inv * g[t];
        s_sc[t] = sc;
        s_sh[t] = bbias[t] - mean * sc;
    }
    __syncthreads();

    int idx = blockIdx.x * 256 + t;
    if (idx >= 64 * C * Hp * G) return;
    int m = idx % G;
    int hp = (idx / G) % Hp;
    int c = (idx / (G * Hp)) % C;
    int b = idx / (G * Hp * C);

    u16x8 o;
#pragma unroll
    for (int i = 0; i < 8; ++i) o[i] = 0;

    if (hp >= 1 && hp <= H) {
        float sc = s_sc[c], sh = s_sh[c];
        float vals[8];
        if (INB) {
            const u16* base = (const u16*)in + ((size_t)(b * C + c) * H + (hp - 1)) * W;
            vals[0] = (m > 0) ? b2f(base[8 * m - 1]) : 0.f;
            if (m < G - 1) {
                bf16x8 va = *(const bf16x8*)(base + 8 * m);
#pragma unroll
                for (int i = 0; i < 7; ++i) vals[i + 1] = b2f((u16)va[i]);
            }
        } else {
            const float* base = (const float*)in + ((size_t)(b * C + c) * H + (hp - 1)) * W;
            vals[0] = (m > 0) ? base[8 * m - 1] : 0.f;
            if (m < G - 1) {
                float4 a  = *(const float4*)(base + 8 * m);
                float4 b4 = *(const float4*)(base + 8 * m + 4);
                vals[1] = a.x; vals[2] = a.y; vals[3] = a.z; vals[4] = a.w;
                vals[5] = b4.x; vals[6] = b4.y; vals[7] = b4.z;
            }
        }
        if (m > 0) o[0] = f2b(leaky(vals[0] * sc + sh));
        if (m < G - 1) {
#pragma unroll
            for (int i = 1; i < 8; ++i) o[i] = f2b(leaky(vals[i] * sc + sh));
        }
    }
    *(u16x8*)(outp + ((size_t)(b * C + c) * Hp + hp) * Wp + 8 * m) = o;
}

// ---------------- L4: BN finalize (LDS) + leaky + im2col bf16 for conv5 ----------------
__global__ __launch_bounds__(256) void im2col5(const float* __restrict__ A,
                                               const float* __restrict__ part,
                                               const float* __restrict__ g,
                                               const float* __restrict__ bbias,
                                               u16* __restrict__ ic) {
    constexpr float invN = 1.f / 3072.f;
    __shared__ float s_sc[256], s_sh[256];
    int t = threadIdx.x;
    {
        float s1 = 0.f, s2 = 0.f;
#pragma unroll
        for (int k = 0; k < 16; ++k) {
            s1 += part[((size_t)t * 16 + k) * 2 + 0];
            s2 += part[((size_t)t * 16 + k) * 2 + 1];
        }
        float mean = s1 * invN;
        float var  = s2 * invN - mean * mean;
        float inv  = rsqrtf(var + EPS);
        float sc   = inv * g[t];
        s_sc[t] = sc;
        s_sh[t] = bbias[t] - mean * sc;
    }
    __syncthreads();

    int idx = blockIdx.x * 256 + t;
    if (idx >= 1472 * 1024) return;
    int k = idx & 1023;
    int n = idx >> 10;
    int b = n / 23, j = n % 23;
    int ci = k >> 2, kh = (k >> 1) & 1, kw = k & 1;
    float v = A[(size_t)b * 12288 + ci * 48 + kh * 24 + j + kw];
    v = leaky(v * s_sc[ci] + s_sh[ci]);
    ic[idx] = f2b(v);
}

// ---------------- conv5 GEMM: [1024 x 1024] x [1024 x 1472], 32x32 per wave ----------------
__global__ __launch_bounds__(256) void conv5_mfma2(const u16* __restrict__ ic,
                                                   const u16* __restrict__ w5b,
                                                   u16* __restrict__ ic2) {
    int tid = threadIdx.x;
    int wave = tid >> 6;
    int lane = tid & 63;
    int r = lane & 15;
    int quad = lane >> 4;
    int gx = blockIdx.x % 23;      // n-block (64)
    int gy = blockIdx.x / 23;      // m-block (64), 0..15
    int m0 = gy * 64 + (wave >> 1) * 32;
    int n0 = gx * 64 + (wave & 1) * 32;

    const u16* pA0 = w5b + (size_t)(m0 + r) * 1024 + quad * 8;
    const u16* pA1 = pA0 + 16 * 1024;
    const u16* pB0 = ic + (size_t)(n0 + r) * 1024 + quad * 8;
    const u16* pB1 = pB0 + 16 * 1024;

    f32x4 a00 = {0.f,0.f,0.f,0.f}, a01 = {0.f,0.f,0.f,0.f};
    f32x4 a10 = {0.f,0.f,0.f,0.f}, a11 = {0.f,0.f,0.f,0.f};

#pragma unroll 4
    for (int kk = 0; kk < 32; ++kk) {
        bf16x8 fa0 = *(const bf16x8*)pA0;
        bf16x8 fa1 = *(const bf16x8*)pA1;
        bf16x8 fb0 = *(const bf16x8*)pB0;
        bf16x8 fb1 = *(const bf16x8*)pB1;
        a00 = __builtin_amdgcn_mfma_f32_16x16x32_bf16(fa0, fb0, a00, 0, 0, 0);
        a01 = __builtin_amdgcn_mfma_f32_16x16x32_bf16(fa0, fb1, a01, 0, 0, 0);
        a10 = __builtin_amdgcn_mfma_f32_16x16x32_bf16(fa1, fb0, a10, 0, 0, 0);
        a11 = __builtin_amdgcn_mfma_f32_16x16x32_bf16(fa1, fb1, a11, 0, 0, 0);
        pA0 += 32; pA1 += 32; pB0 += 32; pB1 += 32;
    }

#pragma unroll
    for (int mi = 0; mi < 2; ++mi) {
#pragma unroll
        for (int ni = 0; ni < 2; ++ni) {
            f32x4 acc = (mi == 0) ? (ni == 0 ? a00 : a01) : (ni == 0 ? a10 : a11);
            int n = n0 + ni * 16 + r;
            int co0 = m0 + mi * 16 + quad * 4;
            u16x4 pk;
#pragma unroll
            for (int j = 0; j < 4; ++j) pk[j] = f2b(leaky(acc[j]));
            *(u16x4*)(ic2 + (size_t)n * 1024 + co0) = pk;
        }
    }
}

// ---------------- linear as MFMA GEMM [64 x 1024] x [1024 x 1472] + sigmoid ----------------
__global__ __launch_bounds__(256) void linear_mfma(const u16* __restrict__ ic2,
                                                   const u16* __restrict__ lwb,
                                                   float* __restrict__ sig) {
    int tid = threadIdx.x;
    int wid = blockIdx.x * 4 + (tid >> 6);
    int lane = tid & 63;
    int r = lane & 15;
    int quad = lane >> 4;
    int mt = wid & 3;           // 4 m-tiles (64 rows)
    int nt = wid >> 2;          // 92 n-tiles

    int n = nt * 16 + r;
    const u16* pA = lwb + (size_t)(mt * 16 + r) * 1024 + quad * 8;
    const u16* pB = ic2 + (size_t)n * 1024 + quad * 8;

    f32x4 acc = {0.f, 0.f, 0.f, 0.f};
#pragma unroll 4
    for (int kk = 0; kk < 32; ++kk) {
        bf16x8 a = *(const bf16x8*)pA;
        bf16x8 bv = *(const bf16x8*)pB;
        acc = __builtin_amdgcn_mfma_f32_16x16x32_bf16(a, bv, acc, 0, 0, 0);
        pA += 32;
        pB += 32;
    }

    int b = n / 23, j = n % 23;
#pragma unroll
    for (int jj = 0; jj < 4; ++jj) {
        int o = mt * 16 + quad * 4 + jj;
        float v = 1.f / (1.f + expf(-acc[jj]));
        sig[(size_t)b * 1472 + (size_t)o * 23 + j] = v;
    }
}

// ---------------- final interleave/shuffle ----------------
__global__ void shuffle_out_kernel(const float* __restrict__ sig, float* __restrict__ out) {
    int idx = blockIdx.x * blockDim.x + threadIdx.x;
    if (idx >= 64 * 768) return;
    int o = idx % 32;
    int j = (idx / 32) % 24;
    int b = idx / 768;
    const float* s = sig + (size_t)b * 64 * 23;
    float v;
    if (j == 0)       v = s[o * 23];
    else if (j == 23) v = s[(o + 32) * 23 + 22];
    else              v = 0.5f * (s[(o + 32) * 23 + (j - 1)] + s[o * 23 + j]);
    out[idx] = v;
}

extern "C" void kernel_launch(void* const* d_in, const int* in_sizes, int n_in,
                              void* d_out, int out_size, void* d_ws, size_t ws_size,
                              hipStream_t stream) {
    (void)in_sizes; (void)n_in; (void)out_size; (void)ws_size;

    const float* x = (const float*)d_in[0];
    const float* w[5]; const float* g[5]; const float* bb[5];
    for (int i = 0; i < 5; ++i) {
        w[i]  = (const float*)d_in[1 + 3 * i];
        g[i]  = (const float*)d_in[2 + 3 * i];
        bb[i] = (const float*)d_in[3 + 3 * i];
    }
    const float* w5 = (const float*)d_in[16];
    const float* lw = (const float*)d_in[17];
    float* out = (float*)d_out;

    // ---- workspace layout (~60 MB) ----
    float* ws   = (float*)d_ws;
    float* A    = ws;                          // 6,291,456 f32 (conv-out; L0 as u16)
    u16*   P    = (u16*)(ws + 6291456);        // up to 13,647,872 u16 (padded inputs)
    u16*   wbf  = (u16*)(ws + 13115392);       // 697,344 u16
    float* part = ws + 13464064;               // 8,192 f32
    u16*   w5b  = (u16*)(ws + 13474304);       // 1,048,576 u16 (w5 padded to 1024 rows)
    u16*   ic   = (u16*)(ws + 13998592);       // 1,507,328 u16 (conv5 B-matrix)
    u16*   ic2  = (u16*)(ws + 14752256);       // 1,507,328 u16 (linear B-matrix)
    u16*   lwb  = (u16*)(ws + 15505920);       // 65,536 u16 (lw K-padded)
    float* sig  = ws + 2359296;                // (64,64,23) f32 (inside dead A region)

    const size_t wofs[5] = {0, 1024, 9216, 41984, 173056};

    // ---- single prep kernel: all weights + x padding ----
    hipLaunchKernelGGL(prep, dim3(13478), dim3(256), 0, stream,
                       x, w[0], w[1], w[2], w[3], w[4], w5, lw, wbf, w5b, lwb, P);

    // L0: conv -> bf16 A
    hipLaunchKernelGGL((conv_mfma<16, 4, 64, 64, 768, 66, 776, 1, true>),
                       dim3(12288), dim3(256), 0, stream, P, wbf + wofs[0], A);
    hipLaunchKernelGGL((stats_bf<16, 12288>), dim3(256), dim3(256), 0, stream,
                       (const u16*)A, part);
    hipLaunchKernelGGL((bn_pad_v<16, 32, 384, true>), dim3(6664), dim3(256), 0, stream,
                       (const void*)A, part, g[0], bb[0], P);

    // L1
    hipLaunchKernelGGL((conv_mfma<32, 16, 256, 32, 384, 34, 392, 2, false>),
                       dim3(3072), dim3(256), 0, stream, P, wbf + wofs[1], A);
    hipLaunchKernelGGL((stats_f32<32, 3072>), dim3(512), dim3(256), 0, stream, A, part);
    hipLaunchKernelGGL((bn_pad_v<32, 16, 192, false>), dim3(3600), dim3(256), 0, stream,
                       (const void*)A, part, g[1], bb[1], P);

    // L2
    hipLaunchKernelGGL((conv_mfma<64, 32, 512, 16, 192, 18, 200, 4, false>),
                       dim3(768), dim3(256), 0, stream, P, wbf + wofs[2], A);
    hipLaunchKernelGGL((stats_f32<64, 768>), dim3(1024), dim3(256), 0, stream, A, part);
    hipLaunchKernelGGL((bn_pad_v<64, 8, 96, false>), dim3(2080), dim3(256), 0, stream,
                       (const void*)A, part, g[2], bb[2], P);

    // L3
    hipLaunchKernelGGL((conv_mfma<128, 64, 1024, 8, 96, 10, 104, 4, false>),
                       dim3(384), dim3(256), 0, stream, P, wbf + wofs[3], A);
    hipLaunchKernelGGL((stats_f32<128, 192>), dim3(2048), dim3(256), 0, stream, A, part);
    hipLaunchKernelGGL((bn_pad_v<128, 4, 48, false>), dim3(1344), dim3(256), 0, stream,
                       (const void*)A, part, g[3], bb[3], P);

    // L4
    hipLaunchKernelGGL((conv_mfma<256, 128, 2048, 4, 48, 6, 56, 4, false>),
                       dim3(192), dim3(256), 0, stream, P, wbf + wofs[4], A);
    hipLaunchKernelGGL((stats_f32<256, 48>), dim3(4096), dim3(256), 0, stream, A, part);
    hipLaunchKernelGGL(im2col5, dim3(5888), dim3(256), 0, stream,
                       A, part, g[4], bb[4], ic);

    // tail: conv5 GEMM -> ic2 (bf16), linear GEMM + sigmoid -> sig, shuffle
    hipLaunchKernelGGL(conv5_mfma2, dim3(368), dim3(256), 0, stream, ic, w5b, ic2);
    hipLaunchKernelGGL(linear_mfma, dim3(92), dim3(256), 0, stream, ic2, lwb, sig);
    hipLaunchKernelGGL(shuffle_out_kernel, dim3((64 * 768 + 255) / 256), dim3(256), 0, stream,
                       sig, out);
}

// Round 12
// 304.040 us; speedup vs baseline: 15.4558x; 1.0108x over previous
//
#include <hip/hip_runtime.h>
#include <cmath>

#define EPS 1e-5f
#define SLOPE 0.2f

typedef unsigned short u16;
typedef unsigned int u32;
typedef __attribute__((ext_vector_type(8))) short bf16x8;
typedef __attribute__((ext_vector_type(8))) unsigned short u16x8;
typedef __attribute__((ext_vector_type(4))) unsigned short u16x4;
typedef __attribute__((ext_vector_type(4))) float f32x4;

__device__ __forceinline__ u16 f2b(float f) {
    union { float f; u32 u; } v; v.f = f;
    u32 r = (v.u + 0x7FFF + ((v.u >> 16) & 1)) >> 16;
    return (u16)r;
}
__device__ __forceinline__ float b2f(u16 h) {
    union { u32 u; float f; } v; v.u = ((u32)h) << 16;
    return v.f;
}
__device__ __forceinline__ float leaky(float v) { return v >= 0.f ? v : SLOPE * v; }

// ---------------- fused prep: all weight->bf16 converts + x padding ----------------
__global__ __launch_bounds__(256) void prep(const float* __restrict__ x,
                                            const float* __restrict__ w0,
                                            const float* __restrict__ w1,
                                            const float* __restrict__ w2,
                                            const float* __restrict__ w3,
                                            const float* __restrict__ w4,
                                            const float* __restrict__ w5,
                                            const float* __restrict__ lw,
                                            u16* __restrict__ wbf,
                                            u16* __restrict__ w5b,
                                            u16* __restrict__ lwb,
                                            u16* __restrict__ P) {
    int idx = blockIdx.x * 256 + threadIdx.x;
    if (idx < 697344) {
        const float* src; int K, Kp; int base;
        if (idx < 1024)        { src = w0; K = 48;   Kp = 64;   base = 0; }
        else if (idx < 9216)   { src = w1; K = 256;  Kp = 256;  base = 1024; }
        else if (idx < 41984)  { src = w2; K = 512;  Kp = 512;  base = 9216; }
        else if (idx < 173056) { src = w3; K = 1024; Kp = 1024; base = 41984; }
        else                   { src = w4; K = 2048; Kp = 2048; base = 173056; }
        int local = idx - base;
        int k = local % Kp;
        int co = local / Kp;
        wbf[idx] = (k < K) ? f2b(src[(size_t)co * K + k]) : (u16)0;
    } else if (idx < 1745920) {
        int local = idx - 697344;
        int k = local & 1023;
        int co = local >> 10;
        w5b[local] = (co < 1000) ? f2b(w5[(size_t)co * 1024 + k]) : (u16)0;
    } else if (idx < 1811456) {
        int local = idx - 1745920;
        int k = local & 1023;
        int o = local >> 10;
        lwb[local] = (k < 1000) ? f2b(lw[(size_t)o * 1000 + k]) : (u16)0;
    } else if (idx < 3450368) {
        constexpr int H = 64, W = 768, G = 97, Wp = 776, Hp = 66;
        int local = idx - 1811456;
        int m = local % G;
        int hp = (local / G) % Hp;
        int c = (local / (G * Hp)) % 4;
        int b = local / (G * Hp * 4);
        u16x8 o;
#pragma unroll
        for (int i = 0; i < 8; ++i) o[i] = 0;
        if (c < 3 && hp >= 1 && hp <= H) {
            const float* base = x + ((size_t)(b * 3 + c) * H + (hp - 1)) * W;
            if (m > 0) o[0] = f2b(base[8 * m - 1]);
            if (m < G - 1) {
                float4 a  = *(const float4*)(base + 8 * m);
                float4 b4 = *(const float4*)(base + 8 * m + 4);
                o[1] = f2b(a.x); o[2] = f2b(a.y); o[3] = f2b(a.z); o[4] = f2b(a.w);
                o[5] = f2b(b4.x); o[6] = f2b(b4.y); o[7] = f2b(b4.z);
            }
        }
        *(u16x8*)(P + ((size_t)(b * 4 + c) * Hp + hp) * Wp + 8 * m) = o;
    }
}

// ---------------- implicit-GEMM MFMA conv, MT m-tiles x NT n-tiles per wave ----------------
template <int Co, int CiPad, int Kp, int Hi, int Wi, int Hp, int Wp, int MT, int NT, bool OB>
__global__ __launch_bounds__(256) void conv_mfma(const u16* __restrict__ inp,
                                                 const u16* __restrict__ wt,
                                                 void* __restrict__ outv) {
    constexpr int Ho = Hi / 2, Wo = Wi / 2, HW = Ho * Wo;
    constexpr int MG = Co / 16 / MT;   // m-groups

    int tid = threadIdx.x;
    int wid = blockIdx.x * 4 + (tid >> 6);
    int lane = tid & 63;
    int r = lane & 15;
    int quad = lane >> 4;
    int mg = wid % MG;
    int ng = wid / MG;

    int ciq = quad >> 1;
    int kh0 = (quad & 1) * 2;

    const u16* pB[NT];
    int b_[NT], hw_[NT];
#pragma unroll
    for (int i = 0; i < NT; ++i) {
        int n = (ng * NT + i) * 16 + r;
        int b = n / HW;
        int hw = n % HW;
        int oh = hw / Wo;
        int ow = hw % Wo;
        b_[i] = b; hw_[i] = hw;
        pB[i] = inp + ((size_t)(b * CiPad + ciq) * Hp + (2 * oh + kh0)) * Wp + 2 * ow;
    }
    const u16* pA = wt + (size_t)(mg * MT * 16 + r) * Kp + quad * 8;

    f32x4 acc[MT][NT];
#pragma unroll
    for (int mt = 0; mt < MT; ++mt)
#pragma unroll
        for (int i = 0; i < NT; ++i) acc[mt][i] = (f32x4){0.f, 0.f, 0.f, 0.f};

#pragma unroll 2
    for (int kk = 0; kk < Kp / 32; ++kk) {
        bf16x8 a[MT];
#pragma unroll
        for (int mt = 0; mt < MT; ++mt)
            a[mt] = *(const bf16x8*)(pA + (size_t)mt * 16 * Kp);
#pragma unroll
        for (int i = 0; i < NT; ++i) {
            union { u32 u[4]; bf16x8 v; } bb;
            bb.u[0] = *(const u32*)(pB[i]);
            bb.u[1] = *(const u32*)(pB[i] + 2);
            bb.u[2] = *(const u32*)(pB[i] + Wp);
            bb.u[3] = *(const u32*)(pB[i] + Wp + 2);
#pragma unroll
            for (int mt = 0; mt < MT; ++mt)
                acc[mt][i] = __builtin_amdgcn_mfma_f32_16x16x32_bf16(a[mt], bb.v, acc[mt][i], 0, 0, 0);
            pB[i] += (size_t)2 * Hp * Wp;
        }
        pA += 32;
    }

#pragma unroll
    for (int mt = 0; mt < MT; ++mt) {
        int co0 = mg * MT * 16 + mt * 16 + quad * 4;
#pragma unroll
        for (int i = 0; i < NT; ++i) {
            if (OB) {
                u16* o = (u16*)outv;
#pragma unroll
                for (int j = 0; j < 4; ++j)
                    o[((size_t)b_[i] * Co + co0 + j) * HW + hw_[i]] = f2b(acc[mt][i][j]);
            } else {
                float* o = (float*)outv;
#pragma unroll
                for (int j = 0; j < 4; ++j)
                    o[((size_t)b_[i] * Co + co0 + j) * HW + hw_[i]] = acc[mt][i][j];
            }
        }
    }
}

// ---------------- BN stats: vectorized, deterministic, CHUNKS-scalable ----------------
// CHUNKS<=64: chunk = (64/CHUNKS) consecutive batches, full HW.
// CHUNKS=128: chunk = 1 batch x half HW.
template <int C, int HW, int CHUNKS>
__global__ __launch_bounds__(256) void stats_bf(const u16* __restrict__ x,
                                                float* __restrict__ part) {
    constexpr int S = (CHUNKS > 64) ? CHUNKS / 64 : 1;
    constexpr int BPC = 64 * S / CHUNKS;
    constexpr int SEG = HW / S;
    int c = blockIdx.x / CHUNKS;
    int chunk = blockIdx.x % CHUNKS;
    int b0 = (chunk / S) * BPC;
    int s0 = (chunk % S) * SEG;
    double s1 = 0.0, s2 = 0.0;
    for (int bi = 0; bi < BPC; ++bi) {
        const u16* base = x + ((size_t)(b0 + bi) * C + c) * HW + s0;
        for (int p = threadIdx.x * 8; p < SEG; p += 2048) {
            bf16x8 v = *(const bf16x8*)(base + p);
#pragma unroll
            for (int e = 0; e < 8; ++e) {
                float f = b2f((u16)v[e]);
                s1 += f; s2 += (double)f * f;
            }
        }
    }
    __shared__ double sh1[256];
    __shared__ double sh2[256];
    int tid = threadIdx.x;
    sh1[tid] = s1; sh2[tid] = s2;
    __syncthreads();
    for (int s = 128; s > 0; s >>= 1) {
        if (tid < s) { sh1[tid] += sh1[tid + s]; sh2[tid] += sh2[tid + s]; }
        __syncthreads();
    }
    if (tid == 0) {
        part[((size_t)c * CHUNKS + chunk) * 2 + 0] = (float)sh1[0];
        part[((size_t)c * CHUNKS + chunk) * 2 + 1] = (float)sh2[0];
    }
}

template <int C, int HW, int CHUNKS>
__global__ __launch_bounds__(256) void stats_f32(const float* __restrict__ x,
                                                 float* __restrict__ part) {
    constexpr int S = (CHUNKS > 64) ? CHUNKS / 64 : 1;
    constexpr int BPC = 64 * S / CHUNKS;
    constexpr int SEG = HW / S;
    int c = blockIdx.x / CHUNKS;
    int chunk = blockIdx.x % CHUNKS;
    int b0 = (chunk / S) * BPC;
    int s0 = (chunk % S) * SEG;
    double s1 = 0.0, s2 = 0.0;
    for (int bi = 0; bi < BPC; ++bi) {
        const float* base = x + ((size_t)(b0 + bi) * C + c) * HW + s0;
        for (int p = threadIdx.x * 4; p < SEG; p += 1024) {
            float4 v = *(const float4*)(base + p);
            s1 += v.x; s2 += (double)v.x * v.x;
            s1 += v.y; s2 += (double)v.y * v.y;
            s1 += v.z; s2 += (double)v.z * v.z;
            s1 += v.w; s2 += (double)v.w * v.w;
        }
    }
    __shared__ double sh1[256];
    __shared__ double sh2[256];
    int tid = threadIdx.x;
    sh1[tid] = s1; sh2[tid] = s2;
    __syncthreads();
    for (int s = 128; s > 0; s >>= 1) {
        if (tid < s) { sh1[tid] += sh1[tid + s]; sh2[tid] += sh2[tid + s]; }
        __syncthreads();
    }
    if (tid == 0) {
        part[((size_t)c * CHUNKS + chunk) * 2 + 0] = (float)sh1[0];
        part[((size_t)c * CHUNKS + chunk) * 2 + 1] = (float)sh2[0];
    }
}

// ---------------- BN finalize (per-block, LDS) + leaky + padded bf16 write ----------------
template <int C, int H, int W, int CHUNKS, bool INB>
__global__ __launch_bounds__(256) void bn_pad_v(const void* __restrict__ in,
                                                const float* __restrict__ part,
                                                const float* __restrict__ g,
                                                const float* __restrict__ bbias,
                                                u16* __restrict__ outp) {
    constexpr int G = W / 8 + 1;
    constexpr int Wp = 8 * G;
    constexpr int Hp = H + 2;
    constexpr float invN = 1.f / (64.f * H * W);

    __shared__ float s_sc[C], s_sh[C];
    int t = threadIdx.x;
    if (t < C) {
        float s1 = 0.f, s2 = 0.f;
#pragma unroll 8
        for (int k = 0; k < CHUNKS; ++k) {
            s1 += part[((size_t)t * CHUNKS + k) * 2 + 0];
            s2 += part[((size_t)t * CHUNKS + k) * 2 + 1];
        }
        float mean = s1 * invN;
        float var  = s2 * invN - mean * mean;
        float inv  = rsqrtf(var + EPS);
        float sc   = inv * g[t];
        s_sc[t] = sc;
        s_sh[t] = bbias[t] - mean * sc;
    }
    __syncthreads();

    int idx = blockIdx.x * 256 + t;
    if (idx >= 64 * C * Hp * G) return;
    int m = idx % G;
    int hp = (idx / G) % Hp;
    int c = (idx / (G * Hp)) % C;
    int b = idx / (G * Hp * C);

    u16x8 o;
#pragma unroll
    for (int i = 0; i < 8; ++i) o[i] = 0;

    if (hp >= 1 && hp <= H) {
        float sc = s_sc[c], sh = s_sh[c];
        float vals[8];
        if (INB) {
            const u16* base = (const u16*)in + ((size_t)(b * C + c) * H + (hp - 1)) * W;
            vals[0] = (m > 0) ? b2f(base[8 * m - 1]) : 0.f;
            if (m < G - 1) {
                bf16x8 va = *(const bf16x8*)(base + 8 * m);
#pragma unroll
                for (int i = 0; i < 7; ++i) vals[i + 1] = b2f((u16)va[i]);
            }
        } else {
            const float* base = (const float*)in + ((size_t)(b * C + c) * H + (hp - 1)) * W;
            vals[0] = (m > 0) ? base[8 * m - 1] : 0.f;
            if (m < G - 1) {
                float4 a  = *(const float4*)(base + 8 * m);
                float4 b4 = *(const float4*)(base + 8 * m + 4);
                vals[1] = a.x; vals[2] = a.y; vals[3] = a.z; vals[4] = a.w;
                vals[5] = b4.x; vals[6] = b4.y; vals[7] = b4.z;
            }
        }
        if (m > 0) o[0] = f2b(leaky(vals[0] * sc + sh));
        if (m < G - 1) {
#pragma unroll
            for (int i = 1; i < 8; ++i) o[i] = f2b(leaky(vals[i] * sc + sh));
        }
    }
    *(u16x8*)(outp + ((size_t)(b * C + c) * Hp + hp) * Wp + 8 * m) = o;
}

// ---------------- L4: BN finalize (LDS) + leaky + im2col bf16 for conv5 ----------------
__global__ __launch_bounds__(256) void im2col5(const float* __restrict__ A,
                                               const float* __restrict__ part,
                                               const float* __restrict__ g,
                                               const float* __restrict__ bbias,
                                               u16* __restrict__ ic) {
    constexpr float invN = 1.f / 3072.f;
    __shared__ float s_sc[256], s_sh[256];
    int t = threadIdx.x;
    {
        float s1 = 0.f, s2 = 0.f;
#pragma unroll
        for (int k = 0; k < 16; ++k) {
            s1 += part[((size_t)t * 16 + k) * 2 + 0];
            s2 += part[((size_t)t * 16 + k) * 2 + 1];
        }
        float mean = s1 * invN;
        float var  = s2 * invN - mean * mean;
        float inv  = rsqrtf(var + EPS);
        float sc   = inv * g[t];
        s_sc[t] = sc;
        s_sh[t] = bbias[t] - mean * sc;
    }
    __syncthreads();

    int idx = blockIdx.x * 256 + t;
    if (idx >= 1472 * 1024) return;
    int k = idx & 1023;
    int n = idx >> 10;
    int b = n / 23, j = n % 23;
    int ci = k >> 2, kh = (k >> 1) & 1, kw = k & 1;
    float v = A[(size_t)b * 12288 + ci * 48 + kh * 24 + j + kw];
    v = leaky(v * s_sc[ci] + s_sh[ci]);
    ic[idx] = f2b(v);
}

// ---------------- conv5 GEMM: [1024 x 1024] x [1024 x 1472], 32x32 per wave ----------------
__global__ __launch_bounds__(256) void conv5_mfma2(const u16* __restrict__ ic,
                                                   const u16* __restrict__ w5b,
                                                   u16* __restrict__ ic2) {
    int tid = threadIdx.x;
    int wave = tid >> 6;
    int lane = tid & 63;
    int r = lane & 15;
    int quad = lane >> 4;
    int gx = blockIdx.x % 23;      // n-block (64)
    int gy = blockIdx.x / 23;      // m-block (64), 0..15
    int m0 = gy * 64 + (wave >> 1) * 32;
    int n0 = gx * 64 + (wave & 1) * 32;

    const u16* pA0 = w5b + (size_t)(m0 + r) * 1024 + quad * 8;
    const u16* pA1 = pA0 + 16 * 1024;
    const u16* pB0 = ic + (size_t)(n0 + r) * 1024 + quad * 8;
    const u16* pB1 = pB0 + 16 * 1024;

    f32x4 a00 = {0.f,0.f,0.f,0.f}, a01 = {0.f,0.f,0.f,0.f};
    f32x4 a10 = {0.f,0.f,0.f,0.f}, a11 = {0.f,0.f,0.f,0.f};

#pragma unroll 4
    for (int kk = 0; kk < 32; ++kk) {
        bf16x8 fa0 = *(const bf16x8*)pA0;
        bf16x8 fa1 = *(const bf16x8*)pA1;
        bf16x8 fb0 = *(const bf16x8*)pB0;
        bf16x8 fb1 = *(const bf16x8*)pB1;
        a00 = __builtin_amdgcn_mfma_f32_16x16x32_bf16(fa0, fb0, a00, 0, 0, 0);
        a01 = __builtin_amdgcn_mfma_f32_16x16x32_bf16(fa0, fb1, a01, 0, 0, 0);
        a10 = __builtin_amdgcn_mfma_f32_16x16x32_bf16(fa1, fb0, a10, 0, 0, 0);
        a11 = __builtin_amdgcn_mfma_f32_16x16x32_bf16(fa1, fb1, a11, 0, 0, 0);
        pA0 += 32; pA1 += 32; pB0 += 32; pB1 += 32;
    }

#pragma unroll
    for (int mi = 0; mi < 2; ++mi) {
#pragma unroll
        for (int ni = 0; ni < 2; ++ni) {
            f32x4 acc = (mi == 0) ? (ni == 0 ? a00 : a01) : (ni == 0 ? a10 : a11);
            int n = n0 + ni * 16 + r;
            int co0 = m0 + mi * 16 + quad * 4;
            u16x4 pk;
#pragma unroll
            for (int j = 0; j < 4; ++j) pk[j] = f2b(leaky(acc[j]));
            *(u16x4*)(ic2 + (size_t)n * 1024 + co0) = pk;
        }
    }
}

// ---------------- linear as MFMA GEMM [64 x 1024] x [1024 x 1472] + sigmoid ----------------
__global__ __launch_bounds__(256) void linear_mfma(const u16* __restrict__ ic2,
                                                   const u16* __restrict__ lwb,
                                                   float* __restrict__ sig) {
    int tid = threadIdx.x;
    int wid = blockIdx.x * 4 + (tid >> 6);
    int lane = tid & 63;
    int r = lane & 15;
    int quad = lane >> 4;
    int mt = wid & 3;           // 4 m-tiles (64 rows)
    int nt = wid >> 2;          // 92 n-tiles

    int n = nt * 16 + r;
    const u16* pA = lwb + (size_t)(mt * 16 + r) * 1024 + quad * 8;
    const u16* pB = ic2 + (size_t)n * 1024 + quad * 8;

    f32x4 acc = {0.f, 0.f, 0.f, 0.f};
#pragma unroll 4
    for (int kk = 0; kk < 32; ++kk) {
        bf16x8 a = *(const bf16x8*)pA;
        bf16x8 bv = *(const bf16x8*)pB;
        acc = __builtin_amdgcn_mfma_f32_16x16x32_bf16(a, bv, acc, 0, 0, 0);
        pA += 32;
        pB += 32;
    }

    int b = n / 23, j = n % 23;
#pragma unroll
    for (int jj = 0; jj < 4; ++jj) {
        int o = mt * 16 + quad * 4 + jj;
        float v = 1.f / (1.f + expf(-acc[jj]));
        sig[(size_t)b * 1472 + (size_t)o * 23 + j] = v;
    }
}

// ---------------- final interleave/shuffle ----------------
__global__ void shuffle_out_kernel(const float* __restrict__ sig, float* __restrict__ out) {
    int idx = blockIdx.x * blockDim.x + threadIdx.x;
    if (idx >= 64 * 768) return;
    int o = idx % 32;
    int j = (idx / 32) % 24;
    int b = idx / 768;
    const float* s = sig + (size_t)b * 64 * 23;
    float v;
    if (j == 0)       v = s[o * 23];
    else if (j == 23) v = s[(o + 32) * 23 + 22];
    else              v = 0.5f * (s[(o + 32) * 23 + (j - 1)] + s[o * 23 + j]);
    out[idx] = v;
}

extern "C" void kernel_launch(void* const* d_in, const int* in_sizes, int n_in,
                              void* d_out, int out_size, void* d_ws, size_t ws_size,
                              hipStream_t stream) {
    (void)in_sizes; (void)n_in; (void)out_size; (void)ws_size;

    const float* x = (const float*)d_in[0];
    const float* w[5]; const float* g[5]; const float* bb[5];
    for (int i = 0; i < 5; ++i) {
        w[i]  = (const float*)d_in[1 + 3 * i];
        g[i]  = (const float*)d_in[2 + 3 * i];
        bb[i] = (const float*)d_in[3 + 3 * i];
    }
    const float* w5 = (const float*)d_in[16];
    const float* lw = (const float*)d_in[17];
    float* out = (float*)d_out;

    // ---- workspace layout (~60 MB) ----
    float* ws   = (float*)d_ws;
    float* A    = ws;                          // 6,291,456 f32 (conv-out; L0 as u16)
    u16*   P    = (u16*)(ws + 6291456);        // up to 13,647,872 u16 (padded inputs)
    u16*   wbf  = (u16*)(ws + 13115392);       // 697,344 u16
    float* part = ws + 13464064;               // 8,192 f32 (max C*CHUNKS*2 = 4096 used)
    u16*   w5b  = (u16*)(ws + 13474304);       // 1,048,576 u16 (w5 padded to 1024 rows)
    u16*   ic   = (u16*)(ws + 13998592);       // 1,507,328 u16 (conv5 B-matrix)
    u16*   ic2  = (u16*)(ws + 14752256);       // 1,507,328 u16 (linear B-matrix)
    u16*   lwb  = (u16*)(ws + 15505920);       // 65,536 u16 (lw K-padded)
    float* sig  = ws + 2359296;                // (64,64,23) f32 (inside dead A region)

    const size_t wofs[5] = {0, 1024, 9216, 41984, 173056};

    // ---- single prep kernel: all weights + x padding ----
    hipLaunchKernelGGL(prep, dim3(13478), dim3(256), 0, stream,
                       x, w[0], w[1], w[2], w[3], w[4], w5, lw, wbf, w5b, lwb, P);

    // L0: conv -> bf16 A  (NT=8: 49152 n-tiles / 8 = 6144 waves, 1536 blocks)
    hipLaunchKernelGGL((conv_mfma<16, 4, 64, 64, 768, 66, 776, 1, 8, true>),
                       dim3(1536), dim3(256), 0, stream, P, wbf + wofs[0], A);
    hipLaunchKernelGGL((stats_bf<16, 12288, 128>), dim3(2048), dim3(256), 0, stream,
                       (const u16*)A, part);
    hipLaunchKernelGGL((bn_pad_v<16, 32, 384, 128, true>), dim3(6664), dim3(256), 0, stream,
                       (const void*)A, part, g[0], bb[0], P);

    // L1: MT=2, NT=2 (12288 n-tiles / 2 = 6144 waves, 1536 blocks)
    hipLaunchKernelGGL((conv_mfma<32, 16, 256, 32, 384, 34, 392, 2, 2, false>),
                       dim3(1536), dim3(256), 0, stream, P, wbf + wofs[1], A);
    hipLaunchKernelGGL((stats_f32<32, 3072, 64>), dim3(2048), dim3(256), 0, stream, A, part);
    hipLaunchKernelGGL((bn_pad_v<32, 16, 192, 64, false>), dim3(3600), dim3(256), 0, stream,
                       (const void*)A, part, g[1], bb[1], P);

    // L2: MT=4, NT=2 (3072 n-tiles / 2 = 1536 waves, 384 blocks)
    hipLaunchKernelGGL((conv_mfma<64, 32, 512, 16, 192, 18, 200, 4, 2, false>),
                       dim3(384), dim3(256), 0, stream, P, wbf + wofs[2], A);
    hipLaunchKernelGGL((stats_f32<64, 768, 32>), dim3(2048), dim3(256), 0, stream, A, part);
    hipLaunchKernelGGL((bn_pad_v<64, 8, 96, 32, false>), dim3(2080), dim3(256), 0, stream,
                       (const void*)A, part, g[2], bb[2], P);

    // L3: MT=4, MG=2, NT=1 (waves 1536, blocks 384)
    hipLaunchKernelGGL((conv_mfma<128, 64, 1024, 8, 96, 10, 104, 4, 1, false>),
                       dim3(384), dim3(256), 0, stream, P, wbf + wofs[3], A);
    hipLaunchKernelGGL((stats_f32<128, 192, 16>), dim3(2048), dim3(256), 0, stream, A, part);
    hipLaunchKernelGGL((bn_pad_v<128, 4, 48, 16, false>), dim3(1344), dim3(256), 0, stream,
                       (const void*)A, part, g[3], bb[3], P);

    // L4: MT=4, MG=4, NT=1 (waves 768, blocks 192)
    hipLaunchKernelGGL((conv_mfma<256, 128, 2048, 4, 48, 6, 56, 4, 1, false>),
                       dim3(192), dim3(256), 0, stream, P, wbf + wofs[4], A);
    hipLaunchKernelGGL((stats_f32<256, 48, 16>), dim3(4096), dim3(256), 0, stream, A, part);
    hipLaunchKernelGGL(im2col5, dim3(5888), dim3(256), 0, stream,
                       A, part, g[4], bb[4], ic);

    // tail: conv5 GEMM -> ic2 (bf16), linear GEMM + sigmoid -> sig, shuffle
    hipLaunchKernelGGL(conv5_mfma2, dim3(368), dim3(256), 0, stream, ic, w5b, ic2);
    hipLaunchKernelGGL(linear_mfma, dim3(92), dim3(256), 0, stream, ic2, lwb, sig);
    hipLaunchKernelGGL(shuffle_out_kernel, dim3((64 * 768 + 255) / 256), dim3(256), 0, stream,
                       sig, out);
}

// Round 13
// 246.666 us; speedup vs baseline: 19.0508x; 1.2326x over previous
//
#include <hip/hip_runtime.h>
#include <cmath>

#define EPS 1e-5f
#define SLOPE 0.2f

typedef unsigned short u16;
typedef unsigned int u32;
typedef __attribute__((ext_vector_type(8))) short bf16x8;
typedef __attribute__((ext_vector_type(8))) unsigned short u16x8;
typedef __attribute__((ext_vector_type(4))) unsigned short u16x4;
typedef __attribute__((ext_vector_type(4))) float f32x4;

__device__ __forceinline__ u16 f2b(float f) {
    union { float f; u32 u; } v; v.f = f;
    u32 r = (v.u + 0x7FFF + ((v.u >> 16) & 1)) >> 16;
    return (u16)r;
}
__device__ __forceinline__ float b2f(u16 h) {
    union { u32 u; float f; } v; v.u = ((u32)h) << 16;
    return v.f;
}
__device__ __forceinline__ float leaky(float v) { return v >= 0.f ? v : SLOPE * v; }

// ---------------- fused prep: all weight->bf16 converts + x padding ----------------
__global__ __launch_bounds__(256) void prep(const float* __restrict__ x,
                                            const float* __restrict__ w0,
                                            const float* __restrict__ w1,
                                            const float* __restrict__ w2,
                                            const float* __restrict__ w3,
                                            const float* __restrict__ w4,
                                            const float* __restrict__ w5,
                                            const float* __restrict__ lw,
                                            u16* __restrict__ wbf,
                                            u16* __restrict__ w5b,
                                            u16* __restrict__ lwb,
                                            u16* __restrict__ P) {
    int idx = blockIdx.x * 256 + threadIdx.x;
    if (idx < 697344) {
        const float* src; int K, Kp; int base;
        if (idx < 1024)        { src = w0; K = 48;   Kp = 64;   base = 0; }
        else if (idx < 9216)   { src = w1; K = 256;  Kp = 256;  base = 1024; }
        else if (idx < 41984)  { src = w2; K = 512;  Kp = 512;  base = 9216; }
        else if (idx < 173056) { src = w3; K = 1024; Kp = 1024; base = 41984; }
        else                   { src = w4; K = 2048; Kp = 2048; base = 173056; }
        int local = idx - base;
        int k = local % Kp;
        int co = local / Kp;
        wbf[idx] = (k < K) ? f2b(src[(size_t)co * K + k]) : (u16)0;
    } else if (idx < 1745920) {
        int local = idx - 697344;
        int k = local & 1023;
        int co = local >> 10;
        w5b[local] = (co < 1000) ? f2b(w5[(size_t)co * 1024 + k]) : (u16)0;
    } else if (idx < 1811456) {
        int local = idx - 1745920;
        int k = local & 1023;
        int o = local >> 10;
        lwb[local] = (k < 1000) ? f2b(lw[(size_t)o * 1000 + k]) : (u16)0;
    } else if (idx < 3450368) {
        constexpr int H = 64, W = 768, G = 97, Wp = 776, Hp = 66;
        int local = idx - 1811456;
        int m = local % G;
        int hp = (local / G) % Hp;
        int c = (local / (G * Hp)) % 4;
        int b = local / (G * Hp * 4);
        u16x8 o;
#pragma unroll
        for (int i = 0; i < 8; ++i) o[i] = 0;
        if (c < 3 && hp >= 1 && hp <= H) {
            const float* base = x + ((size_t)(b * 3 + c) * H + (hp - 1)) * W;
            if (m > 0) o[0] = f2b(base[8 * m - 1]);
            if (m < G - 1) {
                float4 a  = *(const float4*)(base + 8 * m);
                float4 b4 = *(const float4*)(base + 8 * m + 4);
                o[1] = f2b(a.x); o[2] = f2b(a.y); o[3] = f2b(a.z); o[4] = f2b(a.w);
                o[5] = f2b(b4.x); o[6] = f2b(b4.y); o[7] = f2b(b4.z);
            }
        }
        *(u16x8*)(P + ((size_t)(b * 4 + c) * Hp + hp) * Wp + 8 * m) = o;
    }
}

// ---------------- implicit-GEMM MFMA conv, MT x NT tiles per wave, P-way K-split ----------------
template <int Co, int CiPad, int Kp, int Hi, int Wi, int Hp, int Wp, int MT, int NT, int P, bool OB>
__global__ __launch_bounds__(256) void conv_mfma(const u16* __restrict__ inp,
                                                 const u16* __restrict__ wt,
                                                 void* __restrict__ outv) {
    constexpr int Ho = Hi / 2, Wo = Wi / 2, HW = Ho * Wo;
    constexpr int MG = Co / 16 / MT;
    constexpr int KPP = Kp / P;
    constexpr size_t TOT = (size_t)64 * Co * HW;

    int tid = threadIdx.x;
    int wid = blockIdx.x * 4 + (tid >> 6);
    int p = blockIdx.y;
    int lane = tid & 63;
    int r = lane & 15;
    int quad = lane >> 4;
    int mg = wid % MG;
    int ng = wid / MG;

    int ciq = quad >> 1;
    int kh0 = (quad & 1) * 2;

    const u16* pB[NT];
    int b_[NT], hw_[NT];
#pragma unroll
    for (int i = 0; i < NT; ++i) {
        int n = (ng * NT + i) * 16 + r;
        int b = n / HW;
        int hw = n % HW;
        int oh = hw / Wo;
        int ow = hw % Wo;
        b_[i] = b; hw_[i] = hw;
        pB[i] = inp + ((size_t)(b * CiPad + p * (CiPad / P) + ciq) * Hp + (2 * oh + kh0)) * Wp + 2 * ow;
    }
    const u16* pA = wt + (size_t)(mg * MT * 16 + r) * Kp + p * KPP + quad * 8;

    f32x4 acc[MT][NT];
#pragma unroll
    for (int mt = 0; mt < MT; ++mt)
#pragma unroll
        for (int i = 0; i < NT; ++i) acc[mt][i] = (f32x4){0.f, 0.f, 0.f, 0.f};

#pragma unroll 2
    for (int kk = 0; kk < KPP / 32; ++kk) {
        bf16x8 a[MT];
#pragma unroll
        for (int mt = 0; mt < MT; ++mt)
            a[mt] = *(const bf16x8*)(pA + (size_t)mt * 16 * Kp);
#pragma unroll
        for (int i = 0; i < NT; ++i) {
            union { u32 u[4]; bf16x8 v; } bb;
            bb.u[0] = *(const u32*)(pB[i]);
            bb.u[1] = *(const u32*)(pB[i] + 2);
            bb.u[2] = *(const u32*)(pB[i] + Wp);
            bb.u[3] = *(const u32*)(pB[i] + Wp + 2);
#pragma unroll
            for (int mt = 0; mt < MT; ++mt)
                acc[mt][i] = __builtin_amdgcn_mfma_f32_16x16x32_bf16(a[mt], bb.v, acc[mt][i], 0, 0, 0);
            pB[i] += (size_t)2 * Hp * Wp;
        }
        pA += 32;
    }

#pragma unroll
    for (int mt = 0; mt < MT; ++mt) {
        int co0 = mg * MT * 16 + mt * 16 + quad * 4;
#pragma unroll
        for (int i = 0; i < NT; ++i) {
            if (OB) {
                u16* o = (u16*)outv;
#pragma unroll
                for (int j = 0; j < 4; ++j)
                    o[((size_t)b_[i] * Co + co0 + j) * HW + hw_[i]] = f2b(acc[mt][i][j]);
            } else {
                float* o = (float*)outv + (size_t)p * TOT;
#pragma unroll
                for (int j = 0; j < 4; ++j)
                    o[((size_t)b_[i] * Co + co0 + j) * HW + hw_[i]] = acc[mt][i][j];
            }
        }
    }
}

// ---------------- BN stats: vectorized, deterministic, CHUNKS-scalable, P-plane sum ----------------
template <int C, int HW, int CHUNKS>
__global__ __launch_bounds__(256) void stats_bf(const u16* __restrict__ x,
                                                float* __restrict__ part) {
    constexpr int S = (CHUNKS > 64) ? CHUNKS / 64 : 1;
    constexpr int BPC = 64 * S / CHUNKS;
    constexpr int SEG = HW / S;
    int c = blockIdx.x / CHUNKS;
    int chunk = blockIdx.x % CHUNKS;
    int b0 = (chunk / S) * BPC;
    int s0 = (chunk % S) * SEG;
    double s1 = 0.0, s2 = 0.0;
    for (int bi = 0; bi < BPC; ++bi) {
        const u16* base = x + ((size_t)(b0 + bi) * C + c) * HW + s0;
        for (int p = threadIdx.x * 8; p < SEG; p += 2048) {
            bf16x8 v = *(const bf16x8*)(base + p);
#pragma unroll
            for (int e = 0; e < 8; ++e) {
                float f = b2f((u16)v[e]);
                s1 += f; s2 += (double)f * f;
            }
        }
    }
    __shared__ double sh1[256];
    __shared__ double sh2[256];
    int tid = threadIdx.x;
    sh1[tid] = s1; sh2[tid] = s2;
    __syncthreads();
    for (int s = 128; s > 0; s >>= 1) {
        if (tid < s) { sh1[tid] += sh1[tid + s]; sh2[tid] += sh2[tid + s]; }
        __syncthreads();
    }
    if (tid == 0) {
        part[((size_t)c * CHUNKS + chunk) * 2 + 0] = (float)sh1[0];
        part[((size_t)c * CHUNKS + chunk) * 2 + 1] = (float)sh2[0];
    }
}

template <int C, int HW, int CHUNKS, int P>
__global__ __launch_bounds__(256) void stats_f32(const float* __restrict__ x,
                                                 float* __restrict__ part) {
    constexpr int S = (CHUNKS > 64) ? CHUNKS / 64 : 1;
    constexpr int BPC = 64 * S / CHUNKS;
    constexpr int SEG = HW / S;
    constexpr size_t TOT = (size_t)64 * C * HW;
    int c = blockIdx.x / CHUNKS;
    int chunk = blockIdx.x % CHUNKS;
    int b0 = (chunk / S) * BPC;
    int s0 = (chunk % S) * SEG;
    double s1 = 0.0, s2 = 0.0;
    for (int bi = 0; bi < BPC; ++bi) {
        const float* base = x + ((size_t)(b0 + bi) * C + c) * HW + s0;
        for (int p = threadIdx.x * 4; p < SEG; p += 1024) {
            float4 v = *(const float4*)(base + p);
            if (P == 2) {
                float4 v2 = *(const float4*)(base + TOT + p);
                v.x += v2.x; v.y += v2.y; v.z += v2.z; v.w += v2.w;
            }
            s1 += v.x; s2 += (double)v.x * v.x;
            s1 += v.y; s2 += (double)v.y * v.y;
            s1 += v.z; s2 += (double)v.z * v.z;
            s1 += v.w; s2 += (double)v.w * v.w;
        }
    }
    __shared__ double sh1[256];
    __shared__ double sh2[256];
    int tid = threadIdx.x;
    sh1[tid] = s1; sh2[tid] = s2;
    __syncthreads();
    for (int s = 128; s > 0; s >>= 1) {
        if (tid < s) { sh1[tid] += sh1[tid + s]; sh2[tid] += sh2[tid + s]; }
        __syncthreads();
    }
    if (tid == 0) {
        part[((size_t)c * CHUNKS + chunk) * 2 + 0] = (float)sh1[0];
        part[((size_t)c * CHUNKS + chunk) * 2 + 1] = (float)sh2[0];
    }
}

// ---------------- tiny per-layer finalize: part -> ss (scale, shift) ----------------
template <int C, int CHUNKS>
__global__ void bn_finalize(const float* __restrict__ part, const float* __restrict__ g,
                            const float* __restrict__ bb, float* __restrict__ ss,
                            float invN) {
    int c = threadIdx.x;
    if (c >= C) return;
    float s1 = 0.f, s2 = 0.f;
#pragma unroll 8
    for (int k = 0; k < CHUNKS; ++k) {
        s1 += part[((size_t)c * CHUNKS + k) * 2 + 0];
        s2 += part[((size_t)c * CHUNKS + k) * 2 + 1];
    }
    float mean = s1 * invN;
    float var  = s2 * invN - mean * mean;
    float inv  = rsqrtf(var + EPS);
    float sc   = inv * g[c];
    ss[c]     = sc;
    ss[C + c] = bb[c] - mean * sc;
}

// ---------------- BN apply + leaky + padded bf16 write (reads ss; optional plane-sum) ----------------
template <int C, int H, int W, bool INB, bool SPLIT>
__global__ __launch_bounds__(256) void bn_pad_v(const void* __restrict__ in,
                                                const float* __restrict__ ss,
                                                u16* __restrict__ outp) {
    constexpr int G = W / 8 + 1;
    constexpr int Wp = 8 * G;
    constexpr int Hp = H + 2;
    constexpr size_t TOT = (size_t)64 * C * H * W;
    int idx = blockIdx.x * 256 + threadIdx.x;
    if (idx >= 64 * C * Hp * G) return;
    int m = idx % G;
    int hp = (idx / G) % Hp;
    int c = (idx / (G * Hp)) % C;
    int b = idx / (G * Hp * C);

    u16x8 o;
#pragma unroll
    for (int i = 0; i < 8; ++i) o[i] = 0;

    if (hp >= 1 && hp <= H) {
        float sc = ss[c], sh = ss[C + c];
        float vals[8];
        if (INB) {
            const u16* base = (const u16*)in + ((size_t)(b * C + c) * H + (hp - 1)) * W;
            vals[0] = (m > 0) ? b2f(base[8 * m - 1]) : 0.f;
            if (m < G - 1) {
                bf16x8 va = *(const bf16x8*)(base + 8 * m);
#pragma unroll
                for (int i = 0; i < 7; ++i) vals[i + 1] = b2f((u16)va[i]);
            }
        } else {
            const float* base = (const float*)in + ((size_t)(b * C + c) * H + (hp - 1)) * W;
            if (m > 0) {
                vals[0] = base[8 * m - 1];
                if (SPLIT) vals[0] += base[TOT + 8 * m - 1];
            } else vals[0] = 0.f;
            if (m < G - 1) {
                float4 a  = *(const float4*)(base + 8 * m);
                float4 b4 = *(const float4*)(base + 8 * m + 4);
                if (SPLIT) {
                    float4 a2  = *(const float4*)(base + TOT + 8 * m);
                    float4 b42 = *(const float4*)(base + TOT + 8 * m + 4);
                    a.x += a2.x; a.y += a2.y; a.z += a2.z; a.w += a2.w;
                    b4.x += b42.x; b4.y += b42.y; b4.z += b42.z; b4.w += b42.w;
                }
                vals[1] = a.x; vals[2] = a.y; vals[3] = a.z; vals[4] = a.w;
                vals[5] = b4.x; vals[6] = b4.y; vals[7] = b4.z;
            }
        }
        if (m > 0) o[0] = f2b(leaky(vals[0] * sc + sh));
        if (m < G - 1) {
#pragma unroll
            for (int i = 1; i < 8; ++i) o[i] = f2b(leaky(vals[i] * sc + sh));
        }
    }
    *(u16x8*)(outp + ((size_t)(b * C + c) * Hp + hp) * Wp + 8 * m) = o;
}

// ---------------- L4: BN + leaky + im2col bf16 (reads ss; sums 2 K-split planes) ----------------
__global__ __launch_bounds__(256) void im2col5(const float* __restrict__ A,
                                               const float* __restrict__ ss,
                                               u16* __restrict__ ic) {
    int idx = blockIdx.x * 256 + threadIdx.x;
    if (idx >= 1472 * 1024) return;
    int k = idx & 1023;
    int n = idx >> 10;
    int b = n / 23, j = n % 23;
    int ci = k >> 2, kh = (k >> 1) & 1, kw = k & 1;
    size_t off = (size_t)b * 12288 + ci * 48 + kh * 24 + j + kw;
    float v = A[off] + A[786432 + off];
    v = leaky(v * ss[ci] + ss[256 + ci]);
    ic[idx] = f2b(v);
}

// ---------------- conv5 GEMM, LDS-staged 64x64 block tile (4 waves 2x2, 32x32 each) ----------------
__global__ __launch_bounds__(256) void conv5_lds(const u16* __restrict__ ic,
                                                 const u16* __restrict__ w5b,
                                                 u16* __restrict__ ic2) {
    __shared__ u16 As[64][72];
    __shared__ u16 Bs[64][72];
    int tid = threadIdx.x;
    int wv = tid >> 6;
    int lane = tid & 63;
    int r = lane & 15;
    int quad = lane >> 4;
    int gx = blockIdx.x % 23;      // n-block (64)
    int gy = blockIdx.x / 23;      // m-block (64)

    int trow = tid >> 3;           // 0..31
    int tcol = (tid & 7) * 8;

    f32x4 acc[2][2];
#pragma unroll
    for (int mi = 0; mi < 2; ++mi)
#pragma unroll
        for (int ni = 0; ni < 2; ++ni) acc[mi][ni] = (f32x4){0.f, 0.f, 0.f, 0.f};

    for (int ko = 0; ko < 16; ++ko) {
        int kbase = ko * 64;
        *(bf16x8*)&As[trow][tcol]      = *(const bf16x8*)(w5b + (size_t)(gy * 64 + trow) * 1024 + kbase + tcol);
        *(bf16x8*)&As[trow + 32][tcol] = *(const bf16x8*)(w5b + (size_t)(gy * 64 + trow + 32) * 1024 + kbase + tcol);
        *(bf16x8*)&Bs[trow][tcol]      = *(const bf16x8*)(ic  + (size_t)(gx * 64 + trow) * 1024 + kbase + tcol);
        *(bf16x8*)&Bs[trow + 32][tcol] = *(const bf16x8*)(ic  + (size_t)(gx * 64 + trow + 32) * 1024 + kbase + tcol);
        __syncthreads();
#pragma unroll
        for (int k2 = 0; k2 < 2; ++k2) {
            int koff = k2 * 32 + quad * 8;
            bf16x8 a0 = *(const bf16x8*)&As[(wv >> 1) * 32 + r][koff];
            bf16x8 a1 = *(const bf16x8*)&As[(wv >> 1) * 32 + 16 + r][koff];
            bf16x8 b0 = *(const bf16x8*)&Bs[(wv & 1) * 32 + r][koff];
            bf16x8 b1 = *(const bf16x8*)&Bs[(wv & 1) * 32 + 16 + r][koff];
            acc[0][0] = __builtin_amdgcn_mfma_f32_16x16x32_bf16(a0, b0, acc[0][0], 0, 0, 0);
            acc[0][1] = __builtin_amdgcn_mfma_f32_16x16x32_bf16(a0, b1, acc[0][1], 0, 0, 0);
            acc[1][0] = __builtin_amdgcn_mfma_f32_16x16x32_bf16(a1, b0, acc[1][0], 0, 0, 0);
            acc[1][1] = __builtin_amdgcn_mfma_f32_16x16x32_bf16(a1, b1, acc[1][1], 0, 0, 0);
        }
        __syncthreads();
    }

#pragma unroll
    for (int mi = 0; mi < 2; ++mi) {
#pragma unroll
        for (int ni = 0; ni < 2; ++ni) {
            int n = gx * 64 + (wv & 1) * 32 + ni * 16 + r;
            int co0 = gy * 64 + (wv >> 1) * 32 + mi * 16 + quad * 4;
            u16x4 pk;
#pragma unroll
            for (int j = 0; j < 4; ++j) pk[j] = f2b(leaky(acc[mi][ni][j]));
            *(u16x4*)(ic2 + (size_t)n * 1024 + co0) = pk;
        }
    }
}

// ---------------- linear as MFMA GEMM [64 x 1024] x [1024 x 1472] + sigmoid ----------------
__global__ __launch_bounds__(256) void linear_mfma(const u16* __restrict__ ic2,
                                                   const u16* __restrict__ lwb,
                                                   float* __restrict__ sig) {
    int tid = threadIdx.x;
    int wid = blockIdx.x * 4 + (tid >> 6);
    int lane = tid & 63;
    int r = lane & 15;
    int quad = lane >> 4;
    int mt = wid & 3;
    int nt = wid >> 2;

    int n = nt * 16 + r;
    const u16* pA = lwb + (size_t)(mt * 16 + r) * 1024 + quad * 8;
    const u16* pB = ic2 + (size_t)n * 1024 + quad * 8;

    f32x4 acc = {0.f, 0.f, 0.f, 0.f};
#pragma unroll 4
    for (int kk = 0; kk < 32; ++kk) {
        bf16x8 a = *(const bf16x8*)pA;
        bf16x8 bv = *(const bf16x8*)pB;
        acc = __builtin_amdgcn_mfma_f32_16x16x32_bf16(a, bv, acc, 0, 0, 0);
        pA += 32;
        pB += 32;
    }

    int b = n / 23, j = n % 23;
#pragma unroll
    for (int jj = 0; jj < 4; ++jj) {
        int o = mt * 16 + quad * 4 + jj;
        float v = 1.f / (1.f + expf(-acc[jj]));
        sig[(size_t)b * 1472 + (size_t)o * 23 + j] = v;
    }
}

// ---------------- final interleave/shuffle ----------------
__global__ void shuffle_out_kernel(const float* __restrict__ sig, float* __restrict__ out) {
    int idx = blockIdx.x * blockDim.x + threadIdx.x;
    if (idx >= 64 * 768) return;
    int o = idx % 32;
    int j = (idx / 32) % 24;
    int b = idx / 768;
    const float* s = sig + (size_t)b * 64 * 23;
    float v;
    if (j == 0)       v = s[o * 23];
    else if (j == 23) v = s[(o + 32) * 23 + 22];
    else              v = 0.5f * (s[(o + 32) * 23 + (j - 1)] + s[o * 23 + j]);
    out[idx] = v;
}

extern "C" void kernel_launch(void* const* d_in, const int* in_sizes, int n_in,
                              void* d_out, int out_size, void* d_ws, size_t ws_size,
                              hipStream_t stream) {
    (void)in_sizes; (void)n_in; (void)out_size; (void)ws_size;

    const float* x = (const float*)d_in[0];
    const float* w[5]; const float* g[5]; const float* bb[5];
    for (int i = 0; i < 5; ++i) {
        w[i]  = (const float*)d_in[1 + 3 * i];
        g[i]  = (const float*)d_in[2 + 3 * i];
        bb[i] = (const float*)d_in[3 + 3 * i];
    }
    const float* w5 = (const float*)d_in[16];
    const float* lw = (const float*)d_in[17];
    float* out = (float*)d_out;

    // ---- workspace layout (~60 MB) ----
    float* ws   = (float*)d_ws;
    float* A    = ws;                          // 6,291,456 f32 (conv-out; L0 as u16; L3/L4 2 planes)
    u16*   P    = (u16*)(ws + 6291456);        // up to 13,647,872 u16 (padded inputs)
    u16*   wbf  = (u16*)(ws + 13115392);       // 697,344 u16
    float* part = ws + 13464064;               // 8,192 f32
    float* ss   = ws + 13472256;               // 512 f32 (scale/shift)
    u16*   w5b  = (u16*)(ws + 13474304);       // 1,048,576 u16
    u16*   ic   = (u16*)(ws + 13998592);       // 1,507,328 u16 (conv5 B-matrix)
    u16*   ic2  = (u16*)(ws + 14752256);       // 1,507,328 u16 (linear B-matrix)
    u16*   lwb  = (u16*)(ws + 15505920);       // 65,536 u16
    float* sig  = ws + 2359296;                // (64,64,23) f32 (dead A region)

    const size_t wofs[5] = {0, 1024, 9216, 41984, 173056};

    hipLaunchKernelGGL(prep, dim3(13478), dim3(256), 0, stream,
                       x, w[0], w[1], w[2], w[3], w[4], w5, lw, wbf, w5b, lwb, P);

    // L0
    hipLaunchKernelGGL((conv_mfma<16, 4, 64, 64, 768, 66, 776, 1, 8, 1, true>),
                       dim3(1536), dim3(256), 0, stream, P, wbf + wofs[0], A);
    hipLaunchKernelGGL((stats_bf<16, 12288, 128>), dim3(2048), dim3(256), 0, stream,
                       (const u16*)A, part);
    hipLaunchKernelGGL((bn_finalize<16, 128>), dim3(1), dim3(256), 0, stream,
                       part, g[0], bb[0], ss, 1.f / 786432.f);
    hipLaunchKernelGGL((bn_pad_v<16, 32, 384, true, false>), dim3(6664), dim3(256), 0, stream,
                       (const void*)A, ss, P);

    // L1
    hipLaunchKernelGGL((conv_mfma<32, 16, 256, 32, 384, 34, 392, 2, 2, 1, false>),
                       dim3(1536), dim3(256), 0, stream, P, wbf + wofs[1], A);
    hipLaunchKernelGGL((stats_f32<32, 3072, 64, 1>), dim3(2048), dim3(256), 0, stream, A, part);
    hipLaunchKernelGGL((bn_finalize<32, 64>), dim3(1), dim3(256), 0, stream,
                       part, g[1], bb[1], ss, 1.f / 196608.f);
    hipLaunchKernelGGL((bn_pad_v<32, 16, 192, false, false>), dim3(3600), dim3(256), 0, stream,
                       (const void*)A, ss, P);

    // L2
    hipLaunchKernelGGL((conv_mfma<64, 32, 512, 16, 192, 18, 200, 4, 2, 1, false>),
                       dim3(384), dim3(256), 0, stream, P, wbf + wofs[2], A);
    hipLaunchKernelGGL((stats_f32<64, 768, 32, 1>), dim3(2048), dim3(256), 0, stream, A, part);
    hipLaunchKernelGGL((bn_finalize<64, 32>), dim3(1), dim3(256), 0, stream,
                       part, g[2], bb[2], ss, 1.f / 49152.f);
    hipLaunchKernelGGL((bn_pad_v<64, 8, 96, false, false>), dim3(2080), dim3(256), 0, stream,
                       (const void*)A, ss, P);

    // L3: K-split P=2 (768 blocks total)
    hipLaunchKernelGGL((conv_mfma<128, 64, 1024, 8, 96, 10, 104, 4, 1, 2, false>),
                       dim3(384, 2), dim3(256), 0, stream, P, wbf + wofs[3], A);
    hipLaunchKernelGGL((stats_f32<128, 192, 16, 2>), dim3(2048), dim3(256), 0, stream, A, part);
    hipLaunchKernelGGL((bn_finalize<128, 16>), dim3(1), dim3(256), 0, stream,
                       part, g[3], bb[3], ss, 1.f / 12288.f);
    hipLaunchKernelGGL((bn_pad_v<128, 4, 48, false, true>), dim3(1344), dim3(256), 0, stream,
                       (const void*)A, ss, P);

    // L4: K-split P=2 (384 blocks total)
    hipLaunchKernelGGL((conv_mfma<256, 128, 2048, 4, 48, 6, 56, 4, 1, 2, false>),
                       dim3(192, 2), dim3(256), 0, stream, P, wbf + wofs[4], A);
    hipLaunchKernelGGL((stats_f32<256, 48, 16, 2>), dim3(4096), dim3(256), 0, stream, A, part);
    hipLaunchKernelGGL((bn_finalize<256, 16>), dim3(1), dim3(256), 0, stream,
                       part, g[4], bb[4], ss, 1.f / 3072.f);
    hipLaunchKernelGGL(im2col5, dim3(5888), dim3(256), 0, stream, A, ss, ic);

    // tail
    hipLaunchKernelGGL(conv5_lds, dim3(368), dim3(256), 0, stream, ic, w5b, ic2);
    hipLaunchKernelGGL(linear_mfma, dim3(92), dim3(256), 0, stream, ic2, lwb, sig);
    hipLaunchKernelGGL(shuffle_out_kernel, dim3((64 * 768 + 255) / 256), dim3(256), 0, stream,
                       sig, out);
}

// Round 14
// 236.344 us; speedup vs baseline: 19.8828x; 1.0437x over previous
//
#include <hip/hip_runtime.h>
#include <cmath>

#define EPS 1e-5f
#define SLOPE 0.2f

typedef unsigned short u16;
typedef unsigned int u32;
typedef __attribute__((ext_vector_type(8))) short bf16x8;
typedef __attribute__((ext_vector_type(8))) unsigned short u16x8;
typedef __attribute__((ext_vector_type(4))) unsigned short u16x4;
typedef __attribute__((ext_vector_type(4))) float f32x4;

__device__ __forceinline__ u16 f2b(float f) {
    union { float f; u32 u; } v; v.f = f;
    u32 r = (v.u + 0x7FFF + ((v.u >> 16) & 1)) >> 16;
    return (u16)r;
}
__device__ __forceinline__ float b2f(u16 h) {
    union { u32 u; float f; } v; v.u = ((u32)h) << 16;
    return v.f;
}
__device__ __forceinline__ float leaky(float v) { return v >= 0.f ? v : SLOPE * v; }

// ---------------- fused prep: all weight->bf16 converts + x padding ----------------
__global__ __launch_bounds__(256) void prep(const float* __restrict__ x,
                                            const float* __restrict__ w0,
                                            const float* __restrict__ w1,
                                            const float* __restrict__ w2,
                                            const float* __restrict__ w3,
                                            const float* __restrict__ w4,
                                            const float* __restrict__ w5,
                                            const float* __restrict__ lw,
                                            u16* __restrict__ wbf,
                                            u16* __restrict__ w5b,
                                            u16* __restrict__ lwb,
                                            u16* __restrict__ P) {
    int idx = blockIdx.x * 256 + threadIdx.x;
    if (idx < 697344) {
        const float* src; int K, Kp; int base;
        if (idx < 1024)        { src = w0; K = 48;   Kp = 64;   base = 0; }
        else if (idx < 9216)   { src = w1; K = 256;  Kp = 256;  base = 1024; }
        else if (idx < 41984)  { src = w2; K = 512;  Kp = 512;  base = 9216; }
        else if (idx < 173056) { src = w3; K = 1024; Kp = 1024; base = 41984; }
        else                   { src = w4; K = 2048; Kp = 2048; base = 173056; }
        int local = idx - base;
        int k = local % Kp;
        int co = local / Kp;
        wbf[idx] = (k < K) ? f2b(src[(size_t)co * K + k]) : (u16)0;
    } else if (idx < 1745920) {
        int local = idx - 697344;
        int k = local & 1023;
        int co = local >> 10;
        w5b[local] = (co < 1000) ? f2b(w5[(size_t)co * 1024 + k]) : (u16)0;
    } else if (idx < 1811456) {
        int local = idx - 1745920;
        int k = local & 1023;
        int o = local >> 10;
        lwb[local] = (k < 1000) ? f2b(lw[(size_t)o * 1000 + k]) : (u16)0;
    } else if (idx < 3450368) {
        constexpr int H = 64, W = 768, G = 97, Wp = 776, Hp = 66;
        int local = idx - 1811456;
        int m = local % G;
        int hp = (local / G) % Hp;
        int c = (local / (G * Hp)) % 4;
        int b = local / (G * Hp * 4);
        u16x8 o;
#pragma unroll
        for (int i = 0; i < 8; ++i) o[i] = 0;
        if (c < 3 && hp >= 1 && hp <= H) {
            const float* base = x + ((size_t)(b * 3 + c) * H + (hp - 1)) * W;
            if (m > 0) o[0] = f2b(base[8 * m - 1]);
            if (m < G - 1) {
                float4 a  = *(const float4*)(base + 8 * m);
                float4 b4 = *(const float4*)(base + 8 * m + 4);
                o[1] = f2b(a.x); o[2] = f2b(a.y); o[3] = f2b(a.z); o[4] = f2b(a.w);
                o[5] = f2b(b4.x); o[6] = f2b(b4.y); o[7] = f2b(b4.z);
            }
        }
        *(u16x8*)(P + ((size_t)(b * 4 + c) * Hp + hp) * Wp + 8 * m) = o;
    }
}

// ---------------- implicit-GEMM MFMA conv; optional fused BN-stats (needs MG==1) ----------------
template <int Co, int CiPad, int Kp, int Hi, int Wi, int Hp, int Wp, int MT, int NT, int P,
          bool OB, bool STATS>
__global__ __launch_bounds__(256) void conv_mfma(const u16* __restrict__ inp,
                                                 const u16* __restrict__ wt,
                                                 void* __restrict__ outv,
                                                 float* __restrict__ part) {
    constexpr int Ho = Hi / 2, Wo = Wi / 2, HW = Ho * Wo;
    constexpr int MG = Co / 16 / MT;
    constexpr int KPP = Kp / P;
    constexpr size_t TOT = (size_t)64 * Co * HW;

    int tid = threadIdx.x;
    int wid = blockIdx.x * 4 + (tid >> 6);
    int p = blockIdx.y;
    int lane = tid & 63;
    int r = lane & 15;
    int quad = lane >> 4;
    int mg = wid % MG;
    int ng = wid / MG;

    int ciq = quad >> 1;
    int kh0 = (quad & 1) * 2;

    const u16* pB[NT];
    int b_[NT], hw_[NT];
#pragma unroll
    for (int i = 0; i < NT; ++i) {
        int n = (ng * NT + i) * 16 + r;
        int b = n / HW;
        int hw = n % HW;
        int oh = hw / Wo;
        int ow = hw % Wo;
        b_[i] = b; hw_[i] = hw;
        pB[i] = inp + ((size_t)(b * CiPad + p * (CiPad / P) + ciq) * Hp + (2 * oh + kh0)) * Wp + 2 * ow;
    }
    const u16* pA = wt + (size_t)(mg * MT * 16 + r) * Kp + p * KPP + quad * 8;

    f32x4 acc[MT][NT];
#pragma unroll
    for (int mt = 0; mt < MT; ++mt)
#pragma unroll
        for (int i = 0; i < NT; ++i) acc[mt][i] = (f32x4){0.f, 0.f, 0.f, 0.f};

#pragma unroll 2
    for (int kk = 0; kk < KPP / 32; ++kk) {
        bf16x8 a[MT];
#pragma unroll
        for (int mt = 0; mt < MT; ++mt)
            a[mt] = *(const bf16x8*)(pA + (size_t)mt * 16 * Kp);
#pragma unroll
        for (int i = 0; i < NT; ++i) {
            union { u32 u[4]; bf16x8 v; } bb;
            bb.u[0] = *(const u32*)(pB[i]);
            bb.u[1] = *(const u32*)(pB[i] + 2);
            bb.u[2] = *(const u32*)(pB[i] + Wp);
            bb.u[3] = *(const u32*)(pB[i] + Wp + 2);
#pragma unroll
            for (int mt = 0; mt < MT; ++mt)
                acc[mt][i] = __builtin_amdgcn_mfma_f32_16x16x32_bf16(a[mt], bb.v, acc[mt][i], 0, 0, 0);
            pB[i] += (size_t)2 * Hp * Wp;
        }
        pA += 32;
    }

#pragma unroll
    for (int mt = 0; mt < MT; ++mt) {
        int co0 = mg * MT * 16 + mt * 16 + quad * 4;
#pragma unroll
        for (int i = 0; i < NT; ++i) {
            if (OB) {
                u16* o = (u16*)outv;
#pragma unroll
                for (int j = 0; j < 4; ++j)
                    o[((size_t)b_[i] * Co + co0 + j) * HW + hw_[i]] = f2b(acc[mt][i][j]);
            } else {
                float* o = (float*)outv + (size_t)p * TOT;
#pragma unroll
                for (int j = 0; j < 4; ++j)
                    o[((size_t)b_[i] * Co + co0 + j) * HW + hw_[i]] = acc[mt][i][j];
            }
        }
    }

    if constexpr (STATS) {
        // deterministic per-block stats from f32 accumulators (MG==1: block covers all Co)
        __shared__ float sred[4][MT * 16 * 2];
        int wv = tid >> 6;
#pragma unroll
        for (int mt = 0; mt < MT; ++mt) {
#pragma unroll
            for (int j = 0; j < 4; ++j) {
                float ls1 = 0.f, ls2 = 0.f;
#pragma unroll
                for (int i = 0; i < NT; ++i) {
                    float v = acc[mt][i][j];
                    ls1 += v; ls2 += v * v;
                }
#pragma unroll
                for (int m = 1; m < 16; m <<= 1) {
                    ls1 += __shfl_xor(ls1, m);
                    ls2 += __shfl_xor(ls2, m);
                }
                if (r == 0) {
                    int cl = mt * 16 + quad * 4 + j;
                    sred[wv][cl * 2 + 0] = ls1;
                    sred[wv][cl * 2 + 1] = ls2;
                }
            }
        }
        __syncthreads();
        if (tid < MT * 16) {
            float s1 = ((sred[0][tid * 2] + sred[1][tid * 2]) +
                        (sred[2][tid * 2] + sred[3][tid * 2]));
            float s2 = ((sred[0][tid * 2 + 1] + sred[1][tid * 2 + 1]) +
                        (sred[2][tid * 2 + 1] + sred[3][tid * 2 + 1]));
            part[((size_t)tid * gridDim.x + blockIdx.x) * 2 + 0] = s1;
            part[((size_t)tid * gridDim.x + blockIdx.x) * 2 + 1] = s2;
        }
    }
}

// ---------------- stats for K-split fp32 layers (L3/L4) ----------------
template <int C, int HW, int CHUNKS, int P>
__global__ __launch_bounds__(256) void stats_f32(const float* __restrict__ x,
                                                 float* __restrict__ part) {
    constexpr int BPC = 64 / CHUNKS;
    constexpr size_t TOT = (size_t)64 * C * HW;
    int c = blockIdx.x / CHUNKS;
    int chunk = blockIdx.x % CHUNKS;
    int b0 = chunk * BPC;
    double s1 = 0.0, s2 = 0.0;
    for (int bi = 0; bi < BPC; ++bi) {
        const float* base = x + ((size_t)(b0 + bi) * C + c) * HW;
        for (int p = threadIdx.x * 4; p < HW; p += 1024) {
            float4 v = *(const float4*)(base + p);
            if (P == 2) {
                float4 v2 = *(const float4*)(base + TOT + p);
                v.x += v2.x; v.y += v2.y; v.z += v2.z; v.w += v2.w;
            }
            s1 += v.x; s2 += (double)v.x * v.x;
            s1 += v.y; s2 += (double)v.y * v.y;
            s1 += v.z; s2 += (double)v.z * v.z;
            s1 += v.w; s2 += (double)v.w * v.w;
        }
    }
    __shared__ double sh1[256];
    __shared__ double sh2[256];
    int tid = threadIdx.x;
    sh1[tid] = s1; sh2[tid] = s2;
    __syncthreads();
    for (int s = 128; s > 0; s >>= 1) {
        if (tid < s) { sh1[tid] += sh1[tid + s]; sh2[tid] += sh2[tid + s]; }
        __syncthreads();
    }
    if (tid == 0) {
        part[((size_t)c * CHUNKS + chunk) * 2 + 0] = (float)sh1[0];
        part[((size_t)c * CHUNKS + chunk) * 2 + 1] = (float)sh2[0];
    }
}

// ---------------- finalize variants: chunked (L3/L4) and block-slot (L0-L2) ----------------
template <int C, int CHUNKS>
__global__ void bn_finalize(const float* __restrict__ part, const float* __restrict__ g,
                            const float* __restrict__ bb, float* __restrict__ ss,
                            float invN) {
    int c = threadIdx.x;
    if (c >= C) return;
    float s1 = 0.f, s2 = 0.f;
#pragma unroll 8
    for (int k = 0; k < CHUNKS; ++k) {
        s1 += part[((size_t)c * CHUNKS + k) * 2 + 0];
        s2 += part[((size_t)c * CHUNKS + k) * 2 + 1];
    }
    float mean = s1 * invN;
    float var  = s2 * invN - mean * mean;
    float inv  = rsqrtf(var + EPS);
    float sc   = inv * g[c];
    ss[c]     = sc;
    ss[C + c] = bb[c] - mean * sc;
}

template <int C, int NBLK>
__global__ __launch_bounds__(256) void bn_finalize_blk(const float* __restrict__ part,
                                                       const float* __restrict__ g,
                                                       const float* __restrict__ bb,
                                                       float* __restrict__ ss, float invN) {
    int c = blockIdx.x;
    int tid = threadIdx.x;
    float s1 = 0.f, s2 = 0.f;
    for (int k = tid; k < NBLK; k += 256) {
        s1 += part[((size_t)c * NBLK + k) * 2 + 0];
        s2 += part[((size_t)c * NBLK + k) * 2 + 1];
    }
    __shared__ float sh1[256], sh2[256];
    sh1[tid] = s1; sh2[tid] = s2;
    __syncthreads();
    for (int s = 128; s > 0; s >>= 1) {
        if (tid < s) { sh1[tid] += sh1[tid + s]; sh2[tid] += sh2[tid + s]; }
        __syncthreads();
    }
    if (tid == 0) {
        float mean = sh1[0] * invN;
        float var  = sh2[0] * invN - mean * mean;
        float inv  = rsqrtf(var + EPS);
        float sc   = inv * g[c];
        ss[c]     = sc;
        ss[C + c] = bb[c] - mean * sc;
    }
}

// ---------------- BN apply + leaky + padded bf16 write ----------------
template <int C, int H, int W, bool INB, bool SPLIT>
__global__ __launch_bounds__(256) void bn_pad_v(const void* __restrict__ in,
                                                const float* __restrict__ ss,
                                                u16* __restrict__ outp) {
    constexpr int G = W / 8 + 1;
    constexpr int Wp = 8 * G;
    constexpr int Hp = H + 2;
    constexpr size_t TOT = (size_t)64 * C * H * W;
    int idx = blockIdx.x * 256 + threadIdx.x;
    if (idx >= 64 * C * Hp * G) return;
    int m = idx % G;
    int hp = (idx / G) % Hp;
    int c = (idx / (G * Hp)) % C;
    int b = idx / (G * Hp * C);

    u16x8 o;
#pragma unroll
    for (int i = 0; i < 8; ++i) o[i] = 0;

    if (hp >= 1 && hp <= H) {
        float sc = ss[c], sh = ss[C + c];
        float vals[8];
        if (INB) {
            const u16* base = (const u16*)in + ((size_t)(b * C + c) * H + (hp - 1)) * W;
            vals[0] = (m > 0) ? b2f(base[8 * m - 1]) : 0.f;
            if (m < G - 1) {
                bf16x8 va = *(const bf16x8*)(base + 8 * m);
#pragma unroll
                for (int i = 0; i < 7; ++i) vals[i + 1] = b2f((u16)va[i]);
            }
        } else {
            const float* base = (const float*)in + ((size_t)(b * C + c) * H + (hp - 1)) * W;
            if (m > 0) {
                vals[0] = base[8 * m - 1];
                if (SPLIT) vals[0] += base[TOT + 8 * m - 1];
            } else vals[0] = 0.f;
            if (m < G - 1) {
                float4 a  = *(const float4*)(base + 8 * m);
                float4 b4 = *(const float4*)(base + 8 * m + 4);
                if (SPLIT) {
                    float4 a2  = *(const float4*)(base + TOT + 8 * m);
                    float4 b42 = *(const float4*)(base + TOT + 8 * m + 4);
                    a.x += a2.x; a.y += a2.y; a.z += a2.z; a.w += a2.w;
                    b4.x += b42.x; b4.y += b42.y; b4.z += b42.z; b4.w += b42.w;
                }
                vals[1] = a.x; vals[2] = a.y; vals[3] = a.z; vals[4] = a.w;
                vals[5] = b4.x; vals[6] = b4.y; vals[7] = b4.z;
            }
        }
        if (m > 0) o[0] = f2b(leaky(vals[0] * sc + sh));
        if (m < G - 1) {
#pragma unroll
            for (int i = 1; i < 8; ++i) o[i] = f2b(leaky(vals[i] * sc + sh));
        }
    }
    *(u16x8*)(outp + ((size_t)(b * C + c) * Hp + hp) * Wp + 8 * m) = o;
}

// ---------------- L4: BN + leaky + im2col bf16 (sums 2 K-split planes) ----------------
__global__ __launch_bounds__(256) void im2col5(const float* __restrict__ A,
                                               const float* __restrict__ ss,
                                               u16* __restrict__ ic) {
    int idx = blockIdx.x * 256 + threadIdx.x;
    if (idx >= 1472 * 1024) return;
    int k = idx & 1023;
    int n = idx >> 10;
    int b = n / 23, j = n % 23;
    int ci = k >> 2, kh = (k >> 1) & 1, kw = k & 1;
    size_t off = (size_t)b * 12288 + ci * 48 + kh * 24 + j + kw;
    float v = A[off] + A[786432 + off];
    v = leaky(v * ss[ci] + ss[256 + ci]);
    ic[idx] = f2b(v);
}

// ---------------- conv5 GEMM, LDS-staged 64x64 block tile ----------------
__global__ __launch_bounds__(256) void conv5_lds(const u16* __restrict__ ic,
                                                 const u16* __restrict__ w5b,
                                                 u16* __restrict__ ic2) {
    __shared__ u16 As[64][72];
    __shared__ u16 Bs[64][72];
    int tid = threadIdx.x;
    int wv = tid >> 6;
    int lane = tid & 63;
    int r = lane & 15;
    int quad = lane >> 4;
    int gx = blockIdx.x % 23;
    int gy = blockIdx.x / 23;

    int trow = tid >> 3;
    int tcol = (tid & 7) * 8;

    f32x4 acc[2][2];
#pragma unroll
    for (int mi = 0; mi < 2; ++mi)
#pragma unroll
        for (int ni = 0; ni < 2; ++ni) acc[mi][ni] = (f32x4){0.f, 0.f, 0.f, 0.f};

    for (int ko = 0; ko < 16; ++ko) {
        int kbase = ko * 64;
        *(bf16x8*)&As[trow][tcol]      = *(const bf16x8*)(w5b + (size_t)(gy * 64 + trow) * 1024 + kbase + tcol);
        *(bf16x8*)&As[trow + 32][tcol] = *(const bf16x8*)(w5b + (size_t)(gy * 64 + trow + 32) * 1024 + kbase + tcol);
        *(bf16x8*)&Bs[trow][tcol]      = *(const bf16x8*)(ic  + (size_t)(gx * 64 + trow) * 1024 + kbase + tcol);
        *(bf16x8*)&Bs[trow + 32][tcol] = *(const bf16x8*)(ic  + (size_t)(gx * 64 + trow + 32) * 1024 + kbase + tcol);
        __syncthreads();
#pragma unroll
        for (int k2 = 0; k2 < 2; ++k2) {
            int koff = k2 * 32 + quad * 8;
            bf16x8 a0 = *(const bf16x8*)&As[(wv >> 1) * 32 + r][koff];
            bf16x8 a1 = *(const bf16x8*)&As[(wv >> 1) * 32 + 16 + r][koff];
            bf16x8 b0 = *(const bf16x8*)&Bs[(wv & 1) * 32 + r][koff];
            bf16x8 b1 = *(const bf16x8*)&Bs[(wv & 1) * 32 + 16 + r][koff];
            acc[0][0] = __builtin_amdgcn_mfma_f32_16x16x32_bf16(a0, b0, acc[0][0], 0, 0, 0);
            acc[0][1] = __builtin_amdgcn_mfma_f32_16x16x32_bf16(a0, b1, acc[0][1], 0, 0, 0);
            acc[1][0] = __builtin_amdgcn_mfma_f32_16x16x32_bf16(a1, b0, acc[1][0], 0, 0, 0);
            acc[1][1] = __builtin_amdgcn_mfma_f32_16x16x32_bf16(a1, b1, acc[1][1], 0, 0, 0);
        }
        __syncthreads();
    }

#pragma unroll
    for (int mi = 0; mi < 2; ++mi) {
#pragma unroll
        for (int ni = 0; ni < 2; ++ni) {
            int n = gx * 64 + (wv & 1) * 32 + ni * 16 + r;
            int co0 = gy * 64 + (wv >> 1) * 32 + mi * 16 + quad * 4;
            u16x4 pk;
#pragma unroll
            for (int j = 0; j < 4; ++j) pk[j] = f2b(leaky(acc[mi][ni][j]));
            *(u16x4*)(ic2 + (size_t)n * 1024 + co0) = pk;
        }
    }
}

// ---------------- linear as MFMA GEMM + sigmoid ----------------
__global__ __launch_bounds__(256) void linear_mfma(const u16* __restrict__ ic2,
                                                   const u16* __restrict__ lwb,
                                                   float* __restrict__ sig) {
    int tid = threadIdx.x;
    int wid = blockIdx.x * 4 + (tid >> 6);
    int lane = tid & 63;
    int r = lane & 15;
    int quad = lane >> 4;
    int mt = wid & 3;
    int nt = wid >> 2;

    int n = nt * 16 + r;
    const u16* pA = lwb + (size_t)(mt * 16 + r) * 1024 + quad * 8;
    const u16* pB = ic2 + (size_t)n * 1024 + quad * 8;

    f32x4 acc = {0.f, 0.f, 0.f, 0.f};
#pragma unroll 4
    for (int kk = 0; kk < 32; ++kk) {
        bf16x8 a = *(const bf16x8*)pA;
        bf16x8 bv = *(const bf16x8*)pB;
        acc = __builtin_amdgcn_mfma_f32_16x16x32_bf16(a, bv, acc, 0, 0, 0);
        pA += 32;
        pB += 32;
    }

    int b = n / 23, j = n % 23;
#pragma unroll
    for (int jj = 0; jj < 4; ++jj) {
        int o = mt * 16 + quad * 4 + jj;
        float v = 1.f / (1.f + expf(-acc[jj]));
        sig[(size_t)b * 1472 + (size_t)o * 23 + j] = v;
    }
}

// ---------------- final interleave/shuffle ----------------
__global__ void shuffle_out_kernel(const float* __restrict__ sig, float* __restrict__ out) {
    int idx = blockIdx.x * blockDim.x + threadIdx.x;
    if (idx >= 64 * 768) return;
    int o = idx % 32;
    int j = (idx / 32) % 24;
    int b = idx / 768;
    const float* s = sig + (size_t)b * 64 * 23;
    float v;
    if (j == 0)       v = s[o * 23];
    else if (j == 23) v = s[(o + 32) * 23 + 22];
    else              v = 0.5f * (s[(o + 32) * 23 + (j - 1)] + s[o * 23 + j]);
    out[idx] = v;
}

extern "C" void kernel_launch(void* const* d_in, const int* in_sizes, int n_in,
                              void* d_out, int out_size, void* d_ws, size_t ws_size,
                              hipStream_t stream) {
    (void)in_sizes; (void)n_in; (void)out_size; (void)ws_size;

    const float* x = (const float*)d_in[0];
    const float* w[5]; const float* g[5]; const float* bb[5];
    for (int i = 0; i < 5; ++i) {
        w[i]  = (const float*)d_in[1 + 3 * i];
        g[i]  = (const float*)d_in[2 + 3 * i];
        bb[i] = (const float*)d_in[3 + 3 * i];
    }
    const float* w5 = (const float*)d_in[16];
    const float* lw = (const float*)d_in[17];
    float* out = (float*)d_out;

    // ---- workspace layout (~63 MB) ----
    float* ws    = (float*)d_ws;
    float* A     = ws;                          // conv-out (bf16 L0-L2; f32 2-plane L3/L4)
    u16*   P     = (u16*)(ws + 6291456);        // padded inputs
    u16*   wbf   = (u16*)(ws + 13115392);       // 697,344 u16
    float* part  = ws + 13464064;               // 8,192 f32 (L3/L4 chunked stats)
    float* ss    = ws + 13472256;               // 512 f32
    u16*   w5b   = (u16*)(ws + 13474304);       // 1,048,576 u16
    u16*   ic    = (u16*)(ws + 13998592);       // 1,507,328 u16
    u16*   ic2   = (u16*)(ws + 14752256);       // 1,507,328 u16
    u16*   lwb   = (u16*)(ws + 15505920);       // 65,536 u16
    float* partB = ws + 15538688;               // 98,304 f32 (block-slot stats L0-L2)
    float* sig   = ws + 2359296;                // (64,64,23) f32 (dead A region)

    const size_t wofs[5] = {0, 1024, 9216, 41984, 173056};

    hipLaunchKernelGGL(prep, dim3(13478), dim3(256), 0, stream,
                       x, w[0], w[1], w[2], w[3], w[4], w5, lw, wbf, w5b, lwb, P);

    // L0: conv (bf16 out) + fused stats; 1536 blocks
    hipLaunchKernelGGL((conv_mfma<16, 4, 64, 64, 768, 66, 776, 1, 8, 1, true, true>),
                       dim3(1536), dim3(256), 0, stream, P, wbf + wofs[0], A, partB);
    hipLaunchKernelGGL((bn_finalize_blk<16, 1536>), dim3(16), dim3(256), 0, stream,
                       partB, g[0], bb[0], ss, 1.f / 786432.f);
    hipLaunchKernelGGL((bn_pad_v<16, 32, 384, true, false>), dim3(6664), dim3(256), 0, stream,
                       (const void*)A, ss, P);

    // L1: conv (bf16 out) + fused stats; 1536 blocks
    hipLaunchKernelGGL((conv_mfma<32, 16, 256, 32, 384, 34, 392, 2, 2, 1, true, true>),
                       dim3(1536), dim3(256), 0, stream, P, wbf + wofs[1], A, partB);
    hipLaunchKernelGGL((bn_finalize_blk<32, 1536>), dim3(32), dim3(256), 0, stream,
                       partB, g[1], bb[1], ss, 1.f / 196608.f);
    hipLaunchKernelGGL((bn_pad_v<32, 16, 192, true, false>), dim3(3600), dim3(256), 0, stream,
                       (const void*)A, ss, P);

    // L2: conv (bf16 out) + fused stats; 384 blocks
    hipLaunchKernelGGL((conv_mfma<64, 32, 512, 16, 192, 18, 200, 4, 2, 1, true, true>),
                       dim3(384), dim3(256), 0, stream, P, wbf + wofs[2], A, partB);
    hipLaunchKernelGGL((bn_finalize_blk<64, 384>), dim3(64), dim3(256), 0, stream,
                       partB, g[2], bb[2], ss, 1.f / 49152.f);
    hipLaunchKernelGGL((bn_pad_v<64, 8, 96, true, false>), dim3(2080), dim3(256), 0, stream,
                       (const void*)A, ss, P);

    // L3: K-split P=2, f32 planes; separate stats
    hipLaunchKernelGGL((conv_mfma<128, 64, 1024, 8, 96, 10, 104, 4, 1, 2, false, false>),
                       dim3(384, 2), dim3(256), 0, stream, P, wbf + wofs[3], A, partB);
    hipLaunchKernelGGL((stats_f32<128, 192, 16, 2>), dim3(2048), dim3(256), 0, stream, A, part);
    hipLaunchKernelGGL((bn_finalize<128, 16>), dim3(1), dim3(256), 0, stream,
                       part, g[3], bb[3], ss, 1.f / 12288.f);
    hipLaunchKernelGGL((bn_pad_v<128, 4, 48, false, true>), dim3(1344), dim3(256), 0, stream,
                       (const void*)A, ss, P);

    // L4: K-split P=2, f32 planes; separate stats
    hipLaunchKernelGGL((conv_mfma<256, 128, 2048, 4, 48, 6, 56, 4, 1, 2, false, false>),
                       dim3(192, 2), dim3(256), 0, stream, P, wbf + wofs[4], A, partB);
    hipLaunchKernelGGL((stats_f32<256, 48, 16, 2>), dim3(4096), dim3(256), 0, stream, A, part);
    hipLaunchKernelGGL((bn_finalize<256, 16>), dim3(1), dim3(256), 0, stream,
                       part, g[4], bb[4], ss, 1.f / 3072.f);
    hipLaunchKernelGGL(im2col5, dim3(5888), dim3(256), 0, stream, A, ss, ic);

    // tail
    hipLaunchKernelGGL(conv5_lds, dim3(368), dim3(256), 0, stream, ic, w5b, ic2);
    hipLaunchKernelGGL(linear_mfma, dim3(92), dim3(256), 0, stream, ic2, lwb, sig);
    hipLaunchKernelGGL(shuffle_out_kernel, dim3((64 * 768 + 255) / 256), dim3(256), 0, stream,
                       sig, out);
}